// Round 1
// baseline (9679.910 us; speedup 1.0000x reference)
//
#include <hip/hip_runtime.h>

typedef __attribute__((ext_vector_type(8))) short bf16x8;
typedef __attribute__((ext_vector_type(4))) float f32x4;

constexpr int T = 2048;
constexpr int D = 4096;
constexpr int NQ = 32;    // query heads
constexpr int NKV = 8;    // kv heads
constexpr int H = 128;    // head dim
constexpr int F = 14336;  // ffn dim

__device__ inline unsigned short f2bf(float f) {
  unsigned u = __float_as_uint(f);
  return (unsigned short)((u + 0x7FFFu + ((u >> 16) & 1u)) >> 16);
}

// ---------------- RMSNorm: f32 in -> bf16 out ----------------
__global__ __launch_bounds__(256) void rmsnorm_kernel(
    const float* __restrict__ in, const float* __restrict__ scale,
    unsigned short* __restrict__ out) {
  int row = blockIdx.x;
  const float4* xr = (const float4*)(in + (size_t)row * D);
  const float4* sr = (const float4*)scale;
  float4 vals[4];
  float ss = 0.f;
#pragma unroll
  for (int i = 0; i < 4; ++i) {
    float4 v = xr[threadIdx.x + i * 256];
    vals[i] = v;
    ss += v.x * v.x + v.y * v.y + v.z * v.z + v.w * v.w;
  }
#pragma unroll
  for (int off = 32; off; off >>= 1) ss += __shfl_xor(ss, off, 64);
  __shared__ float wsum[4];
  if ((threadIdx.x & 63) == 0) wsum[threadIdx.x >> 6] = ss;
  __syncthreads();
  float r = rsqrtf((wsum[0] + wsum[1] + wsum[2] + wsum[3]) * (1.f / D) + 1e-5f);
#pragma unroll
  for (int i = 0; i < 4; ++i) {
    int vi = threadIdx.x + i * 256;
    float4 v = vals[i];
    float4 s = sr[vi];
    ushort4 o;
    o.x = f2bf(v.x * r * s.x);
    o.y = f2bf(v.y * r * s.y);
    o.z = f2bf(v.z * r * s.z);
    o.w = f2bf(v.w * r * s.w);
    *(ushort4*)(out + (size_t)row * D + (size_t)vi * 4) = o;
  }
}

// ---------------- RoPE cos/sin table ----------------
__global__ __launch_bounds__(256) void rope_table(const int* __restrict__ pos,
                                                  float* __restrict__ ctab,
                                                  float* __restrict__ stab) {
  int idx = blockIdx.x * 256 + threadIdx.x;  // T*64
  int t = idx >> 6, i = idx & 63;
  float inv = exp2f(-(float)i * (log2f(500000.0f) / 64.0f));
  float ang = (float)pos[t] * inv;
  ctab[idx] = cosf(ang);
  stab[idx] = sinf(ang);
}

// ---------------- RoPE apply (in-place, f32) ----------------
__global__ __launch_bounds__(256) void rope_apply(float* __restrict__ x,
                                                  const float* __restrict__ ctab,
                                                  const float* __restrict__ stab,
                                                  int nheads) {
  int idx = blockIdx.x * 256 + threadIdx.x;  // T*nheads*64
  int i = idx & 63;
  int tn = idx >> 6;
  int t = tn / nheads;
  float c = ctab[t * 64 + i], s = stab[t * 64 + i];
  float* p = x + (size_t)tn * H;
  float x1 = p[i], x2 = p[i + 64];
  p[i] = x1 * c - x2 * s;
  p[i + 64] = x2 * c + x1 * s;
}

// ---------------- GEMM: A bf16 (MxK), B f32 (KxN) -> epilogue ----------------
// EP 0: outF = acc            (f32)
// EP 1: outF = acc + addend   (f32)
// EP 2: dual-B; outB = bf16(silu(acc_B0) * acc_B1)
template <int EP>
__global__ __launch_bounds__(256) void gemm_kernel(
    const unsigned short* __restrict__ A, const float* __restrict__ B0,
    const float* __restrict__ B1, const float* __restrict__ addend,
    float* __restrict__ outF, unsigned short* __restrict__ outB, int Kd, int Nd) {
  constexpr int LDT = 40;  // padded LDS row stride (bf16 elems) -> conflict-friendly
  __shared__ unsigned short lA[128 * LDT];
  __shared__ unsigned short lB0[128 * LDT];
  __shared__ unsigned short lB1[(EP == 2) ? 128 * LDT : 8];

  const int tid = threadIdx.x;
  const int m0 = blockIdx.x * 128;
  const int n0 = blockIdx.y * 128;

  f32x4 acc[4][4];
  f32x4 acc1[(EP == 2) ? 4 : 1][(EP == 2) ? 4 : 1];
#pragma unroll
  for (int i = 0; i < 4; ++i)
#pragma unroll
    for (int j = 0; j < 4; ++j) {
      acc[i][j] = (f32x4){0.f, 0.f, 0.f, 0.f};
      if constexpr (EP == 2) acc1[i][j] = (f32x4){0.f, 0.f, 0.f, 0.f};
    }

  const int lane = tid & 63;
  const int wv = tid >> 6;
  const int wr = (wv >> 1) * 64;  // wave row offset in tile
  const int wc = (wv & 1) * 64;   // wave col offset in tile
  const int k8 = (lane >> 4) * 8;
  const int rl = lane & 15;

  const int ar = tid >> 3;         // 0..31 (A row group)
  const int ac = (tid & 7) * 4;    // 0..28 (A col)
  const int bkr = tid >> 5;        // 0..7  (B k row group)
  const int bc = (tid & 31) * 4;   // 0..124 (B col)

  for (int k0 = 0; k0 < Kd; k0 += 32) {
    __syncthreads();
    // --- stage A tile (128x32 bf16), direct copy ---
    {
      const unsigned short* Ag = A + (size_t)(m0 + ar) * Kd + k0 + ac;
#pragma unroll
      for (int p = 0; p < 4; ++p) {
        ushort4 vA = *(const ushort4*)(Ag + (size_t)(p * 32) * Kd);
        *(ushort4*)&lA[(ar + p * 32) * LDT + ac] = vA;
      }
    }
    // --- stage B tile (32x128 f32) transposed+converted -> lB[n][k] bf16 ---
    {
      const float* Bg = B0 + (size_t)(k0 + bkr) * Nd + n0 + bc;
#pragma unroll
      for (int p = 0; p < 4; ++p) {
        float4 bv = *(const float4*)(Bg + (size_t)(p * 8) * Nd);
        int kk = bkr + p * 8;
        lB0[(bc + 0) * LDT + kk] = f2bf(bv.x);
        lB0[(bc + 1) * LDT + kk] = f2bf(bv.y);
        lB0[(bc + 2) * LDT + kk] = f2bf(bv.z);
        lB0[(bc + 3) * LDT + kk] = f2bf(bv.w);
      }
      if constexpr (EP == 2) {
        const float* Bg1 = B1 + (size_t)(k0 + bkr) * Nd + n0 + bc;
#pragma unroll
        for (int p = 0; p < 4; ++p) {
          float4 bv = *(const float4*)(Bg1 + (size_t)(p * 8) * Nd);
          int kk = bkr + p * 8;
          lB1[(bc + 0) * LDT + kk] = f2bf(bv.x);
          lB1[(bc + 1) * LDT + kk] = f2bf(bv.y);
          lB1[(bc + 2) * LDT + kk] = f2bf(bv.z);
          lB1[(bc + 3) * LDT + kk] = f2bf(bv.w);
        }
      }
    }
    __syncthreads();
    // --- MFMA on the 32-deep K slab ---
    bf16x8 af[4], bfr[4], bfr1[(EP == 2) ? 4 : 1];
#pragma unroll
    for (int i = 0; i < 4; ++i)
      af[i] = *(const bf16x8*)&lA[(wr + i * 16 + rl) * LDT + k8];
#pragma unroll
    for (int j = 0; j < 4; ++j) {
      bfr[j] = *(const bf16x8*)&lB0[(wc + j * 16 + rl) * LDT + k8];
      if constexpr (EP == 2)
        bfr1[j] = *(const bf16x8*)&lB1[(wc + j * 16 + rl) * LDT + k8];
    }
#pragma unroll
    for (int i = 0; i < 4; ++i)
#pragma unroll
      for (int j = 0; j < 4; ++j) {
        acc[i][j] =
            __builtin_amdgcn_mfma_f32_16x16x32_bf16(af[i], bfr[j], acc[i][j], 0, 0, 0);
        if constexpr (EP == 2)
          acc1[i][j] = __builtin_amdgcn_mfma_f32_16x16x32_bf16(af[i], bfr1[j],
                                                               acc1[i][j], 0, 0, 0);
      }
  }

  // --- epilogue: C/D layout col=lane&15, row=(lane>>4)*4+reg ---
  const int rb = (lane >> 4) * 4;
#pragma unroll
  for (int i = 0; i < 4; ++i)
#pragma unroll
    for (int j = 0; j < 4; ++j)
#pragma unroll
      for (int jj = 0; jj < 4; ++jj) {
        int row = m0 + wr + i * 16 + rb + jj;
        int col = n0 + wc + j * 16 + rl;
        size_t idx = (size_t)row * Nd + col;
        float val = acc[i][j][jj];
        if constexpr (EP == 0) {
          outF[idx] = val;
        } else if constexpr (EP == 1) {
          outF[idx] = val + addend[idx];
        } else {
          float g = val;
          float u = acc1[i][j][jj];
          float a = g / (1.f + __expf(-g)) * u;
          outB[idx] = f2bf(a);
        }
      }
}

// ---------------- Attention: wave per (t, head), online softmax, f32 ----------------
__global__ __launch_bounds__(256) void attn_kernel(const float* __restrict__ q,
                                                   const float* __restrict__ k,
                                                   const float* __restrict__ v,
                                                   unsigned short* __restrict__ out) {
  int wave = (blockIdx.x * 256 + threadIdx.x) >> 6;  // t*NQ + n
  int lane = threadIdx.x & 63;
  int t = wave >> 5;
  int n = wave & 31;
  int kv = n >> 2;  // G = NQ/NKV = 4
  const float* qp = q + ((size_t)t * NQ + n) * H;
  float q0 = qp[lane], q1 = qp[lane + 64];
  const float scale = 0.08838834764831845f;  // 1/sqrt(128)
  float m = -INFINITY, l = 0.f, o0 = 0.f, o1 = 0.f;
  for (int s = 0; s <= t; ++s) {
    const float* kp = k + ((size_t)s * NKV + kv) * H;
    float part = q0 * kp[lane] + q1 * kp[lane + 64];
#pragma unroll
    for (int off = 32; off; off >>= 1) part += __shfl_xor(part, off, 64);
    float sc = part * scale;
    float nm = fmaxf(m, sc);
    float corr = __expf(m - nm);
    float p = __expf(sc - nm);
    const float* vp = v + ((size_t)s * NKV + kv) * H;
    l = l * corr + p;
    o0 = o0 * corr + p * vp[lane];
    o1 = o1 * corr + p * vp[lane + 64];
    m = nm;
  }
  float inv = 1.f / l;
  unsigned short* op = out + ((size_t)t * NQ + n) * H;
  op[lane] = f2bf(o0 * inv);
  op[lane + 64] = f2bf(o1 * inv);
}

extern "C" void kernel_launch(void* const* d_in, const int* in_sizes, int n_in,
                              void* d_out, int out_size, void* d_ws, size_t ws_size,
                              hipStream_t stream) {
  (void)in_sizes; (void)n_in; (void)out_size; (void)ws_size;
  const float* x = (const float*)d_in[0];
  const int* positions = (const int*)d_in[1];
  const float* ln1 = (const float*)d_in[2];
  const float* w_q = (const float*)d_in[3];
  const float* w_k = (const float*)d_in[4];
  const float* w_v = (const float*)d_in[5];
  const float* w_o = (const float*)d_in[6];
  const float* ln2 = (const float*)d_in[7];
  const float* w_gate = (const float*)d_in[8];
  const float* w_up = (const float*)d_in[9];
  const float* w_down = (const float*)d_in[10];
  float* out = (float*)d_out;

  char* ws = (char*)d_ws;
  size_t off = 0;
  auto alloc = [&](size_t bytes) {
    char* p = ws + off;
    off += (bytes + 255) & ~(size_t)255;
    return p;
  };
  unsigned short* h_bf = (unsigned short*)alloc((size_t)T * D * 2);
  unsigned short* h2_bf = (unsigned short*)alloc((size_t)T * D * 2);
  unsigned short* attn_bf = (unsigned short*)alloc((size_t)T * NQ * H * 2);
  unsigned short* act_bf = (unsigned short*)alloc((size_t)T * F * 2);
  float* qf = (float*)alloc((size_t)T * NQ * H * 4);
  float* kf = (float*)alloc((size_t)T * NKV * H * 4);
  float* vf = (float*)alloc((size_t)T * NKV * H * 4);
  float* resid = (float*)alloc((size_t)T * D * 4);
  float* ctab = (float*)alloc((size_t)T * 64 * 4);
  float* stab = (float*)alloc((size_t)T * 64 * 4);

  // h = rmsnorm(x) * ln1  (bf16)
  rmsnorm_kernel<<<T, 256, 0, stream>>>(x, ln1, h_bf);
  rope_table<<<(T * 64) / 256, 256, 0, stream>>>(positions, ctab, stab);
  // q, k, v projections
  gemm_kernel<0><<<dim3(T / 128, (NQ * H) / 128), 256, 0, stream>>>(
      h_bf, w_q, nullptr, nullptr, qf, nullptr, D, NQ * H);
  gemm_kernel<0><<<dim3(T / 128, (NKV * H) / 128), 256, 0, stream>>>(
      h_bf, w_k, nullptr, nullptr, kf, nullptr, D, NKV * H);
  gemm_kernel<0><<<dim3(T / 128, (NKV * H) / 128), 256, 0, stream>>>(
      h_bf, w_v, nullptr, nullptr, vf, nullptr, D, NKV * H);
  // RoPE on q and k
  rope_apply<<<(T * NQ * 64) / 256, 256, 0, stream>>>(qf, ctab, stab, NQ);
  rope_apply<<<(T * NKV * 64) / 256, 256, 0, stream>>>(kf, ctab, stab, NKV);
  // attention -> bf16 (T, NQ, H)
  attn_kernel<<<(T * NQ) / 4, 256, 0, stream>>>(qf, kf, vf, attn_bf);
  // O projection + residual
  gemm_kernel<1><<<dim3(T / 128, D / 128), 256, 0, stream>>>(
      attn_bf, w_o, nullptr, x, resid, nullptr, NQ * H, D);
  // second norm
  rmsnorm_kernel<<<T, 256, 0, stream>>>(resid, ln2, h2_bf);
  // gate/up fused -> act bf16
  gemm_kernel<2><<<dim3(T / 128, F / 128), 256, 0, stream>>>(
      h2_bf, w_gate, w_up, nullptr, nullptr, act_bf, D, F);
  // down projection + residual -> out
  gemm_kernel<1><<<dim3(T / 128, D / 128), 256, 0, stream>>>(
      act_bf, w_down, nullptr, resid, out, nullptr, F, D);
}

// Round 2
// 5174.352 us; speedup vs baseline: 1.8707x; 1.8707x over previous
//
#include <hip/hip_runtime.h>

typedef __attribute__((ext_vector_type(8))) short bf16x8;
typedef __attribute__((ext_vector_type(4))) float f32x4;

constexpr int T = 2048;
constexpr int D = 4096;
constexpr int NQ = 32;    // query heads
constexpr int NKV = 8;    // kv heads
constexpr int H = 128;    // head dim
constexpr int F = 14336;  // ffn dim

__device__ inline unsigned short f2bf(float f) {
  unsigned u = __float_as_uint(f);
  return (unsigned short)((u + 0x7FFFu + ((u >> 16) & 1u)) >> 16);
}

// ---------------- RMSNorm: f32 in -> bf16 out ----------------
__global__ __launch_bounds__(256) void rmsnorm_kernel(
    const float* __restrict__ in, const float* __restrict__ scale,
    unsigned short* __restrict__ out) {
  int row = blockIdx.x;
  const float4* xr = (const float4*)(in + (size_t)row * D);
  const float4* sr = (const float4*)scale;
  float4 vals[4];
  float ss = 0.f;
#pragma unroll
  for (int i = 0; i < 4; ++i) {
    float4 v = xr[threadIdx.x + i * 256];
    vals[i] = v;
    ss += v.x * v.x + v.y * v.y + v.z * v.z + v.w * v.w;
  }
#pragma unroll
  for (int off = 32; off; off >>= 1) ss += __shfl_xor(ss, off, 64);
  __shared__ float wsum[4];
  if ((threadIdx.x & 63) == 0) wsum[threadIdx.x >> 6] = ss;
  __syncthreads();
  float r = rsqrtf((wsum[0] + wsum[1] + wsum[2] + wsum[3]) * (1.f / D) + 1e-5f);
#pragma unroll
  for (int i = 0; i < 4; ++i) {
    int vi = threadIdx.x + i * 256;
    float4 v = vals[i];
    float4 s = sr[vi];
    ushort4 o;
    o.x = f2bf(v.x * r * s.x);
    o.y = f2bf(v.y * r * s.y);
    o.z = f2bf(v.z * r * s.z);
    o.w = f2bf(v.w * r * s.w);
    *(ushort4*)(out + (size_t)row * D + (size_t)vi * 4) = o;
  }
}

// ---------------- RoPE cos/sin table ----------------
__global__ __launch_bounds__(256) void rope_table(const int* __restrict__ pos,
                                                  float* __restrict__ ctab,
                                                  float* __restrict__ stab) {
  int idx = blockIdx.x * 256 + threadIdx.x;  // T*64
  int t = idx >> 6, i = idx & 63;
  float inv = exp2f(-(float)i * (log2f(500000.0f) / 64.0f));
  float ang = (float)pos[t] * inv;
  ctab[idx] = cosf(ang);
  stab[idx] = sinf(ang);
}

// ---------------- RoPE apply: f32 in -> bf16 out (scale folded) ----------------
__global__ __launch_bounds__(256) void rope_bf16(const float* __restrict__ x,
                                                 const float* __restrict__ ctab,
                                                 const float* __restrict__ stab,
                                                 unsigned short* __restrict__ out,
                                                 int nheads, float scale) {
  int idx = blockIdx.x * 256 + threadIdx.x;  // T*nheads*64
  int i = idx & 63;
  int tn = idx >> 6;
  int t = tn / nheads;
  float c = ctab[t * 64 + i], s = stab[t * 64 + i];
  const float* p = x + (size_t)tn * H;
  float x1 = p[i], x2 = p[i + 64];
  unsigned short* o = out + (size_t)tn * H;
  o[i] = f2bf((x1 * c - x2 * s) * scale);
  o[i + 64] = f2bf((x2 * c + x1 * s) * scale);
}

// ---------------- GEMM: A bf16 (MxK), B f32 (KxN) -> epilogue ----------------
// EP 0: outF = acc            (f32)
// EP 1: outF = acc + addend   (f32)
// EP 2: dual-B; outB = bf16(silu(acc_B0) * acc_B1)
// EP 3: outB[col*T + row] = bf16(acc)   (transposed bf16 write, M==T)
template <int EP>
__global__ __launch_bounds__(256) void gemm_kernel(
    const unsigned short* __restrict__ A, const float* __restrict__ B0,
    const float* __restrict__ B1, const float* __restrict__ addend,
    float* __restrict__ outF, unsigned short* __restrict__ outB, int Kd, int Nd) {
  constexpr int LDT = 40;  // padded LDS row stride (bf16 elems)
  __shared__ unsigned short lA[128 * LDT];
  __shared__ unsigned short lB0[128 * LDT];
  __shared__ unsigned short lB1[(EP == 2) ? 128 * LDT : 8];

  const int tid = threadIdx.x;
  const int m0 = blockIdx.x * 128;
  const int n0 = blockIdx.y * 128;

  f32x4 acc[4][4];
  f32x4 acc1[(EP == 2) ? 4 : 1][(EP == 2) ? 4 : 1];
#pragma unroll
  for (int i = 0; i < 4; ++i)
#pragma unroll
    for (int j = 0; j < 4; ++j) {
      acc[i][j] = (f32x4){0.f, 0.f, 0.f, 0.f};
      if constexpr (EP == 2) acc1[i][j] = (f32x4){0.f, 0.f, 0.f, 0.f};
    }

  const int lane = tid & 63;
  const int wv = tid >> 6;
  const int wr = (wv >> 1) * 64;  // wave row offset in tile
  const int wc = (wv & 1) * 64;   // wave col offset in tile
  const int k8 = (lane >> 4) * 8;
  const int rl = lane & 15;

  const int ar = tid >> 3;         // 0..31 (A row group)
  const int ac = (tid & 7) * 4;    // 0..28 (A col)
  const int bkr = tid >> 5;        // 0..7  (B k row group)
  const int bc = (tid & 31) * 4;   // 0..124 (B col)

  for (int k0 = 0; k0 < Kd; k0 += 32) {
    __syncthreads();
    {
      const unsigned short* Ag = A + (size_t)(m0 + ar) * Kd + k0 + ac;
#pragma unroll
      for (int p = 0; p < 4; ++p) {
        ushort4 vA = *(const ushort4*)(Ag + (size_t)(p * 32) * Kd);
        *(ushort4*)&lA[(ar + p * 32) * LDT + ac] = vA;
      }
    }
    {
      const float* Bg = B0 + (size_t)(k0 + bkr) * Nd + n0 + bc;
#pragma unroll
      for (int p = 0; p < 4; ++p) {
        float4 bv = *(const float4*)(Bg + (size_t)(p * 8) * Nd);
        int kk = bkr + p * 8;
        lB0[(bc + 0) * LDT + kk] = f2bf(bv.x);
        lB0[(bc + 1) * LDT + kk] = f2bf(bv.y);
        lB0[(bc + 2) * LDT + kk] = f2bf(bv.z);
        lB0[(bc + 3) * LDT + kk] = f2bf(bv.w);
      }
      if constexpr (EP == 2) {
        const float* Bg1 = B1 + (size_t)(k0 + bkr) * Nd + n0 + bc;
#pragma unroll
        for (int p = 0; p < 4; ++p) {
          float4 bv = *(const float4*)(Bg1 + (size_t)(p * 8) * Nd);
          int kk = bkr + p * 8;
          lB1[(bc + 0) * LDT + kk] = f2bf(bv.x);
          lB1[(bc + 1) * LDT + kk] = f2bf(bv.y);
          lB1[(bc + 2) * LDT + kk] = f2bf(bv.z);
          lB1[(bc + 3) * LDT + kk] = f2bf(bv.w);
        }
      }
    }
    __syncthreads();
    bf16x8 af[4], bfr[4], bfr1[(EP == 2) ? 4 : 1];
#pragma unroll
    for (int i = 0; i < 4; ++i)
      af[i] = *(const bf16x8*)&lA[(wr + i * 16 + rl) * LDT + k8];
#pragma unroll
    for (int j = 0; j < 4; ++j) {
      bfr[j] = *(const bf16x8*)&lB0[(wc + j * 16 + rl) * LDT + k8];
      if constexpr (EP == 2)
        bfr1[j] = *(const bf16x8*)&lB1[(wc + j * 16 + rl) * LDT + k8];
    }
#pragma unroll
    for (int i = 0; i < 4; ++i)
#pragma unroll
      for (int j = 0; j < 4; ++j) {
        acc[i][j] =
            __builtin_amdgcn_mfma_f32_16x16x32_bf16(af[i], bfr[j], acc[i][j], 0, 0, 0);
        if constexpr (EP == 2)
          acc1[i][j] = __builtin_amdgcn_mfma_f32_16x16x32_bf16(af[i], bfr1[j],
                                                               acc1[i][j], 0, 0, 0);
      }
  }

  const int rb = (lane >> 4) * 4;
#pragma unroll
  for (int i = 0; i < 4; ++i)
#pragma unroll
    for (int j = 0; j < 4; ++j) {
      if constexpr (EP == 3) {
        int row0 = m0 + wr + i * 16 + rb;
        int col = n0 + wc + j * 16 + rl;
        ushort4 o;
        o.x = f2bf(acc[i][j][0]);
        o.y = f2bf(acc[i][j][1]);
        o.z = f2bf(acc[i][j][2]);
        o.w = f2bf(acc[i][j][3]);
        *(ushort4*)&outB[(size_t)col * T + row0] = o;
      } else {
#pragma unroll
        for (int jj = 0; jj < 4; ++jj) {
          int row = m0 + wr + i * 16 + rb + jj;
          int col = n0 + wc + j * 16 + rl;
          size_t idx = (size_t)row * Nd + col;
          float val = acc[i][j][jj];
          if constexpr (EP == 0) {
            outF[idx] = val;
          } else if constexpr (EP == 1) {
            outF[idx] = val + addend[idx];
          } else if constexpr (EP == 2) {
            float g = val;
            float u = acc1[i][j][jj];
            float a = g / (1.f + __expf(-g)) * u;
            outB[idx] = f2bf(a);
          }
        }
      }
    }
}

// ---------------- Flash attention (MFMA) ----------------
// Q (T,NQ,H) bf16 pre-scaled+roped; K (T,NKV,H) bf16 roped; Vt (NKV*H, T) bf16.
// Block: 64 q-rows x 1 head; 4 waves x 16 rows. KV tiles of 64.
constexpr int KLD = 136;  // K_lds row stride (bf16)
constexpr int VLD = 72;   // Vt_lds row stride
constexpr int PLD = 72;   // P_lds row stride

__global__ __launch_bounds__(256) void flash_attn(
    const unsigned short* __restrict__ qbf, const unsigned short* __restrict__ kbf,
    const unsigned short* __restrict__ vtbf, unsigned short* __restrict__ out) {
  __shared__ unsigned short K_lds[64 * KLD];
  __shared__ unsigned short Vt_lds[H * VLD];
  __shared__ unsigned short P_lds[4 * 16 * PLD];

  const int tid = threadIdx.x;
  const int lane = tid & 63;
  const int wave = tid >> 6;
  const int qb = blockIdx.x;
  const int n = blockIdx.y;
  const int kvh = n >> 2;
  const int g = lane >> 4;
  const int rl = lane & 15;
  const int qrow = qb * 64 + wave * 16;

  // Q fragments: lane -> q row (qrow+rl), k = ks*32 + g*8 + e
  bf16x8 qfrag[4];
  {
    const unsigned short* qp = qbf + ((size_t)(qrow + rl) * NQ + n) * H + g * 8;
#pragma unroll
    for (int ks = 0; ks < 4; ++ks) qfrag[ks] = *(const bf16x8*)(qp + ks * 32);
  }

  f32x4 oacc[8];
#pragma unroll
  for (int ob = 0; ob < 8; ++ob) oacc[ob] = (f32x4){0.f, 0.f, 0.f, 0.f};
  float mrun[4] = {-1e30f, -1e30f, -1e30f, -1e30f};
  float lrun[4] = {0.f, 0.f, 0.f, 0.f};

  // staging maps
  const int krow = tid >> 2, kseg = (tid & 3) * 32;        // K: row 0..63, 32 cols
  const int vh = tid >> 1, vseg = (tid & 1) * 32;          // Vt: h 0..127, 32 s-cols

  for (int kt = 0; kt <= qb; ++kt) {
    const int kbase = kt * 64;
    __syncthreads();
    {
      const unsigned short* kp =
          kbf + ((size_t)(kbase + krow) * NKV + kvh) * H + kseg;
#pragma unroll
      for (int i = 0; i < 4; ++i)
        *(bf16x8*)&K_lds[krow * KLD + kseg + i * 8] = *(const bf16x8*)(kp + i * 8);
      const unsigned short* vp =
          vtbf + (size_t)(kvh * H + vh) * T + kbase + vseg;
#pragma unroll
      for (int i = 0; i < 4; ++i)
        *(bf16x8*)&Vt_lds[vh * VLD + vseg + i * 8] = *(const bf16x8*)(vp + i * 8);
    }
    __syncthreads();

    // S = Q K^T  (acc: row = q = g*4+r, col = kv = cb*16+rl)
    f32x4 sacc[4];
#pragma unroll
    for (int cb = 0; cb < 4; ++cb) sacc[cb] = (f32x4){0.f, 0.f, 0.f, 0.f};
#pragma unroll
    for (int cb = 0; cb < 4; ++cb)
#pragma unroll
      for (int ks = 0; ks < 4; ++ks) {
        bf16x8 kf = *(const bf16x8*)&K_lds[(cb * 16 + rl) * KLD + ks * 32 + g * 8];
        sacc[cb] = __builtin_amdgcn_mfma_f32_16x16x32_bf16(qfrag[ks], kf, sacc[cb], 0, 0, 0);
      }

    if (kt == qb) {  // diagonal tile: causal mask
#pragma unroll
      for (int cb = 0; cb < 4; ++cb) {
        int kvg = cb * 16 + rl;  // relative; qrel = wave*16 + g*4 + r... both + qb*64
#pragma unroll
        for (int r = 0; r < 4; ++r) {
          int qrel = wave * 16 + g * 4 + r;
          if (kvg > qrel) sacc[cb][r] = -1e30f;
        }
      }
    }

    // row max over kv: in-register over cb, then shfl over 16-lane col group
    float mx[4], sm[4], corr[4];
#pragma unroll
    for (int r = 0; r < 4; ++r) {
      float m0 = fmaxf(fmaxf(sacc[0][r], sacc[1][r]), fmaxf(sacc[2][r], sacc[3][r]));
#pragma unroll
      for (int off = 1; off < 16; off <<= 1) m0 = fmaxf(m0, __shfl_xor(m0, off, 64));
      float nm = fmaxf(mrun[r], m0);
      corr[r] = __expf(mrun[r] - nm);
      mrun[r] = nm;
      mx[r] = nm;
    }
#pragma unroll
    for (int cb = 0; cb < 4; ++cb)
#pragma unroll
      for (int r = 0; r < 4; ++r) sacc[cb][r] = __expf(sacc[cb][r] - mx[r]);
#pragma unroll
    for (int r = 0; r < 4; ++r) {
      float s0 = sacc[0][r] + sacc[1][r] + sacc[2][r] + sacc[3][r];
#pragma unroll
      for (int off = 1; off < 16; off <<= 1) s0 += __shfl_xor(s0, off, 64);
      sm[r] = s0;
      lrun[r] = lrun[r] * corr[r] + sm[r];
    }
#pragma unroll
    for (int ob = 0; ob < 8; ++ob)
#pragma unroll
      for (int r = 0; r < 4; ++r) oacc[ob][r] *= corr[r];

    // P -> LDS (per-wave region), re-layout to A-fragment
#pragma unroll
    for (int cb = 0; cb < 4; ++cb)
#pragma unroll
      for (int r = 0; r < 4; ++r)
        P_lds[(wave * 16 + g * 4 + r) * PLD + cb * 16 + rl] = f2bf(sacc[cb][r]);

    bf16x8 pa[2];
#pragma unroll
    for (int ks = 0; ks < 2; ++ks)
      pa[ks] = *(const bf16x8*)&P_lds[(wave * 16 + rl) * PLD + ks * 32 + g * 8];

#pragma unroll
    for (int ob = 0; ob < 8; ++ob)
#pragma unroll
      for (int ks = 0; ks < 2; ++ks) {
        bf16x8 vf = *(const bf16x8*)&Vt_lds[(ob * 16 + rl) * VLD + ks * 32 + g * 8];
        oacc[ob] = __builtin_amdgcn_mfma_f32_16x16x32_bf16(pa[ks], vf, oacc[ob], 0, 0, 0);
      }
  }

  float inv[4];
#pragma unroll
  for (int r = 0; r < 4; ++r) inv[r] = 1.f / lrun[r];
#pragma unroll
  for (int ob = 0; ob < 8; ++ob)
#pragma unroll
    for (int r = 0; r < 4; ++r) {
      int t = qrow + g * 4 + r;
      out[((size_t)t * NQ + n) * H + ob * 16 + rl] = f2bf(oacc[ob][r] * inv[r]);
    }
}

extern "C" void kernel_launch(void* const* d_in, const int* in_sizes, int n_in,
                              void* d_out, int out_size, void* d_ws, size_t ws_size,
                              hipStream_t stream) {
  (void)in_sizes; (void)n_in; (void)out_size; (void)ws_size;
  const float* x = (const float*)d_in[0];
  const int* positions = (const int*)d_in[1];
  const float* ln1 = (const float*)d_in[2];
  const float* w_q = (const float*)d_in[3];
  const float* w_k = (const float*)d_in[4];
  const float* w_v = (const float*)d_in[5];
  const float* w_o = (const float*)d_in[6];
  const float* ln2 = (const float*)d_in[7];
  const float* w_gate = (const float*)d_in[8];
  const float* w_up = (const float*)d_in[9];
  const float* w_down = (const float*)d_in[10];
  float* out = (float*)d_out;

  char* ws = (char*)d_ws;
  size_t off = 0;
  auto alloc = [&](size_t bytes) {
    char* p = ws + off;
    off += (bytes + 255) & ~(size_t)255;
    return p;
  };
  unsigned short* h_bf = (unsigned short*)alloc((size_t)T * D * 2);
  unsigned short* h2_bf = (unsigned short*)alloc((size_t)T * D * 2);
  unsigned short* attn_bf = (unsigned short*)alloc((size_t)T * NQ * H * 2);
  unsigned short* act_bf = (unsigned short*)alloc((size_t)T * F * 2);
  float* qf = (float*)alloc((size_t)T * NQ * H * 4);
  float* kf = (float*)alloc((size_t)T * NKV * H * 4);
  float* resid = (float*)alloc((size_t)T * D * 4);
  float* ctab = (float*)alloc((size_t)T * 64 * 4);
  float* stab = (float*)alloc((size_t)T * 64 * 4);
  // alias bf16 q/k/vt inside act_bf (dead until MLP phase)
  unsigned short* qbf = act_bf;                       // T*NQ*H
  unsigned short* kbf = qbf + (size_t)T * NQ * H;     // T*NKV*H
  unsigned short* vtbf = kbf + (size_t)T * NKV * H;   // NKV*H*T

  rmsnorm_kernel<<<T, 256, 0, stream>>>(x, ln1, h_bf);
  rope_table<<<(T * 64) / 256, 256, 0, stream>>>(positions, ctab, stab);
  gemm_kernel<0><<<dim3(T / 128, (NQ * H) / 128), 256, 0, stream>>>(
      h_bf, w_q, nullptr, nullptr, qf, nullptr, D, NQ * H);
  gemm_kernel<0><<<dim3(T / 128, (NKV * H) / 128), 256, 0, stream>>>(
      h_bf, w_k, nullptr, nullptr, kf, nullptr, D, NKV * H);
  gemm_kernel<3><<<dim3(T / 128, (NKV * H) / 128), 256, 0, stream>>>(
      h_bf, w_v, nullptr, nullptr, nullptr, vtbf, D, NKV * H);
  rope_bf16<<<(T * NQ * 64) / 256, 256, 0, stream>>>(qf, ctab, stab, qbf, NQ,
                                                     0.08838834764831845f);
  rope_bf16<<<(T * NKV * 64) / 256, 256, 0, stream>>>(kf, ctab, stab, kbf, NKV, 1.0f);
  flash_attn<<<dim3(T / 64, NQ), 256, 0, stream>>>(qbf, kbf, vtbf, attn_bf);
  gemm_kernel<1><<<dim3(T / 128, D / 128), 256, 0, stream>>>(
      attn_bf, w_o, nullptr, x, resid, nullptr, NQ * H, D);
  rmsnorm_kernel<<<T, 256, 0, stream>>>(resid, ln2, h2_bf);
  gemm_kernel<2><<<dim3(T / 128, F / 128), 256, 0, stream>>>(
      h2_bf, w_gate, w_up, nullptr, nullptr, act_bf, D, F);
  gemm_kernel<1><<<dim3(T / 128, D / 128), 256, 0, stream>>>(
      act_bf, w_down, nullptr, resid, out, nullptr, F, D);
}

// Round 3
// 2463.122 us; speedup vs baseline: 3.9299x; 2.1007x over previous
//
#include <hip/hip_runtime.h>

typedef __attribute__((ext_vector_type(8))) short bf16x8;
typedef __attribute__((ext_vector_type(4))) float f32x4;

constexpr int T = 2048;
constexpr int D = 4096;
constexpr int NQ = 32;    // query heads
constexpr int NKV = 8;    // kv heads
constexpr int H = 128;    // head dim
constexpr int F = 14336;  // ffn dim

__device__ inline unsigned short f2bf(float f) {
  unsigned u = __float_as_uint(f);
  return (unsigned short)((u + 0x7FFFu + ((u >> 16) & 1u)) >> 16);
}

__device__ inline void gload_lds16(const void* g, void* l) {
  __builtin_amdgcn_global_load_lds((const __attribute__((address_space(1))) void*)g,
                                   (__attribute__((address_space(3))) void*)l, 16, 0, 0);
}

// ---------------- weight transpose+convert: (K,N) f32 -> (N,K) bf16 ----------------
__global__ __launch_bounds__(256) void transpose_bf16(const float* __restrict__ in,
                                                      unsigned short* __restrict__ out,
                                                      int K, int N) {
  __shared__ float tile[64 * 65];
  const int kb = blockIdx.x * 64;
  const int nb = blockIdx.y * 64;
  const int tid = threadIdx.x;
  const int r = tid >> 2;          // 0..63
  const int c4 = tid & 3;          // 0..3 (16-col group)
#pragma unroll
  for (int i = 0; i < 4; ++i) {
    float4 v = *(const float4*)(in + (size_t)(kb + r) * N + nb + c4 * 16 + i * 4);
    *(float4*)&tile[r * 65 + c4 * 16 + i * 4] = v;
  }
  __syncthreads();
  // write out: row n = tid>>2, k-quad = tid&3 (16 k values)
  const int n = tid >> 2;
  const int kq = tid & 3;
#pragma unroll
  for (int half = 0; half < 2; ++half) {
    ushort4 o0, o1;
    int k0 = kq * 16 + half * 8;
    o0.x = f2bf(tile[(k0 + 0) * 65 + n]);
    o0.y = f2bf(tile[(k0 + 1) * 65 + n]);
    o0.z = f2bf(tile[(k0 + 2) * 65 + n]);
    o0.w = f2bf(tile[(k0 + 3) * 65 + n]);
    o1.x = f2bf(tile[(k0 + 4) * 65 + n]);
    o1.y = f2bf(tile[(k0 + 5) * 65 + n]);
    o1.z = f2bf(tile[(k0 + 6) * 65 + n]);
    o1.w = f2bf(tile[(k0 + 7) * 65 + n]);
    unsigned short* op = out + (size_t)(nb + n) * K + kb + k0;
    *(ushort4*)(op + 0) = o0;
    *(ushort4*)(op + 4) = o1;
  }
}

// ---------------- RMSNorm: f32 in -> bf16 out ----------------
__global__ __launch_bounds__(256) void rmsnorm_kernel(
    const float* __restrict__ in, const float* __restrict__ scale,
    unsigned short* __restrict__ out) {
  int row = blockIdx.x;
  const float4* xr = (const float4*)(in + (size_t)row * D);
  const float4* sr = (const float4*)scale;
  float4 vals[4];
  float ss = 0.f;
#pragma unroll
  for (int i = 0; i < 4; ++i) {
    float4 v = xr[threadIdx.x + i * 256];
    vals[i] = v;
    ss += v.x * v.x + v.y * v.y + v.z * v.z + v.w * v.w;
  }
#pragma unroll
  for (int off = 32; off; off >>= 1) ss += __shfl_xor(ss, off, 64);
  __shared__ float wsum[4];
  if ((threadIdx.x & 63) == 0) wsum[threadIdx.x >> 6] = ss;
  __syncthreads();
  float r = rsqrtf((wsum[0] + wsum[1] + wsum[2] + wsum[3]) * (1.f / D) + 1e-5f);
#pragma unroll
  for (int i = 0; i < 4; ++i) {
    int vi = threadIdx.x + i * 256;
    float4 v = vals[i];
    float4 s = sr[vi];
    ushort4 o;
    o.x = f2bf(v.x * r * s.x);
    o.y = f2bf(v.y * r * s.y);
    o.z = f2bf(v.z * r * s.z);
    o.w = f2bf(v.w * r * s.w);
    *(ushort4*)(out + (size_t)row * D + (size_t)vi * 4) = o;
  }
}

// ---------------- RoPE cos/sin table ----------------
__global__ __launch_bounds__(256) void rope_table(const int* __restrict__ pos,
                                                  float* __restrict__ ctab,
                                                  float* __restrict__ stab) {
  int idx = blockIdx.x * 256 + threadIdx.x;  // T*64
  int t = idx >> 6, i = idx & 63;
  float inv = exp2f(-(float)i * (log2f(500000.0f) / 64.0f));
  float ang = (float)pos[t] * inv;
  ctab[idx] = cosf(ang);
  stab[idx] = sinf(ang);
}

// ---------------- RoPE apply: f32 in -> bf16 out (scale folded) ----------------
__global__ __launch_bounds__(256) void rope_bf16(const float* __restrict__ x,
                                                 const float* __restrict__ ctab,
                                                 const float* __restrict__ stab,
                                                 unsigned short* __restrict__ out,
                                                 int nheads, float scale) {
  int idx = blockIdx.x * 256 + threadIdx.x;  // T*nheads*64
  int i = idx & 63;
  int tn = idx >> 6;
  int t = tn / nheads;
  float c = ctab[t * 64 + i], s = stab[t * 64 + i];
  const float* p = x + (size_t)tn * H;
  float x1 = p[i], x2 = p[i + 64];
  unsigned short* o = out + (size_t)tn * H;
  o[i] = f2bf((x1 * c - x2 * s) * scale);
  o[i + 64] = f2bf((x2 * c + x1 * s) * scale);
}

// ---------------- GEMM: A bf16 (M,K), Bt bf16 (N,K) -> epilogue ----------------
// EP 0: outF = acc            (f32)
// EP 1: outF = acc + addend   (f32)
// EP 2: dual-B; outB = bf16(silu(acc_B0) * acc_B1)
// EP 3: outB[col*T + row] = bf16(acc)   (transposed bf16 write, M==T)
template <int EP>
__global__ __launch_bounds__(256) void gemm_bf(
    const unsigned short* __restrict__ A, const unsigned short* __restrict__ Bt0,
    const unsigned short* __restrict__ Bt1, const float* __restrict__ addend,
    float* __restrict__ outF, unsigned short* __restrict__ outB, int Kd, int Nd) {
  __shared__ unsigned short lA[128 * 32];
  __shared__ unsigned short lB0[128 * 32];
  __shared__ unsigned short lB1[(EP == 2) ? 128 * 32 : 8];

  const int tid = threadIdx.x;
  const int m0 = blockIdx.x * 128;
  const int n0 = blockIdx.y * 128;
  const int lane = tid & 63;
  const int wv = tid >> 6;

  f32x4 acc[4][4];
  f32x4 acc1[(EP == 2) ? 4 : 1][(EP == 2) ? 4 : 1];
#pragma unroll
  for (int i = 0; i < 4; ++i)
#pragma unroll
    for (int j = 0; j < 4; ++j) {
      acc[i][j] = (f32x4){0.f, 0.f, 0.f, 0.f};
      if constexpr (EP == 2) acc1[i][j] = (f32x4){0.f, 0.f, 0.f, 0.f};
    }

  const int wr = (wv >> 1) * 64;  // wave row offset in tile
  const int wc = (wv & 1) * 64;   // wave col offset in tile
  const int k8 = (lane >> 4) * 8;
  const int rl = lane & 15;

  // staging map for global_load_lds: wave wv, iter it covers ushort idx
  // [wv*512 + it*2048 + lane*8 .. +7]  (tile is 128 rows x 32 cols, linear)
  const int sidx0 = wv * 512 + lane * 8;

  for (int k0 = 0; k0 < Kd; k0 += 32) {
    __syncthreads();
#pragma unroll
    for (int it = 0; it < 2; ++it) {
      int idx = sidx0 + it * 2048;
      int row = idx >> 5, kk = idx & 31;
      int base = wv * 512 + it * 2048;
      gload_lds16(A + (size_t)(m0 + row) * Kd + k0 + kk, &lA[base]);
      gload_lds16(Bt0 + (size_t)(n0 + row) * Kd + k0 + kk, &lB0[base]);
      if constexpr (EP == 2)
        gload_lds16(Bt1 + (size_t)(n0 + row) * Kd + k0 + kk, &lB1[base]);
    }
    asm volatile("s_waitcnt vmcnt(0)" ::: "memory");
    __syncthreads();

    bf16x8 af[4], bfr[4], bfr1[(EP == 2) ? 4 : 1];
#pragma unroll
    for (int i = 0; i < 4; ++i)
      af[i] = *(const bf16x8*)&lA[(wr + i * 16 + rl) * 32 + k8];
#pragma unroll
    for (int j = 0; j < 4; ++j) {
      bfr[j] = *(const bf16x8*)&lB0[(wc + j * 16 + rl) * 32 + k8];
      if constexpr (EP == 2)
        bfr1[j] = *(const bf16x8*)&lB1[(wc + j * 16 + rl) * 32 + k8];
    }
#pragma unroll
    for (int i = 0; i < 4; ++i)
#pragma unroll
      for (int j = 0; j < 4; ++j) {
        acc[i][j] =
            __builtin_amdgcn_mfma_f32_16x16x32_bf16(af[i], bfr[j], acc[i][j], 0, 0, 0);
        if constexpr (EP == 2)
          acc1[i][j] = __builtin_amdgcn_mfma_f32_16x16x32_bf16(af[i], bfr1[j],
                                                               acc1[i][j], 0, 0, 0);
      }
  }

  const int rb = (lane >> 4) * 4;
#pragma unroll
  for (int i = 0; i < 4; ++i)
#pragma unroll
    for (int j = 0; j < 4; ++j) {
      if constexpr (EP == 3) {
        int row0 = m0 + wr + i * 16 + rb;
        int col = n0 + wc + j * 16 + rl;
        ushort4 o;
        o.x = f2bf(acc[i][j][0]);
        o.y = f2bf(acc[i][j][1]);
        o.z = f2bf(acc[i][j][2]);
        o.w = f2bf(acc[i][j][3]);
        *(ushort4*)&outB[(size_t)col * T + row0] = o;
      } else {
#pragma unroll
        for (int jj = 0; jj < 4; ++jj) {
          int row = m0 + wr + i * 16 + rb + jj;
          int col = n0 + wc + j * 16 + rl;
          size_t idx = (size_t)row * Nd + col;
          float val = acc[i][j][jj];
          if constexpr (EP == 0) {
            outF[idx] = val;
          } else if constexpr (EP == 1) {
            outF[idx] = val + addend[idx];
          } else if constexpr (EP == 2) {
            float g = val;
            float u = acc1[i][j][jj];
            float a = g / (1.f + __expf(-g)) * u;
            outB[idx] = f2bf(a);
          }
        }
      }
    }
}

// ---------------- Flash attention (MFMA) ----------------
constexpr int KLD = 136;  // K_lds row stride (bf16)
constexpr int VLD = 72;   // Vt_lds row stride
constexpr int PLD = 72;   // P_lds row stride

__global__ __launch_bounds__(256) void flash_attn(
    const unsigned short* __restrict__ qbf, const unsigned short* __restrict__ kbf,
    const unsigned short* __restrict__ vtbf, unsigned short* __restrict__ out) {
  __shared__ unsigned short K_lds[64 * KLD];
  __shared__ unsigned short Vt_lds[H * VLD];
  __shared__ unsigned short P_lds[4 * 16 * PLD];

  const int tid = threadIdx.x;
  const int lane = tid & 63;
  const int wave = tid >> 6;
  const int qb = blockIdx.x;
  const int n = blockIdx.y;
  const int kvh = n >> 2;
  const int g = lane >> 4;
  const int rl = lane & 15;
  const int qrow = qb * 64 + wave * 16;

  bf16x8 qfrag[4];
  {
    const unsigned short* qp = qbf + ((size_t)(qrow + rl) * NQ + n) * H + g * 8;
#pragma unroll
    for (int ks = 0; ks < 4; ++ks) qfrag[ks] = *(const bf16x8*)(qp + ks * 32);
  }

  f32x4 oacc[8];
#pragma unroll
  for (int ob = 0; ob < 8; ++ob) oacc[ob] = (f32x4){0.f, 0.f, 0.f, 0.f};
  float mrun[4] = {-1e30f, -1e30f, -1e30f, -1e30f};
  float lrun[4] = {0.f, 0.f, 0.f, 0.f};

  const int krow = tid >> 2, kseg = (tid & 3) * 32;
  const int vh = tid >> 1, vseg = (tid & 1) * 32;

  for (int kt = 0; kt <= qb; ++kt) {
    const int kbase = kt * 64;
    __syncthreads();
    {
      const unsigned short* kp = kbf + ((size_t)(kbase + krow) * NKV + kvh) * H + kseg;
#pragma unroll
      for (int i = 0; i < 4; ++i)
        *(bf16x8*)&K_lds[krow * KLD + kseg + i * 8] = *(const bf16x8*)(kp + i * 8);
      const unsigned short* vp = vtbf + (size_t)(kvh * H + vh) * T + kbase + vseg;
#pragma unroll
      for (int i = 0; i < 4; ++i)
        *(bf16x8*)&Vt_lds[vh * VLD + vseg + i * 8] = *(const bf16x8*)(vp + i * 8);
    }
    __syncthreads();

    f32x4 sacc[4];
#pragma unroll
    for (int cb = 0; cb < 4; ++cb) sacc[cb] = (f32x4){0.f, 0.f, 0.f, 0.f};
#pragma unroll
    for (int cb = 0; cb < 4; ++cb)
#pragma unroll
      for (int ks = 0; ks < 4; ++ks) {
        bf16x8 kf = *(const bf16x8*)&K_lds[(cb * 16 + rl) * KLD + ks * 32 + g * 8];
        sacc[cb] = __builtin_amdgcn_mfma_f32_16x16x32_bf16(qfrag[ks], kf, sacc[cb], 0, 0, 0);
      }

    if (kt == qb) {
#pragma unroll
      for (int cb = 0; cb < 4; ++cb) {
        int kvg = cb * 16 + rl;
#pragma unroll
        for (int r = 0; r < 4; ++r) {
          int qrel = wave * 16 + g * 4 + r;
          if (kvg > qrel) sacc[cb][r] = -1e30f;
        }
      }
    }

    float mx[4], sm[4], corr[4];
#pragma unroll
    for (int r = 0; r < 4; ++r) {
      float m0 = fmaxf(fmaxf(sacc[0][r], sacc[1][r]), fmaxf(sacc[2][r], sacc[3][r]));
#pragma unroll
      for (int off = 1; off < 16; off <<= 1) m0 = fmaxf(m0, __shfl_xor(m0, off, 64));
      float nm = fmaxf(mrun[r], m0);
      corr[r] = __expf(mrun[r] - nm);
      mrun[r] = nm;
      mx[r] = nm;
    }
#pragma unroll
    for (int cb = 0; cb < 4; ++cb)
#pragma unroll
      for (int r = 0; r < 4; ++r) sacc[cb][r] = __expf(sacc[cb][r] - mx[r]);
#pragma unroll
    for (int r = 0; r < 4; ++r) {
      float s0 = sacc[0][r] + sacc[1][r] + sacc[2][r] + sacc[3][r];
#pragma unroll
      for (int off = 1; off < 16; off <<= 1) s0 += __shfl_xor(s0, off, 64);
      sm[r] = s0;
      lrun[r] = lrun[r] * corr[r] + sm[r];
    }
#pragma unroll
    for (int ob = 0; ob < 8; ++ob)
#pragma unroll
      for (int r = 0; r < 4; ++r) oacc[ob][r] *= corr[r];

#pragma unroll
    for (int cb = 0; cb < 4; ++cb)
#pragma unroll
      for (int r = 0; r < 4; ++r)
        P_lds[(wave * 16 + g * 4 + r) * PLD + cb * 16 + rl] = f2bf(sacc[cb][r]);

    bf16x8 pa[2];
#pragma unroll
    for (int ks = 0; ks < 2; ++ks)
      pa[ks] = *(const bf16x8*)&P_lds[(wave * 16 + rl) * PLD + ks * 32 + g * 8];

#pragma unroll
    for (int ob = 0; ob < 8; ++ob)
#pragma unroll
      for (int ks = 0; ks < 2; ++ks) {
        bf16x8 vf = *(const bf16x8*)&Vt_lds[(ob * 16 + rl) * VLD + ks * 32 + g * 8];
        oacc[ob] = __builtin_amdgcn_mfma_f32_16x16x32_bf16(pa[ks], vf, oacc[ob], 0, 0, 0);
      }
  }

  float inv[4];
#pragma unroll
  for (int r = 0; r < 4; ++r) inv[r] = 1.f / lrun[r];
#pragma unroll
  for (int ob = 0; ob < 8; ++ob)
#pragma unroll
    for (int r = 0; r < 4; ++r) {
      int t = qrow + g * 4 + r;
      out[((size_t)t * NQ + n) * H + ob * 16 + rl] = f2bf(oacc[ob][r] * inv[r]);
    }
}

extern "C" void kernel_launch(void* const* d_in, const int* in_sizes, int n_in,
                              void* d_out, int out_size, void* d_ws, size_t ws_size,
                              hipStream_t stream) {
  (void)in_sizes; (void)n_in; (void)out_size; (void)ws_size;
  const float* x = (const float*)d_in[0];
  const int* positions = (const int*)d_in[1];
  const float* ln1 = (const float*)d_in[2];
  const float* w_q = (const float*)d_in[3];
  const float* w_k = (const float*)d_in[4];
  const float* w_v = (const float*)d_in[5];
  const float* w_o = (const float*)d_in[6];
  const float* ln2 = (const float*)d_in[7];
  const float* w_gate = (const float*)d_in[8];
  const float* w_up = (const float*)d_in[9];
  const float* w_down = (const float*)d_in[10];
  float* out = (float*)d_out;

  char* ws = (char*)d_ws;
  size_t off = 0;
  auto alloc = [&](size_t bytes) {
    char* p = ws + off;
    off += (bytes + 255) & ~(size_t)255;
    return p;
  };
  unsigned short* h_bf = (unsigned short*)alloc((size_t)T * D * 2);
  unsigned short* h2_bf = (unsigned short*)alloc((size_t)T * D * 2);
  unsigned short* attn_bf = (unsigned short*)alloc((size_t)T * NQ * H * 2);
  unsigned short* act_bf = (unsigned short*)alloc((size_t)T * F * 2);
  float* qf = (float*)alloc((size_t)T * NQ * H * 4);
  float* kf = (float*)alloc((size_t)T * NKV * H * 4);
  float* resid = (float*)alloc((size_t)T * D * 4);
  float* ctab = (float*)alloc((size_t)T * 64 * 4);
  float* stab = (float*)alloc((size_t)T * 64 * 4);
  // bf16 transposed weights
  unsigned short* wqt = (unsigned short*)alloc((size_t)D * NQ * H * 2);
  unsigned short* wkt = (unsigned short*)alloc((size_t)D * NKV * H * 2);
  unsigned short* wvt = (unsigned short*)alloc((size_t)D * NKV * H * 2);
  unsigned short* wot = (unsigned short*)alloc((size_t)NQ * H * D * 2);
  unsigned short* wgt = (unsigned short*)alloc((size_t)D * F * 2);
  unsigned short* wut = (unsigned short*)alloc((size_t)D * F * 2);
  unsigned short* wdt = (unsigned short*)alloc((size_t)F * D * 2);
  // alias bf16 q/k/vt inside act_bf (dead until MLP phase)
  unsigned short* qbf = act_bf;                       // T*NQ*H
  unsigned short* kbf = qbf + (size_t)T * NQ * H;     // T*NKV*H
  unsigned short* vtbf = kbf + (size_t)T * NKV * H;   // NKV*H*T

  // weight transposes (f32 (K,N) -> bf16 (N,K))
  transpose_bf16<<<dim3(D / 64, (NQ * H) / 64), 256, 0, stream>>>(w_q, wqt, D, NQ * H);
  transpose_bf16<<<dim3(D / 64, (NKV * H) / 64), 256, 0, stream>>>(w_k, wkt, D, NKV * H);
  transpose_bf16<<<dim3(D / 64, (NKV * H) / 64), 256, 0, stream>>>(w_v, wvt, D, NKV * H);
  transpose_bf16<<<dim3((NQ * H) / 64, D / 64), 256, 0, stream>>>(w_o, wot, NQ * H, D);
  transpose_bf16<<<dim3(D / 64, F / 64), 256, 0, stream>>>(w_gate, wgt, D, F);
  transpose_bf16<<<dim3(D / 64, F / 64), 256, 0, stream>>>(w_up, wut, D, F);
  transpose_bf16<<<dim3(F / 64, D / 64), 256, 0, stream>>>(w_down, wdt, F, D);

  rmsnorm_kernel<<<T, 256, 0, stream>>>(x, ln1, h_bf);
  rope_table<<<(T * 64) / 256, 256, 0, stream>>>(positions, ctab, stab);
  gemm_bf<0><<<dim3(T / 128, (NQ * H) / 128), 256, 0, stream>>>(
      h_bf, wqt, nullptr, nullptr, qf, nullptr, D, NQ * H);
  gemm_bf<0><<<dim3(T / 128, (NKV * H) / 128), 256, 0, stream>>>(
      h_bf, wkt, nullptr, nullptr, kf, nullptr, D, NKV * H);
  gemm_bf<3><<<dim3(T / 128, (NKV * H) / 128), 256, 0, stream>>>(
      h_bf, wvt, nullptr, nullptr, nullptr, vtbf, D, NKV * H);
  rope_bf16<<<(T * NQ * 64) / 256, 256, 0, stream>>>(qf, ctab, stab, qbf, NQ,
                                                     0.08838834764831845f);
  rope_bf16<<<(T * NKV * 64) / 256, 256, 0, stream>>>(kf, ctab, stab, kbf, NKV, 1.0f);
  flash_attn<<<dim3(T / 64, NQ), 256, 0, stream>>>(qbf, kbf, vtbf, attn_bf);
  gemm_bf<1><<<dim3(T / 128, D / 128), 256, 0, stream>>>(
      attn_bf, wot, nullptr, x, resid, nullptr, NQ * H, D);
  rmsnorm_kernel<<<T, 256, 0, stream>>>(resid, ln2, h2_bf);
  gemm_bf<2><<<dim3(T / 128, F / 128), 256, 0, stream>>>(
      h2_bf, wgt, wut, nullptr, nullptr, act_bf, D, F);
  gemm_bf<1><<<dim3(T / 128, D / 128), 256, 0, stream>>>(
      act_bf, wdt, nullptr, resid, out, nullptr, F, D);
}

// Round 4
// 1814.353 us; speedup vs baseline: 5.3352x; 1.3576x over previous
//
#include <hip/hip_runtime.h>

typedef __attribute__((ext_vector_type(8))) short bf16x8;
typedef __attribute__((ext_vector_type(4))) float f32x4;

constexpr int T = 2048;
constexpr int D = 4096;
constexpr int NQ = 32;    // query heads
constexpr int NKV = 8;    // kv heads
constexpr int H = 128;    // head dim
constexpr int F = 14336;  // ffn dim
constexpr int NQKV = (NQ + 2 * NKV) * H;  // 6144 packed qkv cols
constexpr int VOFF = (NQ + NKV) * H;      // 5120 col offset of V

__device__ inline unsigned short f2bf(float f) {
  unsigned u = __float_as_uint(f);
  return (unsigned short)((u + 0x7FFFu + ((u >> 16) & 1u)) >> 16);
}

__device__ inline void gload_lds16(const void* g, void* l) {
  __builtin_amdgcn_global_load_lds((const __attribute__((address_space(1))) void*)g,
                                   (__attribute__((address_space(3))) void*)l, 16, 0, 0);
}

// ------- weight transpose+convert: (K,N) f32 -> (rowmap(N),K) bf16 -------
// MODE 0: row = n;  MODE 1: row = (n>>4)*32 + (n&15);  MODE 2: MODE1 + 16
template <int MODE>
__global__ __launch_bounds__(256) void transpose_bf16(const float* __restrict__ in,
                                                      unsigned short* __restrict__ out,
                                                      int K, int N) {
  __shared__ float tile[64 * 65];
  const int kb = blockIdx.x * 64;
  const int nb = blockIdx.y * 64;
  const int tid = threadIdx.x;
  const int r = tid >> 2;
  const int c4 = tid & 3;
#pragma unroll
  for (int i = 0; i < 4; ++i) {
    float4 v = *(const float4*)(in + (size_t)(kb + r) * N + nb + c4 * 16 + i * 4);
    *(float4*)&tile[r * 65 + c4 * 16 + i * 4] = v;
  }
  __syncthreads();
  const int n = tid >> 2;
  const int kq = tid & 3;
  int nsrc = nb + n;
  int prow = (MODE == 0) ? nsrc : ((nsrc >> 4) * 32 + (nsrc & 15) + (MODE == 2 ? 16 : 0));
#pragma unroll
  for (int half = 0; half < 2; ++half) {
    ushort4 o0, o1;
    int k0 = kq * 16 + half * 8;
    o0.x = f2bf(tile[(k0 + 0) * 65 + n]);
    o0.y = f2bf(tile[(k0 + 1) * 65 + n]);
    o0.z = f2bf(tile[(k0 + 2) * 65 + n]);
    o0.w = f2bf(tile[(k0 + 3) * 65 + n]);
    o1.x = f2bf(tile[(k0 + 4) * 65 + n]);
    o1.y = f2bf(tile[(k0 + 5) * 65 + n]);
    o1.z = f2bf(tile[(k0 + 6) * 65 + n]);
    o1.w = f2bf(tile[(k0 + 7) * 65 + n]);
    unsigned short* op = out + (size_t)prow * K + kb + k0;
    *(ushort4*)(op + 0) = o0;
    *(ushort4*)(op + 4) = o1;
  }
}

// ---------------- RMSNorm: f32 in -> bf16 out ----------------
__global__ __launch_bounds__(256) void rmsnorm_kernel(
    const float* __restrict__ in, const float* __restrict__ scale,
    unsigned short* __restrict__ out) {
  int row = blockIdx.x;
  const float4* xr = (const float4*)(in + (size_t)row * D);
  const float4* sr = (const float4*)scale;
  float4 vals[4];
  float ss = 0.f;
#pragma unroll
  for (int i = 0; i < 4; ++i) {
    float4 v = xr[threadIdx.x + i * 256];
    vals[i] = v;
    ss += v.x * v.x + v.y * v.y + v.z * v.z + v.w * v.w;
  }
#pragma unroll
  for (int off = 32; off; off >>= 1) ss += __shfl_xor(ss, off, 64);
  __shared__ float wsum[4];
  if ((threadIdx.x & 63) == 0) wsum[threadIdx.x >> 6] = ss;
  __syncthreads();
  float r = rsqrtf((wsum[0] + wsum[1] + wsum[2] + wsum[3]) * (1.f / D) + 1e-5f);
#pragma unroll
  for (int i = 0; i < 4; ++i) {
    int vi = threadIdx.x + i * 256;
    float4 v = vals[i];
    float4 s = sr[vi];
    ushort4 o;
    o.x = f2bf(v.x * r * s.x);
    o.y = f2bf(v.y * r * s.y);
    o.z = f2bf(v.z * r * s.z);
    o.w = f2bf(v.w * r * s.w);
    *(ushort4*)(out + (size_t)row * D + (size_t)vi * 4) = o;
  }
}

// ---------------- RoPE cos/sin table ----------------
__global__ __launch_bounds__(256) void rope_table(const int* __restrict__ pos,
                                                  float* __restrict__ ctab,
                                                  float* __restrict__ stab) {
  int idx = blockIdx.x * 256 + threadIdx.x;  // T*64
  int t = idx >> 6, i = idx & 63;
  float inv = exp2f(-(float)i * (log2f(500000.0f) / 64.0f));
  float ang = (float)pos[t] * inv;
  ctab[idx] = cosf(ang);
  stab[idx] = sinf(ang);
}

// ------- RoPE apply: f32 strided in -> bf16 out (scale folded) -------
__global__ __launch_bounds__(256) void rope_bf16(const float* __restrict__ x,
                                                 const float* __restrict__ ctab,
                                                 const float* __restrict__ stab,
                                                 unsigned short* __restrict__ out,
                                                 int nheads, int row_stride, float scale) {
  int idx = blockIdx.x * 256 + threadIdx.x;  // T*nheads*64
  int i = idx & 63;
  int tn = idx >> 6;
  int t = tn / nheads;
  int n = tn - t * nheads;
  float c = ctab[t * 64 + i], s = stab[t * 64 + i];
  const float* p = x + (size_t)t * row_stride + n * H;
  float x1 = p[i], x2 = p[i + 64];
  unsigned short* o = out + (size_t)tn * H;
  o[i] = f2bf((x1 * c - x2 * s) * scale);
  o[i + 64] = f2bf((x2 * c + x1 * s) * scale);
}

// ---------------- GEMM: A bf16 (M,K), Bt bf16 (N,K) -> epilogue ----------------
// EP 1: outF = acc + addend                        (f32)
// EP 4: qkv: cols<VOFF -> outF f32 (stride Nd); cols>=VOFF -> outB[(c-VOFF)*T+row] bf16
// EP 5: interleaved gate/up: outB[row*F + acol] = bf16(silu(g)*u)
template <int EP>
__global__ __launch_bounds__(256) void gemm_bf(
    const unsigned short* __restrict__ A, const unsigned short* __restrict__ Bt0,
    const float* __restrict__ addend, float* __restrict__ outF,
    unsigned short* __restrict__ outB, int Kd, int Nd) {
  __shared__ unsigned short lA[128 * 32];
  __shared__ unsigned short lB0[128 * 32];

  const int tid = threadIdx.x;
  const int m0 = blockIdx.x * 128;
  const int n0 = blockIdx.y * 128;
  const int lane = tid & 63;
  const int wv = tid >> 6;

  f32x4 acc[4][4];
#pragma unroll
  for (int i = 0; i < 4; ++i)
#pragma unroll
    for (int j = 0; j < 4; ++j) acc[i][j] = (f32x4){0.f, 0.f, 0.f, 0.f};

  const int wr = (wv >> 1) * 64;
  const int wc = (wv & 1) * 64;
  const int k8 = (lane >> 4) * 8;
  const int rl = lane & 15;
  const int sidx0 = wv * 512 + lane * 8;

  for (int k0 = 0; k0 < Kd; k0 += 32) {
    __syncthreads();
#pragma unroll
    for (int it = 0; it < 2; ++it) {
      int idx = sidx0 + it * 2048;
      int row = idx >> 5, kk = idx & 31;
      int base = wv * 512 + it * 2048;
      gload_lds16(A + (size_t)(m0 + row) * Kd + k0 + kk, &lA[base]);
      gload_lds16(Bt0 + (size_t)(n0 + row) * Kd + k0 + kk, &lB0[base]);
    }
    asm volatile("s_waitcnt vmcnt(0)" ::: "memory");
    __syncthreads();

    bf16x8 af[4], bfr[4];
#pragma unroll
    for (int i = 0; i < 4; ++i)
      af[i] = *(const bf16x8*)&lA[(wr + i * 16 + rl) * 32 + k8];
#pragma unroll
    for (int j = 0; j < 4; ++j)
      bfr[j] = *(const bf16x8*)&lB0[(wc + j * 16 + rl) * 32 + k8];
#pragma unroll
    for (int i = 0; i < 4; ++i)
#pragma unroll
      for (int j = 0; j < 4; ++j)
        acc[i][j] =
            __builtin_amdgcn_mfma_f32_16x16x32_bf16(af[i], bfr[j], acc[i][j], 0, 0, 0);
  }

  const int rb = (lane >> 4) * 4;
  if constexpr (EP == 5) {
    // interleaved gate/up: j even = gate frag, j+1 = up frag of same act cols
#pragma unroll
    for (int i = 0; i < 4; ++i)
#pragma unroll
      for (int jp = 0; jp < 4; jp += 2) {
        int acol = ((n0 + wc) >> 1) + (jp >> 1) * 16 + rl;
#pragma unroll
        for (int jj = 0; jj < 4; ++jj) {
          int row = m0 + wr + i * 16 + rb + jj;
          float g = acc[i][jp][jj];
          float u = acc[i][jp + 1][jj];
          float a = g / (1.f + __expf(-g)) * u;
          outB[(size_t)row * F + acol] = f2bf(a);
        }
      }
  } else {
#pragma unroll
    for (int i = 0; i < 4; ++i)
#pragma unroll
      for (int j = 0; j < 4; ++j) {
        int col = n0 + wc + j * 16 + rl;
        if (EP == 4 && n0 >= VOFF) {
          int row0 = m0 + wr + i * 16 + rb;
          ushort4 o;
          o.x = f2bf(acc[i][j][0]);
          o.y = f2bf(acc[i][j][1]);
          o.z = f2bf(acc[i][j][2]);
          o.w = f2bf(acc[i][j][3]);
          *(ushort4*)&outB[(size_t)(col - VOFF) * T + row0] = o;
        } else {
#pragma unroll
          for (int jj = 0; jj < 4; ++jj) {
            int row = m0 + wr + i * 16 + rb + jj;
            size_t idx = (size_t)row * Nd + col;
            float val = acc[i][j][jj];
            if constexpr (EP == 1) {
              outF[idx] = val + addend[idx];
            } else {
              outF[idx] = val;
            }
          }
        }
      }
  }
}

// ---------------- Flash attention (MFMA) ----------------
constexpr int KLD = 136;
constexpr int VLD = 72;
constexpr int PLD = 72;

__global__ __launch_bounds__(256) void flash_attn(
    const unsigned short* __restrict__ qbf, const unsigned short* __restrict__ kbf,
    const unsigned short* __restrict__ vtbf, unsigned short* __restrict__ out) {
  __shared__ unsigned short K_lds[64 * KLD];
  __shared__ unsigned short Vt_lds[H * VLD];
  __shared__ unsigned short P_lds[4 * 16 * PLD];

  const int tid = threadIdx.x;
  const int lane = tid & 63;
  const int wave = tid >> 6;
  const int qb = blockIdx.x;
  const int n = blockIdx.y;
  const int kvh = n >> 2;
  const int g = lane >> 4;
  const int rl = lane & 15;
  const int qrow = qb * 64 + wave * 16;

  bf16x8 qfrag[4];
  {
    const unsigned short* qp = qbf + ((size_t)(qrow + rl) * NQ + n) * H + g * 8;
#pragma unroll
    for (int ks = 0; ks < 4; ++ks) qfrag[ks] = *(const bf16x8*)(qp + ks * 32);
  }

  f32x4 oacc[8];
#pragma unroll
  for (int ob = 0; ob < 8; ++ob) oacc[ob] = (f32x4){0.f, 0.f, 0.f, 0.f};
  float mrun[4] = {-1e30f, -1e30f, -1e30f, -1e30f};
  float lrun[4] = {0.f, 0.f, 0.f, 0.f};

  const int krow = tid >> 2, kseg = (tid & 3) * 32;
  const int vh = tid >> 1, vseg = (tid & 1) * 32;

  for (int kt = 0; kt <= qb; ++kt) {
    const int kbase = kt * 64;
    __syncthreads();
    {
      const unsigned short* kp = kbf + ((size_t)(kbase + krow) * NKV + kvh) * H + kseg;
#pragma unroll
      for (int i = 0; i < 4; ++i)
        *(bf16x8*)&K_lds[krow * KLD + kseg + i * 8] = *(const bf16x8*)(kp + i * 8);
      const unsigned short* vp = vtbf + (size_t)(kvh * H + vh) * T + kbase + vseg;
#pragma unroll
      for (int i = 0; i < 4; ++i)
        *(bf16x8*)&Vt_lds[vh * VLD + vseg + i * 8] = *(const bf16x8*)(vp + i * 8);
    }
    __syncthreads();

    f32x4 sacc[4];
#pragma unroll
    for (int cb = 0; cb < 4; ++cb) sacc[cb] = (f32x4){0.f, 0.f, 0.f, 0.f};
#pragma unroll
    for (int cb = 0; cb < 4; ++cb)
#pragma unroll
      for (int ks = 0; ks < 4; ++ks) {
        bf16x8 kf = *(const bf16x8*)&K_lds[(cb * 16 + rl) * KLD + ks * 32 + g * 8];
        sacc[cb] = __builtin_amdgcn_mfma_f32_16x16x32_bf16(qfrag[ks], kf, sacc[cb], 0, 0, 0);
      }

    if (kt == qb) {
#pragma unroll
      for (int cb = 0; cb < 4; ++cb) {
        int kvg = cb * 16 + rl;
#pragma unroll
        for (int r = 0; r < 4; ++r) {
          int qrel = wave * 16 + g * 4 + r;
          if (kvg > qrel) sacc[cb][r] = -1e30f;
        }
      }
    }

    float mx[4], sm[4], corr[4];
#pragma unroll
    for (int r = 0; r < 4; ++r) {
      float m0 = fmaxf(fmaxf(sacc[0][r], sacc[1][r]), fmaxf(sacc[2][r], sacc[3][r]));
#pragma unroll
      for (int off = 1; off < 16; off <<= 1) m0 = fmaxf(m0, __shfl_xor(m0, off, 64));
      float nm = fmaxf(mrun[r], m0);
      corr[r] = __expf(mrun[r] - nm);
      mrun[r] = nm;
      mx[r] = nm;
    }
#pragma unroll
    for (int cb = 0; cb < 4; ++cb)
#pragma unroll
      for (int r = 0; r < 4; ++r) sacc[cb][r] = __expf(sacc[cb][r] - mx[r]);
#pragma unroll
    for (int r = 0; r < 4; ++r) {
      float s0 = sacc[0][r] + sacc[1][r] + sacc[2][r] + sacc[3][r];
#pragma unroll
      for (int off = 1; off < 16; off <<= 1) s0 += __shfl_xor(s0, off, 64);
      sm[r] = s0;
      lrun[r] = lrun[r] * corr[r] + sm[r];
    }
#pragma unroll
    for (int ob = 0; ob < 8; ++ob)
#pragma unroll
      for (int r = 0; r < 4; ++r) oacc[ob][r] *= corr[r];

#pragma unroll
    for (int cb = 0; cb < 4; ++cb)
#pragma unroll
      for (int r = 0; r < 4; ++r)
        P_lds[(wave * 16 + g * 4 + r) * PLD + cb * 16 + rl] = f2bf(sacc[cb][r]);

    bf16x8 pa[2];
#pragma unroll
    for (int ks = 0; ks < 2; ++ks)
      pa[ks] = *(const bf16x8*)&P_lds[(wave * 16 + rl) * PLD + ks * 32 + g * 8];

#pragma unroll
    for (int ob = 0; ob < 8; ++ob)
#pragma unroll
      for (int ks = 0; ks < 2; ++ks) {
        bf16x8 vf = *(const bf16x8*)&Vt_lds[(ob * 16 + rl) * VLD + ks * 32 + g * 8];
        oacc[ob] = __builtin_amdgcn_mfma_f32_16x16x32_bf16(pa[ks], vf, oacc[ob], 0, 0, 0);
      }
  }

  float inv[4];
#pragma unroll
  for (int r = 0; r < 4; ++r) inv[r] = 1.f / lrun[r];
#pragma unroll
  for (int ob = 0; ob < 8; ++ob)
#pragma unroll
    for (int r = 0; r < 4; ++r) {
      int t = qrow + g * 4 + r;
      out[((size_t)t * NQ + n) * H + ob * 16 + rl] = f2bf(oacc[ob][r] * inv[r]);
    }
}

extern "C" void kernel_launch(void* const* d_in, const int* in_sizes, int n_in,
                              void* d_out, int out_size, void* d_ws, size_t ws_size,
                              hipStream_t stream) {
  (void)in_sizes; (void)n_in; (void)out_size; (void)ws_size;
  const float* x = (const float*)d_in[0];
  const int* positions = (const int*)d_in[1];
  const float* ln1 = (const float*)d_in[2];
  const float* w_q = (const float*)d_in[3];
  const float* w_k = (const float*)d_in[4];
  const float* w_v = (const float*)d_in[5];
  const float* w_o = (const float*)d_in[6];
  const float* ln2 = (const float*)d_in[7];
  const float* w_gate = (const float*)d_in[8];
  const float* w_up = (const float*)d_in[9];
  const float* w_down = (const float*)d_in[10];
  float* out = (float*)d_out;

  char* ws = (char*)d_ws;
  size_t off = 0;
  auto alloc = [&](size_t bytes) {
    char* p = ws + off;
    off += (bytes + 255) & ~(size_t)255;
    return p;
  };
  unsigned short* h_bf = (unsigned short*)alloc((size_t)T * D * 2);
  unsigned short* h2_bf = (unsigned short*)alloc((size_t)T * D * 2);
  unsigned short* attn_bf = (unsigned short*)alloc((size_t)T * NQ * H * 2);
  unsigned short* act_bf = (unsigned short*)alloc((size_t)T * F * 2);
  float* qkvf = (float*)alloc((size_t)T * NQKV * 4);
  float* resid = (float*)alloc((size_t)T * D * 4);
  float* ctab = (float*)alloc((size_t)T * 64 * 4);
  float* stab = (float*)alloc((size_t)T * 64 * 4);
  unsigned short* qbf = (unsigned short*)alloc((size_t)T * NQ * H * 2);
  unsigned short* kbf = (unsigned short*)alloc((size_t)T * NKV * H * 2);
  unsigned short* vtbf = (unsigned short*)alloc((size_t)NKV * H * T * 2);
  // packed transposed bf16 weights
  unsigned short* wqkvt = (unsigned short*)alloc((size_t)NQKV * D * 2);      // q|k|v rows
  unsigned short* wot = (unsigned short*)alloc((size_t)D * NQ * H * 2);      // (D, 4096)
  unsigned short* wgut = (unsigned short*)alloc((size_t)2 * F * D * 2);      // interleaved
  unsigned short* wdt = (unsigned short*)alloc((size_t)D * F * 2);           // (D, F)

  // weight transposes
  transpose_bf16<0><<<dim3(D / 64, (NQ * H) / 64), 256, 0, stream>>>(w_q, wqkvt, D, NQ * H);
  transpose_bf16<0><<<dim3(D / 64, (NKV * H) / 64), 256, 0, stream>>>(
      w_k, wqkvt + (size_t)NQ * H * D, D, NKV * H);
  transpose_bf16<0><<<dim3(D / 64, (NKV * H) / 64), 256, 0, stream>>>(
      w_v, wqkvt + (size_t)VOFF * D, D, NKV * H);
  transpose_bf16<0><<<dim3((NQ * H) / 64, D / 64), 256, 0, stream>>>(w_o, wot, NQ * H, D);
  transpose_bf16<1><<<dim3(D / 64, F / 64), 256, 0, stream>>>(w_gate, wgut, D, F);
  transpose_bf16<2><<<dim3(D / 64, F / 64), 256, 0, stream>>>(w_up, wgut, D, F);
  transpose_bf16<0><<<dim3(F / 64, D / 64), 256, 0, stream>>>(w_down, wdt, F, D);

  rmsnorm_kernel<<<T, 256, 0, stream>>>(x, ln1, h_bf);
  rope_table<<<(T * 64) / 256, 256, 0, stream>>>(positions, ctab, stab);
  // packed QKV GEMM (V region written transposed bf16 to vtbf)
  gemm_bf<4><<<dim3(T / 128, NQKV / 128), 256, 0, stream>>>(
      h_bf, wqkvt, nullptr, qkvf, vtbf, D, NQKV);
  rope_bf16<<<(T * NQ * 64) / 256, 256, 0, stream>>>(qkvf, ctab, stab, qbf, NQ, NQKV,
                                                     0.08838834764831845f);
  rope_bf16<<<(T * NKV * 64) / 256, 256, 0, stream>>>(qkvf + NQ * H, ctab, stab, kbf,
                                                      NKV, NQKV, 1.0f);
  flash_attn<<<dim3(T / 64, NQ), 256, 0, stream>>>(qbf, kbf, vtbf, attn_bf);
  gemm_bf<1><<<dim3(T / 128, D / 128), 256, 0, stream>>>(
      attn_bf, wot, x, resid, nullptr, NQ * H, D);
  rmsnorm_kernel<<<T, 256, 0, stream>>>(resid, ln2, h2_bf);
  // interleaved gate/up GEMM with fused silu*up epilogue
  gemm_bf<5><<<dim3(T / 128, (2 * F) / 128), 256, 0, stream>>>(
      h2_bf, wgut, nullptr, nullptr, act_bf, D, 2 * F);
  gemm_bf<1><<<dim3(T / 128, D / 128), 256, 0, stream>>>(
      act_bf, wdt, resid, out, nullptr, F, D);
}

// Round 5
// 1798.349 us; speedup vs baseline: 5.3827x; 1.0089x over previous
//
#include <hip/hip_runtime.h>

typedef __attribute__((ext_vector_type(8))) short bf16x8;
typedef __attribute__((ext_vector_type(4))) float f32x4;

constexpr int T = 2048;
constexpr int D = 4096;
constexpr int NQ = 32;    // query heads
constexpr int NKV = 8;    // kv heads
constexpr int H = 128;    // head dim
constexpr int F = 14336;  // ffn dim
constexpr int NQKV = (NQ + 2 * NKV) * H;  // 6144 packed qkv cols
constexpr int VOFF = (NQ + NKV) * H;      // 5120 col offset of V

__device__ inline unsigned short f2bf(float f) {
  unsigned u = __float_as_uint(f);
  return (unsigned short)((u + 0x7FFFu + ((u >> 16) & 1u)) >> 16);
}

__device__ inline void gload_lds16(const void* g, void* l) {
  __builtin_amdgcn_global_load_lds((const __attribute__((address_space(1))) void*)g,
                                   (__attribute__((address_space(3))) void*)l, 16, 0, 0);
}

#define MFMA16(a, b, c) __builtin_amdgcn_mfma_f32_16x16x32_bf16(a, b, c, 0, 0, 0)

// ------- weight transpose+convert: (K,N) f32 -> (rowmap(N),K) bf16 -------
// MODE 0: row = n;  MODE 1: row = (n>>4)*32 + (n&15);  MODE 2: MODE1 + 16
template <int MODE>
__global__ __launch_bounds__(256) void transpose_bf16(const float* __restrict__ in,
                                                      unsigned short* __restrict__ out,
                                                      int K, int N) {
  __shared__ float tile[64 * 65];
  const int kb = blockIdx.x * 64;
  const int nb = blockIdx.y * 64;
  const int tid = threadIdx.x;
  const int r = tid >> 2;
  const int c4 = tid & 3;
#pragma unroll
  for (int i = 0; i < 4; ++i) {
    float4 v = *(const float4*)(in + (size_t)(kb + r) * N + nb + c4 * 16 + i * 4);
    *(float4*)&tile[r * 65 + c4 * 16 + i * 4] = v;
  }
  __syncthreads();
  const int n = tid >> 2;
  const int kq = tid & 3;
  int nsrc = nb + n;
  int prow = (MODE == 0) ? nsrc : ((nsrc >> 4) * 32 + (nsrc & 15) + (MODE == 2 ? 16 : 0));
#pragma unroll
  for (int half = 0; half < 2; ++half) {
    ushort4 o0, o1;
    int k0 = kq * 16 + half * 8;
    o0.x = f2bf(tile[(k0 + 0) * 65 + n]);
    o0.y = f2bf(tile[(k0 + 1) * 65 + n]);
    o0.z = f2bf(tile[(k0 + 2) * 65 + n]);
    o0.w = f2bf(tile[(k0 + 3) * 65 + n]);
    o1.x = f2bf(tile[(k0 + 4) * 65 + n]);
    o1.y = f2bf(tile[(k0 + 5) * 65 + n]);
    o1.z = f2bf(tile[(k0 + 6) * 65 + n]);
    o1.w = f2bf(tile[(k0 + 7) * 65 + n]);
    unsigned short* op = out + (size_t)prow * K + kb + k0;
    *(ushort4*)(op + 0) = o0;
    *(ushort4*)(op + 4) = o1;
  }
}

// ---------------- RMSNorm: f32 in -> bf16 out ----------------
__global__ __launch_bounds__(256) void rmsnorm_kernel(
    const float* __restrict__ in, const float* __restrict__ scale,
    unsigned short* __restrict__ out) {
  int row = blockIdx.x;
  const float4* xr = (const float4*)(in + (size_t)row * D);
  const float4* sr = (const float4*)scale;
  float4 vals[4];
  float ss = 0.f;
#pragma unroll
  for (int i = 0; i < 4; ++i) {
    float4 v = xr[threadIdx.x + i * 256];
    vals[i] = v;
    ss += v.x * v.x + v.y * v.y + v.z * v.z + v.w * v.w;
  }
#pragma unroll
  for (int off = 32; off; off >>= 1) ss += __shfl_xor(ss, off, 64);
  __shared__ float wsum[4];
  if ((threadIdx.x & 63) == 0) wsum[threadIdx.x >> 6] = ss;
  __syncthreads();
  float r = rsqrtf((wsum[0] + wsum[1] + wsum[2] + wsum[3]) * (1.f / D) + 1e-5f);
#pragma unroll
  for (int i = 0; i < 4; ++i) {
    int vi = threadIdx.x + i * 256;
    float4 v = vals[i];
    float4 s = sr[vi];
    ushort4 o;
    o.x = f2bf(v.x * r * s.x);
    o.y = f2bf(v.y * r * s.y);
    o.z = f2bf(v.z * r * s.z);
    o.w = f2bf(v.w * r * s.w);
    *(ushort4*)(out + (size_t)row * D + (size_t)vi * 4) = o;
  }
}

// ---------------- RoPE cos/sin table ----------------
__global__ __launch_bounds__(256) void rope_table(const int* __restrict__ pos,
                                                  float* __restrict__ ctab,
                                                  float* __restrict__ stab) {
  int idx = blockIdx.x * 256 + threadIdx.x;  // T*64
  int t = idx >> 6, i = idx & 63;
  float inv = exp2f(-(float)i * (log2f(500000.0f) / 64.0f));
  float ang = (float)pos[t] * inv;
  ctab[idx] = cosf(ang);
  stab[idx] = sinf(ang);
}

// ------- RoPE apply: f32 strided in -> bf16 out (scale folded) -------
__global__ __launch_bounds__(256) void rope_bf16(const float* __restrict__ x,
                                                 const float* __restrict__ ctab,
                                                 const float* __restrict__ stab,
                                                 unsigned short* __restrict__ out,
                                                 int nheads, int row_stride, float scale) {
  int idx = blockIdx.x * 256 + threadIdx.x;  // T*nheads*64
  int i = idx & 63;
  int tn = idx >> 6;
  int t = tn / nheads;
  int n = tn - t * nheads;
  float c = ctab[t * 64 + i], s = stab[t * 64 + i];
  const float* p = x + (size_t)t * row_stride + n * H;
  float x1 = p[i], x2 = p[i + 64];
  unsigned short* o = out + (size_t)tn * H;
  o[i] = f2bf((x1 * c - x2 * s) * scale);
  o[i + 64] = f2bf((x2 * c + x1 * s) * scale);
}

// ---------------- 128x128 GEMM (m97 structure) ----------------
// EP 1: outF = acc + addend
// EP 4: qkv: cols<VOFF -> outF f32; cols>=VOFF -> outB[(c-VOFF)*T+row] bf16
template <int EP>
__global__ __launch_bounds__(256) void gemm_bf(
    const unsigned short* __restrict__ A, const unsigned short* __restrict__ Bt0,
    const float* __restrict__ addend, float* __restrict__ outF,
    unsigned short* __restrict__ outB, int Kd, int Nd) {
  __shared__ unsigned short lA[128 * 32];
  __shared__ unsigned short lB0[128 * 32];

  const int tid = threadIdx.x;
  const int m0 = blockIdx.x * 128;
  const int n0 = blockIdx.y * 128;
  const int lane = tid & 63;
  const int wv = tid >> 6;

  f32x4 acc[4][4];
#pragma unroll
  for (int i = 0; i < 4; ++i)
#pragma unroll
    for (int j = 0; j < 4; ++j) acc[i][j] = (f32x4){0.f, 0.f, 0.f, 0.f};

  const int wr = (wv >> 1) * 64;
  const int wc = (wv & 1) * 64;
  const int k8 = (lane >> 4) * 8;
  const int rl = lane & 15;
  const int sidx0 = wv * 512 + lane * 8;

  for (int k0 = 0; k0 < Kd; k0 += 32) {
    __syncthreads();
#pragma unroll
    for (int it = 0; it < 2; ++it) {
      int idx = sidx0 + it * 2048;
      int row = idx >> 5, kk = idx & 31;
      int base = wv * 512 + it * 2048;
      gload_lds16(A + (size_t)(m0 + row) * Kd + k0 + kk, &lA[base]);
      gload_lds16(Bt0 + (size_t)(n0 + row) * Kd + k0 + kk, &lB0[base]);
    }
    asm volatile("s_waitcnt vmcnt(0)" ::: "memory");
    __syncthreads();

    bf16x8 af[4], bfr[4];
#pragma unroll
    for (int i = 0; i < 4; ++i)
      af[i] = *(const bf16x8*)&lA[(wr + i * 16 + rl) * 32 + k8];
#pragma unroll
    for (int j = 0; j < 4; ++j)
      bfr[j] = *(const bf16x8*)&lB0[(wc + j * 16 + rl) * 32 + k8];
#pragma unroll
    for (int i = 0; i < 4; ++i)
#pragma unroll
      for (int j = 0; j < 4; ++j)
        acc[i][j] = MFMA16(af[i], bfr[j], acc[i][j]);
  }

  const int rb = (lane >> 4) * 4;
#pragma unroll
  for (int i = 0; i < 4; ++i)
#pragma unroll
    for (int j = 0; j < 4; ++j) {
      int col = n0 + wc + j * 16 + rl;
      if (EP == 4 && n0 >= VOFF) {
        int row0 = m0 + wr + i * 16 + rb;
        ushort4 o;
        o.x = f2bf(acc[i][j][0]);
        o.y = f2bf(acc[i][j][1]);
        o.z = f2bf(acc[i][j][2]);
        o.w = f2bf(acc[i][j][3]);
        *(ushort4*)&outB[(size_t)(col - VOFF) * T + row0] = o;
      } else {
#pragma unroll
        for (int jj = 0; jj < 4; ++jj) {
          int row = m0 + wr + i * 16 + rb + jj;
          size_t idx = (size_t)row * Nd + col;
          float val = acc[i][j][jj];
          if constexpr (EP == 1) {
            outF[idx] = val + addend[idx];
          } else {
            outF[idx] = val;
          }
        }
      }
    }
}

// ---------------- 256x256 8-phase GEMM, interleaved gate/up epilogue ----------------
// A (M,K) bf16; Bt (2F,K) bf16 packed g/u alternating 16-col groups.
// 8 waves (2M x 4N), per-wave 128x64 out. BK=64. LDS 128KB double-buffered.
// Swizzle: phys_byte = logical ^ (((logical>>9)&3)<<4)  (both-sides involution)
__global__ __launch_bounds__(512, 2) void gemm256_gu(
    const unsigned short* __restrict__ A, const unsigned short* __restrict__ Bt,
    unsigned short* __restrict__ outB, int Kd) {
  __shared__ unsigned short lds[65536];
  const int tid = threadIdx.x, lane = tid & 63, wv = tid >> 6;
  const int wm = wv >> 2, wn = wv & 3;
  const int rl = lane & 15, g = lane >> 4;
  // XCD-aware block swizzle (nwg % 8 == 0)
  int raw = blockIdx.x + blockIdx.y * gridDim.x;
  int cpx = (gridDim.x * gridDim.y) >> 3;
  int sid = (raw & 7) * cpx + (raw >> 3);
  int brow = sid % gridDim.x;
  int bcol = sid / gridDim.x;
  const int m0 = brow * 256, n0 = bcol * 256;

  // staging lane constants (pre-swizzled global source, linear LDS dest)
  const int l8 = lane >> 3;
  const int scol =
      ((((lane & 7) * 16) ^ ((((lane >> 5) & 1) | ((wv & 1) << 1)) << 4))) >> 1;
  // read-side swizzled byte-column offsets
  const int xr = ((rl >> 2) & 3) << 4;
  const int pc0 = (g * 16) ^ xr;
  const int pc1 = (64 + g * 16) ^ xr;

  const char* ldsc = (const char*)lds;
  // per-wave global staging base pointers (it0/half0); +64*Kd per it, +128*Kd per half
  const unsigned short* gA = A + (size_t)(m0 + wv * 8 + l8) * Kd + scol;
  const unsigned short* gB = Bt + (size_t)(n0 + wv * 8 + l8) * Kd + scol;

  f32x4 acc[8][4];
#pragma unroll
  for (int i = 0; i < 8; ++i)
#pragma unroll
    for (int j = 0; j < 4; ++j) acc[i][j] = (f32x4){0.f, 0.f, 0.f, 0.f};

  const int NT = Kd >> 6;

#define STAGE_A(kt)                                                              \
  {                                                                              \
    int b_ = (kt) & 1;                                                           \
    const unsigned short* s_ = gA + (size_t)(kt) * 64;                           \
    gload_lds16(s_, (void*)&lds[b_ * 32768 + wv * 512]);                         \
    gload_lds16(s_ + (size_t)64 * Kd, (void*)&lds[b_ * 32768 + (8 + wv) * 512]); \
    gload_lds16(s_ + (size_t)128 * Kd, (void*)&lds[b_ * 32768 + 8192 + wv * 512]); \
    gload_lds16(s_ + (size_t)192 * Kd,                                           \
                (void*)&lds[b_ * 32768 + 8192 + (8 + wv) * 512]);                \
  }
#define STAGE_B(kt)                                                              \
  {                                                                              \
    int b_ = (kt) & 1;                                                           \
    const unsigned short* s_ = gB + (size_t)(kt) * 64;                           \
    gload_lds16(s_, (void*)&lds[b_ * 32768 + 16384 + wv * 512]);                 \
    gload_lds16(s_ + (size_t)64 * Kd,                                            \
                (void*)&lds[b_ * 32768 + 16384 + (8 + wv) * 512]);               \
    gload_lds16(s_ + (size_t)128 * Kd,                                           \
                (void*)&lds[b_ * 32768 + 24576 + wv * 512]);                     \
    gload_lds16(s_ + (size_t)192 * Kd,                                           \
                (void*)&lds[b_ * 32768 + 24576 + (8 + wv) * 512]);               \
  }
#define SBAR()                        \
  __builtin_amdgcn_sched_barrier(0);  \
  __builtin_amdgcn_s_barrier();

  // prologue: stage kt=0 and kt=1 (16 loads), wait for kt=0's 8
  STAGE_A(0); STAGE_B(0);
  STAGE_B(1); STAGE_A(1);
  asm volatile("s_waitcnt vmcnt(8)" ::: "memory");
  SBAR();

  for (int kt = 0; kt < NT; ++kt) {
    const int b = kt & 1;
    const char* aB = ldsc + b * 65536 + wm * 16384;
    const char* bB = ldsc + b * 65536 + 32768 + (wn >> 1) * 16384;
    const int brl = (wn & 1) * 64;
    bf16x8 aR[4][2], bR0[2][2], bR1[2][2];
    // ---- P0: read A(lo) + B(lo), MFMA q0 ----
#pragma unroll
    for (int mf = 0; mf < 4; ++mf) {
      aR[mf][0] = *(const bf16x8*)(aB + (mf * 16 + rl) * 128 + pc0);
      aR[mf][1] = *(const bf16x8*)(aB + (mf * 16 + rl) * 128 + pc1);
    }
#pragma unroll
    for (int nf = 0; nf < 2; ++nf) {
      bR0[nf][0] = *(const bf16x8*)(bB + (brl + nf * 16 + rl) * 128 + pc0);
      bR0[nf][1] = *(const bf16x8*)(bB + (brl + nf * 16 + rl) * 128 + pc1);
    }
    SBAR();
    __builtin_amdgcn_s_setprio(1);
#pragma unroll
    for (int mf = 0; mf < 4; ++mf)
#pragma unroll
      for (int nf = 0; nf < 2; ++nf) {
        acc[mf][nf] = MFMA16(aR[mf][0], bR0[nf][0], acc[mf][nf]);
        acc[mf][nf] = MFMA16(aR[mf][1], bR0[nf][1], acc[mf][nf]);
      }
    __builtin_amdgcn_s_setprio(0);
    SBAR();
    // ---- P1: read B(hi), MFMA q1 ----
#pragma unroll
    for (int nf = 0; nf < 2; ++nf) {
      bR1[nf][0] = *(const bf16x8*)(bB + (brl + (nf + 2) * 16 + rl) * 128 + pc0);
      bR1[nf][1] = *(const bf16x8*)(bB + (brl + (nf + 2) * 16 + rl) * 128 + pc1);
    }
    SBAR();
    __builtin_amdgcn_s_setprio(1);
#pragma unroll
    for (int mf = 0; mf < 4; ++mf)
#pragma unroll
      for (int nf = 0; nf < 2; ++nf) {
        acc[mf][nf + 2] = MFMA16(aR[mf][0], bR1[nf][0], acc[mf][nf + 2]);
        acc[mf][nf + 2] = MFMA16(aR[mf][1], bR1[nf][1], acc[mf][nf + 2]);
      }
    __builtin_amdgcn_s_setprio(0);
    SBAR();
    // ---- P2: stage B(kt+2), read A(hi), MFMA q2 ----
    if (kt + 2 < NT) STAGE_B(kt + 2);
#pragma unroll
    for (int mf = 0; mf < 4; ++mf) {
      aR[mf][0] = *(const bf16x8*)(aB + ((mf + 4) * 16 + rl) * 128 + pc0);
      aR[mf][1] = *(const bf16x8*)(aB + ((mf + 4) * 16 + rl) * 128 + pc1);
    }
    SBAR();
    __builtin_amdgcn_s_setprio(1);
#pragma unroll
    for (int mf = 0; mf < 4; ++mf)
#pragma unroll
      for (int nf = 0; nf < 2; ++nf) {
        acc[mf + 4][nf + 2] = MFMA16(aR[mf][0], bR1[nf][0], acc[mf + 4][nf + 2]);
        acc[mf + 4][nf + 2] = MFMA16(aR[mf][1], bR1[nf][1], acc[mf + 4][nf + 2]);
      }
    __builtin_amdgcn_s_setprio(0);
    SBAR();
    // ---- P3: stage A(kt+2), MFMA q3, counted vmcnt ----
    if (kt + 2 < NT) STAGE_A(kt + 2);
    __builtin_amdgcn_s_setprio(1);
#pragma unroll
    for (int mf = 0; mf < 4; ++mf)
#pragma unroll
      for (int nf = 0; nf < 2; ++nf) {
        acc[mf + 4][nf] = MFMA16(aR[mf][0], bR0[nf][0], acc[mf + 4][nf]);
        acc[mf + 4][nf] = MFMA16(aR[mf][1], bR0[nf][1], acc[mf + 4][nf]);
      }
    __builtin_amdgcn_s_setprio(0);
    if (kt + 2 < NT) {
      asm volatile("s_waitcnt vmcnt(8)" ::: "memory");
    } else if (kt + 1 < NT) {
      asm volatile("s_waitcnt vmcnt(0)" ::: "memory");
    }
    SBAR();
  }

  // epilogue: silu(gate)*up, bf16 out (cols: within wave 0-15 g,16-31 u,32-47 g,48-63 u)
  const int g4 = g * 4;
  const int acolBase = ((n0 + wn * 64) >> 1) + rl;
#pragma unroll
  for (int mf = 0; mf < 8; ++mf)
#pragma unroll
    for (int p = 0; p < 2; ++p) {
      int acol = acolBase + p * 16;
#pragma unroll
      for (int jj = 0; jj < 4; ++jj) {
        int row = m0 + wm * 128 + mf * 16 + g4 + jj;
        float gg = acc[mf][2 * p][jj];
        float uu = acc[mf][2 * p + 1][jj];
        outB[(size_t)row * F + acol] = f2bf(gg / (1.f + __expf(-gg)) * uu);
      }
    }
#undef STAGE_A
#undef STAGE_B
#undef SBAR
}

// ---------------- Flash attention (MFMA) ----------------
constexpr int KLD = 136;
constexpr int VLD = 72;
constexpr int PLD = 72;

__global__ __launch_bounds__(256) void flash_attn(
    const unsigned short* __restrict__ qbf, const unsigned short* __restrict__ kbf,
    const unsigned short* __restrict__ vtbf, unsigned short* __restrict__ out) {
  __shared__ unsigned short K_lds[64 * KLD];
  __shared__ unsigned short Vt_lds[H * VLD];
  __shared__ unsigned short P_lds[4 * 16 * PLD];

  const int tid = threadIdx.x;
  const int lane = tid & 63;
  const int wave = tid >> 6;
  const int qb = blockIdx.x;
  const int n = blockIdx.y;
  const int kvh = n >> 2;
  const int g = lane >> 4;
  const int rl = lane & 15;
  const int qrow = qb * 64 + wave * 16;

  bf16x8 qfrag[4];
  {
    const unsigned short* qp = qbf + ((size_t)(qrow + rl) * NQ + n) * H + g * 8;
#pragma unroll
    for (int ks = 0; ks < 4; ++ks) qfrag[ks] = *(const bf16x8*)(qp + ks * 32);
  }

  f32x4 oacc[8];
#pragma unroll
  for (int ob = 0; ob < 8; ++ob) oacc[ob] = (f32x4){0.f, 0.f, 0.f, 0.f};
  float mrun[4] = {-1e30f, -1e30f, -1e30f, -1e30f};
  float lrun[4] = {0.f, 0.f, 0.f, 0.f};

  const int krow = tid >> 2, kseg = (tid & 3) * 32;
  const int vh = tid >> 1, vseg = (tid & 1) * 32;

  for (int kt = 0; kt <= qb; ++kt) {
    const int kbase = kt * 64;
    __syncthreads();
    {
      const unsigned short* kp = kbf + ((size_t)(kbase + krow) * NKV + kvh) * H + kseg;
#pragma unroll
      for (int i = 0; i < 4; ++i)
        *(bf16x8*)&K_lds[krow * KLD + kseg + i * 8] = *(const bf16x8*)(kp + i * 8);
      const unsigned short* vp = vtbf + (size_t)(kvh * H + vh) * T + kbase + vseg;
#pragma unroll
      for (int i = 0; i < 4; ++i)
        *(bf16x8*)&Vt_lds[vh * VLD + vseg + i * 8] = *(const bf16x8*)(vp + i * 8);
    }
    __syncthreads();

    f32x4 sacc[4];
#pragma unroll
    for (int cb = 0; cb < 4; ++cb) sacc[cb] = (f32x4){0.f, 0.f, 0.f, 0.f};
#pragma unroll
    for (int cb = 0; cb < 4; ++cb)
#pragma unroll
      for (int ks = 0; ks < 4; ++ks) {
        bf16x8 kf = *(const bf16x8*)&K_lds[(cb * 16 + rl) * KLD + ks * 32 + g * 8];
        sacc[cb] = MFMA16(qfrag[ks], kf, sacc[cb]);
      }

    if (kt == qb) {
#pragma unroll
      for (int cb = 0; cb < 4; ++cb) {
        int kvg = cb * 16 + rl;
#pragma unroll
        for (int r = 0; r < 4; ++r) {
          int qrel = wave * 16 + g * 4 + r;
          if (kvg > qrel) sacc[cb][r] = -1e30f;
        }
      }
    }

    float mx[4], sm[4], corr[4];
#pragma unroll
    for (int r = 0; r < 4; ++r) {
      float m0 = fmaxf(fmaxf(sacc[0][r], sacc[1][r]), fmaxf(sacc[2][r], sacc[3][r]));
#pragma unroll
      for (int off = 1; off < 16; off <<= 1) m0 = fmaxf(m0, __shfl_xor(m0, off, 64));
      float nm = fmaxf(mrun[r], m0);
      corr[r] = __expf(mrun[r] - nm);
      mrun[r] = nm;
      mx[r] = nm;
    }
#pragma unroll
    for (int cb = 0; cb < 4; ++cb)
#pragma unroll
      for (int r = 0; r < 4; ++r) sacc[cb][r] = __expf(sacc[cb][r] - mx[r]);
#pragma unroll
    for (int r = 0; r < 4; ++r) {
      float s0 = sacc[0][r] + sacc[1][r] + sacc[2][r] + sacc[3][r];
#pragma unroll
      for (int off = 1; off < 16; off <<= 1) s0 += __shfl_xor(s0, off, 64);
      sm[r] = s0;
      lrun[r] = lrun[r] * corr[r] + sm[r];
    }
#pragma unroll
    for (int ob = 0; ob < 8; ++ob)
#pragma unroll
      for (int r = 0; r < 4; ++r) oacc[ob][r] *= corr[r];

#pragma unroll
    for (int cb = 0; cb < 4; ++cb)
#pragma unroll
      for (int r = 0; r < 4; ++r)
        P_lds[(wave * 16 + g * 4 + r) * PLD + cb * 16 + rl] = f2bf(sacc[cb][r]);

    bf16x8 pa[2];
#pragma unroll
    for (int ks = 0; ks < 2; ++ks)
      pa[ks] = *(const bf16x8*)&P_lds[(wave * 16 + rl) * PLD + ks * 32 + g * 8];

#pragma unroll
    for (int ob = 0; ob < 8; ++ob)
#pragma unroll
      for (int ks = 0; ks < 2; ++ks) {
        bf16x8 vf = *(const bf16x8*)&Vt_lds[(ob * 16 + rl) * VLD + ks * 32 + g * 8];
        oacc[ob] = MFMA16(pa[ks], vf, oacc[ob]);
      }
  }

  float inv[4];
#pragma unroll
  for (int r = 0; r < 4; ++r) inv[r] = 1.f / lrun[r];
#pragma unroll
  for (int ob = 0; ob < 8; ++ob)
#pragma unroll
    for (int r = 0; r < 4; ++r) {
      int t = qrow + g * 4 + r;
      out[((size_t)t * NQ + n) * H + ob * 16 + rl] = f2bf(oacc[ob][r] * inv[r]);
    }
}

extern "C" void kernel_launch(void* const* d_in, const int* in_sizes, int n_in,
                              void* d_out, int out_size, void* d_ws, size_t ws_size,
                              hipStream_t stream) {
  (void)in_sizes; (void)n_in; (void)out_size; (void)ws_size;
  const float* x = (const float*)d_in[0];
  const int* positions = (const int*)d_in[1];
  const float* ln1 = (const float*)d_in[2];
  const float* w_q = (const float*)d_in[3];
  const float* w_k = (const float*)d_in[4];
  const float* w_v = (const float*)d_in[5];
  const float* w_o = (const float*)d_in[6];
  const float* ln2 = (const float*)d_in[7];
  const float* w_gate = (const float*)d_in[8];
  const float* w_up = (const float*)d_in[9];
  const float* w_down = (const float*)d_in[10];
  float* out = (float*)d_out;

  char* ws = (char*)d_ws;
  size_t off = 0;
  auto alloc = [&](size_t bytes) {
    char* p = ws + off;
    off += (bytes + 255) & ~(size_t)255;
    return p;
  };
  unsigned short* h_bf = (unsigned short*)alloc((size_t)T * D * 2);
  unsigned short* h2_bf = (unsigned short*)alloc((size_t)T * D * 2);
  unsigned short* attn_bf = (unsigned short*)alloc((size_t)T * NQ * H * 2);
  unsigned short* act_bf = (unsigned short*)alloc((size_t)T * F * 2);
  float* qkvf = (float*)alloc((size_t)T * NQKV * 4);
  float* resid = (float*)alloc((size_t)T * D * 4);
  float* ctab = (float*)alloc((size_t)T * 64 * 4);
  float* stab = (float*)alloc((size_t)T * 64 * 4);
  unsigned short* qbf = (unsigned short*)alloc((size_t)T * NQ * H * 2);
  unsigned short* kbf = (unsigned short*)alloc((size_t)T * NKV * H * 2);
  unsigned short* vtbf = (unsigned short*)alloc((size_t)NKV * H * T * 2);
  unsigned short* wqkvt = (unsigned short*)alloc((size_t)NQKV * D * 2);
  unsigned short* wot = (unsigned short*)alloc((size_t)D * NQ * H * 2);
  unsigned short* wgut = (unsigned short*)alloc((size_t)2 * F * D * 2);
  unsigned short* wdt = (unsigned short*)alloc((size_t)D * F * 2);

  transpose_bf16<0><<<dim3(D / 64, (NQ * H) / 64), 256, 0, stream>>>(w_q, wqkvt, D, NQ * H);
  transpose_bf16<0><<<dim3(D / 64, (NKV * H) / 64), 256, 0, stream>>>(
      w_k, wqkvt + (size_t)NQ * H * D, D, NKV * H);
  transpose_bf16<0><<<dim3(D / 64, (NKV * H) / 64), 256, 0, stream>>>(
      w_v, wqkvt + (size_t)VOFF * D, D, NKV * H);
  transpose_bf16<0><<<dim3((NQ * H) / 64, D / 64), 256, 0, stream>>>(w_o, wot, NQ * H, D);
  transpose_bf16<1><<<dim3(D / 64, F / 64), 256, 0, stream>>>(w_gate, wgut, D, F);
  transpose_bf16<2><<<dim3(D / 64, F / 64), 256, 0, stream>>>(w_up, wgut, D, F);
  transpose_bf16<0><<<dim3(F / 64, D / 64), 256, 0, stream>>>(w_down, wdt, F, D);

  rmsnorm_kernel<<<T, 256, 0, stream>>>(x, ln1, h_bf);
  rope_table<<<(T * 64) / 256, 256, 0, stream>>>(positions, ctab, stab);
  gemm_bf<4><<<dim3(T / 128, NQKV / 128), 256, 0, stream>>>(
      h_bf, wqkvt, nullptr, qkvf, vtbf, D, NQKV);
  rope_bf16<<<(T * NQ * 64) / 256, 256, 0, stream>>>(qkvf, ctab, stab, qbf, NQ, NQKV,
                                                     0.08838834764831845f);
  rope_bf16<<<(T * NKV * 64) / 256, 256, 0, stream>>>(qkvf + NQ * H, ctab, stab, kbf,
                                                      NKV, NQKV, 1.0f);
  flash_attn<<<dim3(T / 64, NQ), 256, 0, stream>>>(qbf, kbf, vtbf, attn_bf);
  gemm_bf<1><<<dim3(T / 128, D / 128), 256, 0, stream>>>(
      attn_bf, wot, x, resid, nullptr, NQ * H, D);
  rmsnorm_kernel<<<T, 256, 0, stream>>>(resid, ln2, h2_bf);
  // 256² 8-phase interleaved gate/up GEMM
  gemm256_gu<<<dim3(T / 256, (2 * F) / 256), 512, 0, stream>>>(h2_bf, wgut, act_bf, D);
  gemm_bf<1><<<dim3(T / 128, D / 128), 256, 0, stream>>>(
      act_bf, wdt, resid, out, nullptr, F, D);
}

// Round 6
// 1630.015 us; speedup vs baseline: 5.9385x; 1.1033x over previous
//
#include <hip/hip_runtime.h>

typedef __attribute__((ext_vector_type(8))) short bf16x8;
typedef __attribute__((ext_vector_type(4))) float f32x4;

constexpr int T = 2048;
constexpr int D = 4096;
constexpr int NQ = 32;    // query heads
constexpr int NKV = 8;    // kv heads
constexpr int H = 128;    // head dim
constexpr int F = 14336;  // ffn dim
constexpr int NQKV = (NQ + 2 * NKV) * H;  // 6144 packed qkv cols
constexpr int VOFF = (NQ + NKV) * H;      // 5120 col offset of V

__device__ inline unsigned short f2bf(float f) {
  unsigned u = __float_as_uint(f);
  return (unsigned short)((u + 0x7FFFu + ((u >> 16) & 1u)) >> 16);
}

__device__ inline void gload_lds16(const void* g, void* l) {
  __builtin_amdgcn_global_load_lds((const __attribute__((address_space(1))) void*)g,
                                   (__attribute__((address_space(3))) void*)l, 16, 0, 0);
}

#define MFMA16(a, b, c) __builtin_amdgcn_mfma_f32_16x16x32_bf16(a, b, c, 0, 0, 0)

// ------- weight transpose+convert: (K,N) f32 -> (rowmap(N),K) bf16 -------
// MODE 0: row = n;  MODE 1: row = (n>>4)*32 + (n&15);  MODE 2: MODE1 + 16
template <int MODE>
__global__ __launch_bounds__(256) void transpose_bf16(const float* __restrict__ in,
                                                      unsigned short* __restrict__ out,
                                                      int K, int N) {
  __shared__ float tile[64 * 65];
  const int kb = blockIdx.x * 64;
  const int nb = blockIdx.y * 64;
  const int tid = threadIdx.x;
  const int r = tid >> 2;
  const int c4 = tid & 3;
#pragma unroll
  for (int i = 0; i < 4; ++i) {
    float4 v = *(const float4*)(in + (size_t)(kb + r) * N + nb + c4 * 16 + i * 4);
    *(float4*)&tile[r * 65 + c4 * 16 + i * 4] = v;
  }
  __syncthreads();
  const int n = tid >> 2;
  const int kq = tid & 3;
  int nsrc = nb + n;
  int prow = (MODE == 0) ? nsrc : ((nsrc >> 4) * 32 + (nsrc & 15) + (MODE == 2 ? 16 : 0));
#pragma unroll
  for (int half = 0; half < 2; ++half) {
    ushort4 o0, o1;
    int k0 = kq * 16 + half * 8;
    o0.x = f2bf(tile[(k0 + 0) * 65 + n]);
    o0.y = f2bf(tile[(k0 + 1) * 65 + n]);
    o0.z = f2bf(tile[(k0 + 2) * 65 + n]);
    o0.w = f2bf(tile[(k0 + 3) * 65 + n]);
    o1.x = f2bf(tile[(k0 + 4) * 65 + n]);
    o1.y = f2bf(tile[(k0 + 5) * 65 + n]);
    o1.z = f2bf(tile[(k0 + 6) * 65 + n]);
    o1.w = f2bf(tile[(k0 + 7) * 65 + n]);
    unsigned short* op = out + (size_t)prow * K + kb + k0;
    *(ushort4*)(op + 0) = o0;
    *(ushort4*)(op + 4) = o1;
  }
}

// ---------------- RMSNorm: f32 in -> bf16 out ----------------
__global__ __launch_bounds__(256) void rmsnorm_kernel(
    const float* __restrict__ in, const float* __restrict__ scale,
    unsigned short* __restrict__ out) {
  int row = blockIdx.x;
  const float4* xr = (const float4*)(in + (size_t)row * D);
  const float4* sr = (const float4*)scale;
  float4 vals[4];
  float ss = 0.f;
#pragma unroll
  for (int i = 0; i < 4; ++i) {
    float4 v = xr[threadIdx.x + i * 256];
    vals[i] = v;
    ss += v.x * v.x + v.y * v.y + v.z * v.z + v.w * v.w;
  }
#pragma unroll
  for (int off = 32; off; off >>= 1) ss += __shfl_xor(ss, off, 64);
  __shared__ float wsum[4];
  if ((threadIdx.x & 63) == 0) wsum[threadIdx.x >> 6] = ss;
  __syncthreads();
  float r = rsqrtf((wsum[0] + wsum[1] + wsum[2] + wsum[3]) * (1.f / D) + 1e-5f);
#pragma unroll
  for (int i = 0; i < 4; ++i) {
    int vi = threadIdx.x + i * 256;
    float4 v = vals[i];
    float4 s = sr[vi];
    ushort4 o;
    o.x = f2bf(v.x * r * s.x);
    o.y = f2bf(v.y * r * s.y);
    o.z = f2bf(v.z * r * s.z);
    o.w = f2bf(v.w * r * s.w);
    *(ushort4*)(out + (size_t)row * D + (size_t)vi * 4) = o;
  }
}

// ---------------- RoPE cos/sin table ----------------
__global__ __launch_bounds__(256) void rope_table(const int* __restrict__ pos,
                                                  float* __restrict__ ctab,
                                                  float* __restrict__ stab) {
  int idx = blockIdx.x * 256 + threadIdx.x;  // T*64
  int t = idx >> 6, i = idx & 63;
  float inv = exp2f(-(float)i * (log2f(500000.0f) / 64.0f));
  float ang = (float)pos[t] * inv;
  ctab[idx] = cosf(ang);
  stab[idx] = sinf(ang);
}

// ------- RoPE apply: f32 strided in -> bf16 out (scale folded) -------
__global__ __launch_bounds__(256) void rope_bf16(const float* __restrict__ x,
                                                 const float* __restrict__ ctab,
                                                 const float* __restrict__ stab,
                                                 unsigned short* __restrict__ out,
                                                 int nheads, int row_stride, float scale) {
  int idx = blockIdx.x * 256 + threadIdx.x;  // T*nheads*64
  int i = idx & 63;
  int tn = idx >> 6;
  int t = tn / nheads;
  int n = tn - t * nheads;
  float c = ctab[t * 64 + i], s = stab[t * 64 + i];
  const float* p = x + (size_t)t * row_stride + n * H;
  float x1 = p[i], x2 = p[i + 64];
  unsigned short* o = out + (size_t)tn * H;
  o[i] = f2bf((x1 * c - x2 * s) * scale);
  o[i + 64] = f2bf((x2 * c + x1 * s) * scale);
}

// ---------------- 128x128 GEMM (m97 structure) ----------------
// EP 1: outF = acc + addend
// EP 4: qkv: cols<VOFF -> outF f32; cols>=VOFF -> outB[(c-VOFF)*T+row] bf16
template <int EP>
__global__ __launch_bounds__(256) void gemm_bf(
    const unsigned short* __restrict__ A, const unsigned short* __restrict__ Bt0,
    const float* __restrict__ addend, float* __restrict__ outF,
    unsigned short* __restrict__ outB, int Kd, int Nd) {
  __shared__ unsigned short lA[128 * 32];
  __shared__ unsigned short lB0[128 * 32];

  const int tid = threadIdx.x;
  const int m0 = blockIdx.x * 128;
  const int n0 = blockIdx.y * 128;
  const int lane = tid & 63;
  const int wv = tid >> 6;

  f32x4 acc[4][4];
#pragma unroll
  for (int i = 0; i < 4; ++i)
#pragma unroll
    for (int j = 0; j < 4; ++j) acc[i][j] = (f32x4){0.f, 0.f, 0.f, 0.f};

  const int wr = (wv >> 1) * 64;
  const int wc = (wv & 1) * 64;
  const int k8 = (lane >> 4) * 8;
  const int rl = lane & 15;
  const int sidx0 = wv * 512 + lane * 8;

  for (int k0 = 0; k0 < Kd; k0 += 32) {
    __syncthreads();
#pragma unroll
    for (int it = 0; it < 2; ++it) {
      int idx = sidx0 + it * 2048;
      int row = idx >> 5, kk = idx & 31;
      int base = wv * 512 + it * 2048;
      gload_lds16(A + (size_t)(m0 + row) * Kd + k0 + kk, &lA[base]);
      gload_lds16(Bt0 + (size_t)(n0 + row) * Kd + k0 + kk, &lB0[base]);
    }
    asm volatile("s_waitcnt vmcnt(0)" ::: "memory");
    __syncthreads();

    bf16x8 af[4], bfr[4];
#pragma unroll
    for (int i = 0; i < 4; ++i)
      af[i] = *(const bf16x8*)&lA[(wr + i * 16 + rl) * 32 + k8];
#pragma unroll
    for (int j = 0; j < 4; ++j)
      bfr[j] = *(const bf16x8*)&lB0[(wc + j * 16 + rl) * 32 + k8];
#pragma unroll
    for (int i = 0; i < 4; ++i)
#pragma unroll
      for (int j = 0; j < 4; ++j)
        acc[i][j] = MFMA16(af[i], bfr[j], acc[i][j]);
  }

  const int rb = (lane >> 4) * 4;
#pragma unroll
  for (int i = 0; i < 4; ++i)
#pragma unroll
    for (int j = 0; j < 4; ++j) {
      int col = n0 + wc + j * 16 + rl;
      if (EP == 4 && n0 >= VOFF) {
        int row0 = m0 + wr + i * 16 + rb;
        ushort4 o;
        o.x = f2bf(acc[i][j][0]);
        o.y = f2bf(acc[i][j][1]);
        o.z = f2bf(acc[i][j][2]);
        o.w = f2bf(acc[i][j][3]);
        *(ushort4*)&outB[(size_t)(col - VOFF) * T + row0] = o;
      } else {
#pragma unroll
        for (int jj = 0; jj < 4; ++jj) {
          int row = m0 + wr + i * 16 + rb + jj;
          size_t idx = (size_t)row * Nd + col;
          float val = acc[i][j][jj];
          if constexpr (EP == 1) {
            outF[idx] = val + addend[idx];
          } else {
            outF[idx] = val;
          }
        }
      }
    }
}

// ---------------- 256x256 8-phase GEMM ----------------
// A (M,K) bf16; Bt (N,K) bf16. 8 waves (2M x 4N), per-wave 128x64 out. BK=64.
// LDS 128KB double-buffered. Swizzle (both sides): byte_col ^= (row&7)<<4.
// EP 5: Bt packed gate/up alternating 16-col groups; outB = bf16(silu(g)*u), ld F
// EP 1: outF = acc + addend (f32), ld Nd
template <int EP>
__global__ __launch_bounds__(512, 2) void gemm256(
    const unsigned short* __restrict__ A, const unsigned short* __restrict__ Bt,
    const float* __restrict__ addend, float* __restrict__ outF,
    unsigned short* __restrict__ outB, int Kd, int Nd) {
  __shared__ unsigned short lds[65536];
  const int tid = threadIdx.x, lane = tid & 63, wv = tid >> 6;
  const int wm = wv >> 2, wn = wv & 3;
  const int rl = lane & 15, g = lane >> 4;
  // XCD-aware block swizzle (nwg % 8 == 0)
  int raw = blockIdx.x + blockIdx.y * gridDim.x;
  int cpx = (gridDim.x * gridDim.y) >> 3;
  int sid = (raw & 7) * cpx + (raw >> 3);
  int brow = sid % gridDim.x;
  int bcol = sid / gridDim.x;
  const int m0 = brow * 256, n0 = bcol * 256;

  // staging: linear LDS dest (lane*16B); global source col pre-swizzled.
  // dest row (within 64-row substage) = lane>>3, dest bytecol = (lane&7)*16.
  // row&7 == lane>>3 & 7 for all substages -> src col = ((lane&7)^(lane>>3))*8 ushorts
  const int l8 = lane >> 3;
  const int scol = ((lane & 7) ^ l8) * 8;
  // read-side swizzled byte-column offsets: logical ^ ((row&7)<<4), row&7 == rl&7
  const int xr = (rl & 7) << 4;
  const int pc0 = (g * 16) ^ xr;
  const int pc1 = (64 + g * 16) ^ xr;

  const char* ldsc = (const char*)lds;
  const unsigned short* gA = A + (size_t)(m0 + wv * 8 + l8) * Kd + scol;
  const unsigned short* gB = Bt + (size_t)(n0 + wv * 8 + l8) * Kd + scol;

  f32x4 acc[8][4];
#pragma unroll
  for (int i = 0; i < 8; ++i)
#pragma unroll
    for (int j = 0; j < 4; ++j) acc[i][j] = (f32x4){0.f, 0.f, 0.f, 0.f};

  const int NT = Kd >> 6;

#define STAGE_A(kt)                                                              \
  {                                                                              \
    int b_ = (kt) & 1;                                                           \
    const unsigned short* s_ = gA + (size_t)(kt) * 64;                           \
    gload_lds16(s_, (void*)&lds[b_ * 32768 + wv * 512]);                         \
    gload_lds16(s_ + (size_t)64 * Kd, (void*)&lds[b_ * 32768 + (8 + wv) * 512]); \
    gload_lds16(s_ + (size_t)128 * Kd, (void*)&lds[b_ * 32768 + 8192 + wv * 512]); \
    gload_lds16(s_ + (size_t)192 * Kd,                                           \
                (void*)&lds[b_ * 32768 + 8192 + (8 + wv) * 512]);                \
  }
#define STAGE_B(kt)                                                              \
  {                                                                              \
    int b_ = (kt) & 1;                                                           \
    const unsigned short* s_ = gB + (size_t)(kt) * 64;                           \
    gload_lds16(s_, (void*)&lds[b_ * 32768 + 16384 + wv * 512]);                 \
    gload_lds16(s_ + (size_t)64 * Kd,                                            \
                (void*)&lds[b_ * 32768 + 16384 + (8 + wv) * 512]);               \
    gload_lds16(s_ + (size_t)128 * Kd,                                           \
                (void*)&lds[b_ * 32768 + 24576 + wv * 512]);                     \
    gload_lds16(s_ + (size_t)192 * Kd,                                           \
                (void*)&lds[b_ * 32768 + 24576 + (8 + wv) * 512]);               \
  }
#define SBAR()                        \
  __builtin_amdgcn_sched_barrier(0);  \
  __builtin_amdgcn_s_barrier();

  STAGE_A(0); STAGE_B(0);
  STAGE_B(1); STAGE_A(1);
  asm volatile("s_waitcnt vmcnt(8)" ::: "memory");
  SBAR();

  for (int kt = 0; kt < NT; ++kt) {
    const int b = kt & 1;
    const char* aB = ldsc + b * 65536 + wm * 16384;
    const char* bB = ldsc + b * 65536 + 32768 + (wn >> 1) * 16384;
    const int brl = (wn & 1) * 64;
    bf16x8 aR[4][2], bR0[2][2], bR1[2][2];
    // ---- P0: read A(lo) + B(lo), MFMA q0 ----
#pragma unroll
    for (int mf = 0; mf < 4; ++mf) {
      aR[mf][0] = *(const bf16x8*)(aB + (mf * 16 + rl) * 128 + pc0);
      aR[mf][1] = *(const bf16x8*)(aB + (mf * 16 + rl) * 128 + pc1);
    }
#pragma unroll
    for (int nf = 0; nf < 2; ++nf) {
      bR0[nf][0] = *(const bf16x8*)(bB + (brl + nf * 16 + rl) * 128 + pc0);
      bR0[nf][1] = *(const bf16x8*)(bB + (brl + nf * 16 + rl) * 128 + pc1);
    }
    SBAR();
    __builtin_amdgcn_s_setprio(1);
#pragma unroll
    for (int mf = 0; mf < 4; ++mf)
#pragma unroll
      for (int nf = 0; nf < 2; ++nf) {
        acc[mf][nf] = MFMA16(aR[mf][0], bR0[nf][0], acc[mf][nf]);
        acc[mf][nf] = MFMA16(aR[mf][1], bR0[nf][1], acc[mf][nf]);
      }
    __builtin_amdgcn_s_setprio(0);
    SBAR();
    // ---- P1: read B(hi), MFMA q1 ----
#pragma unroll
    for (int nf = 0; nf < 2; ++nf) {
      bR1[nf][0] = *(const bf16x8*)(bB + (brl + (nf + 2) * 16 + rl) * 128 + pc0);
      bR1[nf][1] = *(const bf16x8*)(bB + (brl + (nf + 2) * 16 + rl) * 128 + pc1);
    }
    SBAR();
    __builtin_amdgcn_s_setprio(1);
#pragma unroll
    for (int mf = 0; mf < 4; ++mf)
#pragma unroll
      for (int nf = 0; nf < 2; ++nf) {
        acc[mf][nf + 2] = MFMA16(aR[mf][0], bR1[nf][0], acc[mf][nf + 2]);
        acc[mf][nf + 2] = MFMA16(aR[mf][1], bR1[nf][1], acc[mf][nf + 2]);
      }
    __builtin_amdgcn_s_setprio(0);
    SBAR();
    // ---- P2: stage B(kt+2), read A(hi), MFMA q2 ----
    if (kt + 2 < NT) STAGE_B(kt + 2);
#pragma unroll
    for (int mf = 0; mf < 4; ++mf) {
      aR[mf][0] = *(const bf16x8*)(aB + ((mf + 4) * 16 + rl) * 128 + pc0);
      aR[mf][1] = *(const bf16x8*)(aB + ((mf + 4) * 16 + rl) * 128 + pc1);
    }
    SBAR();
    __builtin_amdgcn_s_setprio(1);
#pragma unroll
    for (int mf = 0; mf < 4; ++mf)
#pragma unroll
      for (int nf = 0; nf < 2; ++nf) {
        acc[mf + 4][nf + 2] = MFMA16(aR[mf][0], bR1[nf][0], acc[mf + 4][nf + 2]);
        acc[mf + 4][nf + 2] = MFMA16(aR[mf][1], bR1[nf][1], acc[mf + 4][nf + 2]);
      }
    __builtin_amdgcn_s_setprio(0);
    SBAR();
    // ---- P3: stage A(kt+2), MFMA q3, counted vmcnt ----
    if (kt + 2 < NT) STAGE_A(kt + 2);
    __builtin_amdgcn_s_setprio(1);
#pragma unroll
    for (int mf = 0; mf < 4; ++mf)
#pragma unroll
      for (int nf = 0; nf < 2; ++nf) {
        acc[mf + 4][nf] = MFMA16(aR[mf][0], bR0[nf][0], acc[mf + 4][nf]);
        acc[mf + 4][nf] = MFMA16(aR[mf][1], bR0[nf][1], acc[mf + 4][nf]);
      }
    __builtin_amdgcn_s_setprio(0);
    if (kt + 2 < NT) {
      asm volatile("s_waitcnt vmcnt(8)" ::: "memory");
    } else if (kt + 1 < NT) {
      asm volatile("s_waitcnt vmcnt(0)" ::: "memory");
    }
    SBAR();
  }

  const int g4 = g * 4;
  if constexpr (EP == 5) {
    // silu(gate)*up epilogue; packed cols: 16 gate, 16 up alternating
    const int acolBase = ((n0 + wn * 64) >> 1) + rl;
#pragma unroll
    for (int mf = 0; mf < 8; ++mf)
#pragma unroll
      for (int p = 0; p < 2; ++p) {
        int acol = acolBase + p * 16;
#pragma unroll
        for (int jj = 0; jj < 4; ++jj) {
          int row = m0 + wm * 128 + mf * 16 + g4 + jj;
          float gg = acc[mf][2 * p][jj];
          float uu = acc[mf][2 * p + 1][jj];
          outB[(size_t)row * F + acol] = f2bf(gg / (1.f + __expf(-gg)) * uu);
        }
      }
  } else {
#pragma unroll
    for (int mf = 0; mf < 8; ++mf)
#pragma unroll
      for (int q = 0; q < 4; ++q) {
        int col = n0 + wn * 64 + q * 16 + rl;
#pragma unroll
        for (int jj = 0; jj < 4; ++jj) {
          int row = m0 + wm * 128 + mf * 16 + g4 + jj;
          size_t idx = (size_t)row * Nd + col;
          outF[idx] = acc[mf][q][jj] + addend[idx];
        }
      }
  }
#undef STAGE_A
#undef STAGE_B
#undef SBAR
}

// ---------------- Flash attention (MFMA) ----------------
constexpr int KLD = 136;
constexpr int VLD = 72;
constexpr int PLD = 72;

__global__ __launch_bounds__(256) void flash_attn(
    const unsigned short* __restrict__ qbf, const unsigned short* __restrict__ kbf,
    const unsigned short* __restrict__ vtbf, unsigned short* __restrict__ out) {
  __shared__ unsigned short K_lds[64 * KLD];
  __shared__ unsigned short Vt_lds[H * VLD];
  __shared__ unsigned short P_lds[4 * 16 * PLD];

  const int tid = threadIdx.x;
  const int lane = tid & 63;
  const int wave = tid >> 6;
  const int qb = blockIdx.x;
  const int n = blockIdx.y;
  const int kvh = n >> 2;
  const int g = lane >> 4;
  const int rl = lane & 15;
  const int qrow = qb * 64 + wave * 16;

  bf16x8 qfrag[4];
  {
    const unsigned short* qp = qbf + ((size_t)(qrow + rl) * NQ + n) * H + g * 8;
#pragma unroll
    for (int ks = 0; ks < 4; ++ks) qfrag[ks] = *(const bf16x8*)(qp + ks * 32);
  }

  f32x4 oacc[8];
#pragma unroll
  for (int ob = 0; ob < 8; ++ob) oacc[ob] = (f32x4){0.f, 0.f, 0.f, 0.f};
  float mrun[4] = {-1e30f, -1e30f, -1e30f, -1e30f};
  float lrun[4] = {0.f, 0.f, 0.f, 0.f};

  const int krow = tid >> 2, kseg = (tid & 3) * 32;
  const int vh = tid >> 1, vseg = (tid & 1) * 32;

  for (int kt = 0; kt <= qb; ++kt) {
    const int kbase = kt * 64;
    __syncthreads();
    {
      const unsigned short* kp = kbf + ((size_t)(kbase + krow) * NKV + kvh) * H + kseg;
#pragma unroll
      for (int i = 0; i < 4; ++i)
        *(bf16x8*)&K_lds[krow * KLD + kseg + i * 8] = *(const bf16x8*)(kp + i * 8);
      const unsigned short* vp = vtbf + (size_t)(kvh * H + vh) * T + kbase + vseg;
#pragma unroll
      for (int i = 0; i < 4; ++i)
        *(bf16x8*)&Vt_lds[vh * VLD + vseg + i * 8] = *(const bf16x8*)(vp + i * 8);
    }
    __syncthreads();

    f32x4 sacc[4];
#pragma unroll
    for (int cb = 0; cb < 4; ++cb) sacc[cb] = (f32x4){0.f, 0.f, 0.f, 0.f};
#pragma unroll
    for (int cb = 0; cb < 4; ++cb)
#pragma unroll
      for (int ks = 0; ks < 4; ++ks) {
        bf16x8 kf = *(const bf16x8*)&K_lds[(cb * 16 + rl) * KLD + ks * 32 + g * 8];
        sacc[cb] = MFMA16(qfrag[ks], kf, sacc[cb]);
      }

    if (kt == qb) {
#pragma unroll
      for (int cb = 0; cb < 4; ++cb) {
        int kvg = cb * 16 + rl;
#pragma unroll
        for (int r = 0; r < 4; ++r) {
          int qrel = wave * 16 + g * 4 + r;
          if (kvg > qrel) sacc[cb][r] = -1e30f;
        }
      }
    }

    float mx[4], sm[4], corr[4];
#pragma unroll
    for (int r = 0; r < 4; ++r) {
      float m0 = fmaxf(fmaxf(sacc[0][r], sacc[1][r]), fmaxf(sacc[2][r], sacc[3][r]));
#pragma unroll
      for (int off = 1; off < 16; off <<= 1) m0 = fmaxf(m0, __shfl_xor(m0, off, 64));
      float nm = fmaxf(mrun[r], m0);
      corr[r] = __expf(mrun[r] - nm);
      mrun[r] = nm;
      mx[r] = nm;
    }
#pragma unroll
    for (int cb = 0; cb < 4; ++cb)
#pragma unroll
      for (int r = 0; r < 4; ++r) sacc[cb][r] = __expf(sacc[cb][r] - mx[r]);
#pragma unroll
    for (int r = 0; r < 4; ++r) {
      float s0 = sacc[0][r] + sacc[1][r] + sacc[2][r] + sacc[3][r];
#pragma unroll
      for (int off = 1; off < 16; off <<= 1) s0 += __shfl_xor(s0, off, 64);
      sm[r] = s0;
      lrun[r] = lrun[r] * corr[r] + sm[r];
    }
#pragma unroll
    for (int ob = 0; ob < 8; ++ob)
#pragma unroll
      for (int r = 0; r < 4; ++r) oacc[ob][r] *= corr[r];

#pragma unroll
    for (int cb = 0; cb < 4; ++cb)
#pragma unroll
      for (int r = 0; r < 4; ++r)
        P_lds[(wave * 16 + g * 4 + r) * PLD + cb * 16 + rl] = f2bf(sacc[cb][r]);

    bf16x8 pa[2];
#pragma unroll
    for (int ks = 0; ks < 2; ++ks)
      pa[ks] = *(const bf16x8*)&P_lds[(wave * 16 + rl) * PLD + ks * 32 + g * 8];

#pragma unroll
    for (int ob = 0; ob < 8; ++ob)
#pragma unroll
      for (int ks = 0; ks < 2; ++ks) {
        bf16x8 vf = *(const bf16x8*)&Vt_lds[(ob * 16 + rl) * VLD + ks * 32 + g * 8];
        oacc[ob] = MFMA16(pa[ks], vf, oacc[ob]);
      }
  }

  float inv[4];
#pragma unroll
  for (int r = 0; r < 4; ++r) inv[r] = 1.f / lrun[r];
#pragma unroll
  for (int ob = 0; ob < 8; ++ob)
#pragma unroll
    for (int r = 0; r < 4; ++r) {
      int t = qrow + g * 4 + r;
      out[((size_t)t * NQ + n) * H + ob * 16 + rl] = f2bf(oacc[ob][r] * inv[r]);
    }
}

extern "C" void kernel_launch(void* const* d_in, const int* in_sizes, int n_in,
                              void* d_out, int out_size, void* d_ws, size_t ws_size,
                              hipStream_t stream) {
  (void)in_sizes; (void)n_in; (void)out_size; (void)ws_size;
  const float* x = (const float*)d_in[0];
  const int* positions = (const int*)d_in[1];
  const float* ln1 = (const float*)d_in[2];
  const float* w_q = (const float*)d_in[3];
  const float* w_k = (const float*)d_in[4];
  const float* w_v = (const float*)d_in[5];
  const float* w_o = (const float*)d_in[6];
  const float* ln2 = (const float*)d_in[7];
  const float* w_gate = (const float*)d_in[8];
  const float* w_up = (const float*)d_in[9];
  const float* w_down = (const float*)d_in[10];
  float* out = (float*)d_out;

  char* ws = (char*)d_ws;
  size_t off = 0;
  auto alloc = [&](size_t bytes) {
    char* p = ws + off;
    off += (bytes + 255) & ~(size_t)255;
    return p;
  };
  unsigned short* h_bf = (unsigned short*)alloc((size_t)T * D * 2);
  unsigned short* h2_bf = (unsigned short*)alloc((size_t)T * D * 2);
  unsigned short* attn_bf = (unsigned short*)alloc((size_t)T * NQ * H * 2);
  unsigned short* act_bf = (unsigned short*)alloc((size_t)T * F * 2);
  float* qkvf = (float*)alloc((size_t)T * NQKV * 4);
  float* resid = (float*)alloc((size_t)T * D * 4);
  float* ctab = (float*)alloc((size_t)T * 64 * 4);
  float* stab = (float*)alloc((size_t)T * 64 * 4);
  unsigned short* qbf = (unsigned short*)alloc((size_t)T * NQ * H * 2);
  unsigned short* kbf = (unsigned short*)alloc((size_t)T * NKV * H * 2);
  unsigned short* vtbf = (unsigned short*)alloc((size_t)NKV * H * T * 2);
  unsigned short* wqkvt = (unsigned short*)alloc((size_t)NQKV * D * 2);
  unsigned short* wot = (unsigned short*)alloc((size_t)D * NQ * H * 2);
  unsigned short* wgut = (unsigned short*)alloc((size_t)2 * F * D * 2);
  unsigned short* wdt = (unsigned short*)alloc((size_t)D * F * 2);

  transpose_bf16<0><<<dim3(D / 64, (NQ * H) / 64), 256, 0, stream>>>(w_q, wqkvt, D, NQ * H);
  transpose_bf16<0><<<dim3(D / 64, (NKV * H) / 64), 256, 0, stream>>>(
      w_k, wqkvt + (size_t)NQ * H * D, D, NKV * H);
  transpose_bf16<0><<<dim3(D / 64, (NKV * H) / 64), 256, 0, stream>>>(
      w_v, wqkvt + (size_t)VOFF * D, D, NKV * H);
  transpose_bf16<0><<<dim3((NQ * H) / 64, D / 64), 256, 0, stream>>>(w_o, wot, NQ * H, D);
  transpose_bf16<1><<<dim3(D / 64, F / 64), 256, 0, stream>>>(w_gate, wgut, D, F);
  transpose_bf16<2><<<dim3(D / 64, F / 64), 256, 0, stream>>>(w_up, wgut, D, F);
  transpose_bf16<0><<<dim3(F / 64, D / 64), 256, 0, stream>>>(w_down, wdt, F, D);

  rmsnorm_kernel<<<T, 256, 0, stream>>>(x, ln1, h_bf);
  rope_table<<<(T * 64) / 256, 256, 0, stream>>>(positions, ctab, stab);
  gemm_bf<4><<<dim3(T / 128, NQKV / 128), 256, 0, stream>>>(
      h_bf, wqkvt, nullptr, qkvf, vtbf, D, NQKV);
  rope_bf16<<<(T * NQ * 64) / 256, 256, 0, stream>>>(qkvf, ctab, stab, qbf, NQ, NQKV,
                                                     0.08838834764831845f);
  rope_bf16<<<(T * NKV * 64) / 256, 256, 0, stream>>>(qkvf + NQ * H, ctab, stab, kbf,
                                                      NKV, NQKV, 1.0f);
  flash_attn<<<dim3(T / 64, NQ), 256, 0, stream>>>(qbf, kbf, vtbf, attn_bf);
  gemm_bf<1><<<dim3(T / 128, D / 128), 256, 0, stream>>>(
      attn_bf, wot, x, resid, nullptr, NQ * H, D);
  rmsnorm_kernel<<<T, 256, 0, stream>>>(resid, ln2, h2_bf);
  // 256² 8-phase interleaved gate/up GEMM (swizzled LDS)
  gemm256<5><<<dim3(T / 256, (2 * F) / 256), 512, 0, stream>>>(
      h2_bf, wgut, nullptr, nullptr, act_bf, D, 2 * F);
  // 256² 8-phase down-proj + residual
  gemm256<1><<<dim3(T / 256, D / 256), 512, 0, stream>>>(
      act_bf, wdt, resid, out, nullptr, F, D);
}

// Round 8
// 1458.530 us; speedup vs baseline: 6.6368x; 1.1176x over previous
//
#include <hip/hip_runtime.h>

typedef __attribute__((ext_vector_type(8))) short bf16x8;
typedef __attribute__((ext_vector_type(4))) float f32x4;

constexpr int T = 2048;
constexpr int D = 4096;
constexpr int NQ = 32;    // query heads
constexpr int NKV = 8;    // kv heads
constexpr int H = 128;    // head dim
constexpr int F = 14336;  // ffn dim
constexpr int NQKV = (NQ + 2 * NKV) * H;  // 6144 packed qkv cols
constexpr int VOFF = (NQ + NKV) * H;      // 5120 col offset of V

__device__ inline unsigned short f2bf(float f) {
  unsigned u = __float_as_uint(f);
  return (unsigned short)((u + 0x7FFFu + ((u >> 16) & 1u)) >> 16);
}

__device__ inline void gload_lds16(const void* g, void* l) {
  __builtin_amdgcn_global_load_lds((const __attribute__((address_space(1))) void*)g,
                                   (__attribute__((address_space(3))) void*)l, 16, 0, 0);
}

#define MFMA16(a, b, c) __builtin_amdgcn_mfma_f32_16x16x32_bf16(a, b, c, 0, 0, 0)

// ------- weight transpose+convert: (K,N) f32 -> (rowmap(N),K) bf16 -------
// MODE 0: row = n;  MODE 1: row = (n>>4)*32 + (n&15);  MODE 2: MODE1 + 16
template <int MODE>
__global__ __launch_bounds__(256) void transpose_bf16(const float* __restrict__ in,
                                                      unsigned short* __restrict__ out,
                                                      int K, int N) {
  __shared__ float tile[64 * 65];
  const int kb = blockIdx.x * 64;
  const int nb = blockIdx.y * 64;
  const int tid = threadIdx.x;
  const int r = tid >> 2;
  const int c4 = tid & 3;
#pragma unroll
  for (int i = 0; i < 4; ++i) {
    float4 v = *(const float4*)(in + (size_t)(kb + r) * N + nb + c4 * 16 + i * 4);
    *(float4*)&tile[r * 65 + c4 * 16 + i * 4] = v;
  }
  __syncthreads();
  const int n = tid >> 2;
  const int kq = tid & 3;
  int nsrc = nb + n;
  int prow = (MODE == 0) ? nsrc : ((nsrc >> 4) * 32 + (nsrc & 15) + (MODE == 2 ? 16 : 0));
#pragma unroll
  for (int half = 0; half < 2; ++half) {
    ushort4 o0, o1;
    int k0 = kq * 16 + half * 8;
    o0.x = f2bf(tile[(k0 + 0) * 65 + n]);
    o0.y = f2bf(tile[(k0 + 1) * 65 + n]);
    o0.z = f2bf(tile[(k0 + 2) * 65 + n]);
    o0.w = f2bf(tile[(k0 + 3) * 65 + n]);
    o1.x = f2bf(tile[(k0 + 4) * 65 + n]);
    o1.y = f2bf(tile[(k0 + 5) * 65 + n]);
    o1.z = f2bf(tile[(k0 + 6) * 65 + n]);
    o1.w = f2bf(tile[(k0 + 7) * 65 + n]);
    unsigned short* op = out + (size_t)prow * K + kb + k0;
    *(ushort4*)(op + 0) = o0;
    *(ushort4*)(op + 4) = o1;
  }
}

// ---------------- RMSNorm: f32 in -> bf16 out ----------------
__global__ __launch_bounds__(256) void rmsnorm_kernel(
    const float* __restrict__ in, const float* __restrict__ scale,
    unsigned short* __restrict__ out) {
  int row = blockIdx.x;
  const float4* xr = (const float4*)(in + (size_t)row * D);
  const float4* sr = (const float4*)scale;
  float4 vals[4];
  float ss = 0.f;
#pragma unroll
  for (int i = 0; i < 4; ++i) {
    float4 v = xr[threadIdx.x + i * 256];
    vals[i] = v;
    ss += v.x * v.x + v.y * v.y + v.z * v.z + v.w * v.w;
  }
#pragma unroll
  for (int off = 32; off; off >>= 1) ss += __shfl_xor(ss, off, 64);
  __shared__ float wsum[4];
  if ((threadIdx.x & 63) == 0) wsum[threadIdx.x >> 6] = ss;
  __syncthreads();
  float r = rsqrtf((wsum[0] + wsum[1] + wsum[2] + wsum[3]) * (1.f / D) + 1e-5f);
#pragma unroll
  for (int i = 0; i < 4; ++i) {
    int vi = threadIdx.x + i * 256;
    float4 v = vals[i];
    float4 s = sr[vi];
    ushort4 o;
    o.x = f2bf(v.x * r * s.x);
    o.y = f2bf(v.y * r * s.y);
    o.z = f2bf(v.z * r * s.z);
    o.w = f2bf(v.w * r * s.w);
    *(ushort4*)(out + (size_t)row * D + (size_t)vi * 4) = o;
  }
}

// ---------------- out = a + b + c (f32, vectorized) ----------------
__global__ __launch_bounds__(256) void add3_kernel(const float* __restrict__ a,
                                                   const float* __restrict__ b,
                                                   const float* __restrict__ c,
                                                   float* __restrict__ o) {
  int i = blockIdx.x * 256 + threadIdx.x;
  float4 va = ((const float4*)a)[i];
  float4 vb = ((const float4*)b)[i];
  float4 vc = ((const float4*)c)[i];
  float4 vo;
  vo.x = va.x + vb.x + vc.x;
  vo.y = va.y + vb.y + vc.y;
  vo.z = va.z + vb.z + vc.z;
  vo.w = va.w + vb.w + vc.w;
  ((float4*)o)[i] = vo;
}

// ---------------- RoPE cos/sin table ----------------
__global__ __launch_bounds__(256) void rope_table(const int* __restrict__ pos,
                                                  float* __restrict__ ctab,
                                                  float* __restrict__ stab) {
  int idx = blockIdx.x * 256 + threadIdx.x;  // T*64
  int t = idx >> 6, i = idx & 63;
  float inv = exp2f(-(float)i * (log2f(500000.0f) / 64.0f));
  float ang = (float)pos[t] * inv;
  ctab[idx] = cosf(ang);
  stab[idx] = sinf(ang);
}

// ------- RoPE apply: f32 strided in -> bf16 out (scale folded) -------
__global__ __launch_bounds__(256) void rope_bf16(const float* __restrict__ x,
                                                 const float* __restrict__ ctab,
                                                 const float* __restrict__ stab,
                                                 unsigned short* __restrict__ out,
                                                 int nheads, int row_stride, float scale) {
  int idx = blockIdx.x * 256 + threadIdx.x;  // T*nheads*64
  int i = idx & 63;
  int tn = idx >> 6;
  int t = tn / nheads;
  int n = tn - t * nheads;
  float c = ctab[t * 64 + i], s = stab[t * 64 + i];
  const float* p = x + (size_t)t * row_stride + n * H;
  float x1 = p[i], x2 = p[i + 64];
  unsigned short* o = out + (size_t)tn * H;
  o[i] = f2bf((x1 * c - x2 * s) * scale);
  o[i + 64] = f2bf((x2 * c + x1 * s) * scale);
}

// ---------------- 128x128 GEMM (m97 structure) ----------------
// EP 4: qkv: cols<VOFF -> outF f32; cols>=VOFF -> outB[(c-VOFF)*T+row] bf16
template <int EP>
__global__ __launch_bounds__(256) void gemm_bf(
    const unsigned short* __restrict__ A, const unsigned short* __restrict__ Bt0,
    float* __restrict__ outF, unsigned short* __restrict__ outB, int Kd, int Nd) {
  __shared__ unsigned short lA[128 * 32];
  __shared__ unsigned short lB0[128 * 32];

  const int tid = threadIdx.x;
  const int m0 = blockIdx.x * 128;
  const int n0 = blockIdx.y * 128;
  const int lane = tid & 63;
  const int wv = tid >> 6;

  f32x4 acc[4][4];
#pragma unroll
  for (int i = 0; i < 4; ++i)
#pragma unroll
    for (int j = 0; j < 4; ++j) acc[i][j] = (f32x4){0.f, 0.f, 0.f, 0.f};

  const int wr = (wv >> 1) * 64;
  const int wc = (wv & 1) * 64;
  const int k8 = (lane >> 4) * 8;
  const int rl = lane & 15;
  const int sidx0 = wv * 512 + lane * 8;

  for (int k0 = 0; k0 < Kd; k0 += 32) {
    __syncthreads();
#pragma unroll
    for (int it = 0; it < 2; ++it) {
      int idx = sidx0 + it * 2048;
      int row = idx >> 5, kk = idx & 31;
      int base = wv * 512 + it * 2048;
      gload_lds16(A + (size_t)(m0 + row) * Kd + k0 + kk, &lA[base]);
      gload_lds16(Bt0 + (size_t)(n0 + row) * Kd + k0 + kk, &lB0[base]);
    }
    asm volatile("s_waitcnt vmcnt(0)" ::: "memory");
    __syncthreads();

    bf16x8 af[4], bfr[4];
#pragma unroll
    for (int i = 0; i < 4; ++i)
      af[i] = *(const bf16x8*)&lA[(wr + i * 16 + rl) * 32 + k8];
#pragma unroll
    for (int j = 0; j < 4; ++j)
      bfr[j] = *(const bf16x8*)&lB0[(wc + j * 16 + rl) * 32 + k8];
#pragma unroll
    for (int i = 0; i < 4; ++i)
#pragma unroll
      for (int j = 0; j < 4; ++j)
        acc[i][j] = MFMA16(af[i], bfr[j], acc[i][j]);
  }

  const int rb = (lane >> 4) * 4;
#pragma unroll
  for (int i = 0; i < 4; ++i)
#pragma unroll
    for (int j = 0; j < 4; ++j) {
      int col = n0 + wc + j * 16 + rl;
      if (EP == 4 && n0 >= VOFF) {
        int row0 = m0 + wr + i * 16 + rb;
        ushort4 o;
        o.x = f2bf(acc[i][j][0]);
        o.y = f2bf(acc[i][j][1]);
        o.z = f2bf(acc[i][j][2]);
        o.w = f2bf(acc[i][j][3]);
        *(ushort4*)&outB[(size_t)(col - VOFF) * T + row0] = o;
      } else {
#pragma unroll
        for (int jj = 0; jj < 4; ++jj) {
          int row = m0 + wr + i * 16 + rb + jj;
          outF[(size_t)row * Nd + col] = acc[i][j][jj];
        }
      }
    }
}

// ---------------- 256x256 8-phase GEMM, K-splittable ----------------
// A (M,K) bf16; Bt (N,K) bf16. 8 waves (2M x 4N), per-wave 128x64. BK=64.
// LDS 128KB dbuf. Swizzle both sides: byte_col ^= (row&7)<<4.
// blockIdx.z = K-split slice (Klen per slice).
// EP 0: outF/outF2 (by z) = acc (f32)
// EP 5: Bt packed gate/up alternating 16-col groups; outB = bf16(silu(g)*u)
template <int EP>
__global__ __launch_bounds__(512, 2) void gemm256(
    const unsigned short* __restrict__ A, const unsigned short* __restrict__ Bt,
    float* __restrict__ outF, float* __restrict__ outF2,
    unsigned short* __restrict__ outB, int Kd, int Nd, int Klen) {
  __shared__ unsigned short lds[65536];
  const int tid = threadIdx.x, lane = tid & 63, wv = tid >> 6;
  const int wm = wv >> 2, wn = wv & 3;
  const int rl = lane & 15, g = lane >> 4;
  const int kz = blockIdx.z;
  // XCD-aware block swizzle within z-slice (gx*gy % 8 == 0)
  int raw = blockIdx.x + blockIdx.y * gridDim.x;
  int cpx = (gridDim.x * gridDim.y) >> 3;
  int sid = (raw & 7) * cpx + (raw >> 3);
  int brow = sid % gridDim.x;
  int bcol = sid / gridDim.x;
  const int m0 = brow * 256, n0 = bcol * 256;

  const int l8 = lane >> 3;
  const int scol = ((lane & 7) ^ l8) * 8;  // pre-swizzled global src col
  const int xr = (rl & 7) << 4;            // read-side swizzle
  const int pc0 = (g * 16) ^ xr;
  const int pc1 = (64 + g * 16) ^ xr;

  const char* ldsc = (const char*)lds;
  const unsigned short* gA = A + (size_t)(m0 + wv * 8 + l8) * Kd + kz * Klen + scol;
  const unsigned short* gB = Bt + (size_t)(n0 + wv * 8 + l8) * Kd + kz * Klen + scol;

  f32x4 acc[8][4];
#pragma unroll
  for (int i = 0; i < 8; ++i)
#pragma unroll
    for (int j = 0; j < 4; ++j) acc[i][j] = (f32x4){0.f, 0.f, 0.f, 0.f};

  const int NT = Klen >> 6;

#define STAGE_A(kt)                                                              \
  {                                                                              \
    int b_ = (kt) & 1;                                                           \
    const unsigned short* s_ = gA + (size_t)(kt) * 64;                           \
    gload_lds16(s_, (void*)&lds[b_ * 32768 + wv * 512]);                         \
    gload_lds16(s_ + (size_t)64 * Kd, (void*)&lds[b_ * 32768 + (8 + wv) * 512]); \
    gload_lds16(s_ + (size_t)128 * Kd, (void*)&lds[b_ * 32768 + 8192 + wv * 512]); \
    gload_lds16(s_ + (size_t)192 * Kd,                                           \
                (void*)&lds[b_ * 32768 + 8192 + (8 + wv) * 512]);                \
  }
#define STAGE_B(kt)                                                              \
  {                                                                              \
    int b_ = (kt) & 1;                                                           \
    const unsigned short* s_ = gB + (size_t)(kt) * 64;                           \
    gload_lds16(s_, (void*)&lds[b_ * 32768 + 16384 + wv * 512]);                 \
    gload_lds16(s_ + (size_t)64 * Kd,                                            \
                (void*)&lds[b_ * 32768 + 16384 + (8 + wv) * 512]);               \
    gload_lds16(s_ + (size_t)128 * Kd,                                           \
                (void*)&lds[b_ * 32768 + 24576 + wv * 512]);                     \
    gload_lds16(s_ + (size_t)192 * Kd,                                           \
                (void*)&lds[b_ * 32768 + 24576 + (8 + wv) * 512]);               \
  }
#define SBAR()                        \
  __builtin_amdgcn_sched_barrier(0);  \
  __builtin_amdgcn_s_barrier();

  STAGE_A(0); STAGE_B(0);
  STAGE_B(1); STAGE_A(1);
  asm volatile("s_waitcnt vmcnt(8)" ::: "memory");
  SBAR();

  const int bhalf = (wn >> 1) * 16384;
  const int brl = (wn & 1) * 64;
  // prologue: pre-read B-lo of kt=0 (buffer 0)
  bf16x8 b0c[2][2];
  {
    const char* bB0 = ldsc + 32768 + bhalf;
#pragma unroll
    for (int nf = 0; nf < 2; ++nf) {
      b0c[nf][0] = *(const bf16x8*)(bB0 + (brl + nf * 16 + rl) * 128 + pc0);
      b0c[nf][1] = *(const bf16x8*)(bB0 + (brl + nf * 16 + rl) * 128 + pc1);
    }
  }

  for (int kt = 0; kt < NT; ++kt) {
    const int b = kt & 1;
    const char* aB = ldsc + b * 65536 + wm * 16384;
    const char* bB = ldsc + b * 65536 + 32768 + bhalf;
    const char* bBn = ldsc + (b ^ 1) * 65536 + 32768 + bhalf;
    bf16x8 aR[4][2], bR1[2][2], b0n[2][2];
    // ---- P0: read A(lo), MFMA q0 (uses pre-read b0c) ----
#pragma unroll
    for (int mf = 0; mf < 4; ++mf) {
      aR[mf][0] = *(const bf16x8*)(aB + (mf * 16 + rl) * 128 + pc0);
      aR[mf][1] = *(const bf16x8*)(aB + (mf * 16 + rl) * 128 + pc1);
    }
    SBAR();
    __builtin_amdgcn_s_setprio(1);
#pragma unroll
    for (int mf = 0; mf < 4; ++mf)
#pragma unroll
      for (int nf = 0; nf < 2; ++nf) {
        acc[mf][nf] = MFMA16(aR[mf][0], b0c[nf][0], acc[mf][nf]);
        acc[mf][nf] = MFMA16(aR[mf][1], b0c[nf][1], acc[mf][nf]);
      }
    __builtin_amdgcn_s_setprio(0);
    SBAR();
    // ---- P1: read B(hi), MFMA q1 ----
#pragma unroll
    for (int nf = 0; nf < 2; ++nf) {
      bR1[nf][0] = *(const bf16x8*)(bB + (brl + (nf + 2) * 16 + rl) * 128 + pc0);
      bR1[nf][1] = *(const bf16x8*)(bB + (brl + (nf + 2) * 16 + rl) * 128 + pc1);
    }
    SBAR();
    __builtin_amdgcn_s_setprio(1);
#pragma unroll
    for (int mf = 0; mf < 4; ++mf)
#pragma unroll
      for (int nf = 0; nf < 2; ++nf) {
        acc[mf][nf + 2] = MFMA16(aR[mf][0], bR1[nf][0], acc[mf][nf + 2]);
        acc[mf][nf + 2] = MFMA16(aR[mf][1], bR1[nf][1], acc[mf][nf + 2]);
      }
    __builtin_amdgcn_s_setprio(0);
    SBAR();
    // ---- P2: stage B(kt+2), read A(hi); drain B(kt+1) before P3's read-ahead ----
    if (kt + 2 < NT) STAGE_B(kt + 2);
#pragma unroll
    for (int mf = 0; mf < 4; ++mf) {
      aR[mf][0] = *(const bf16x8*)(aB + ((mf + 4) * 16 + rl) * 128 + pc0);
      aR[mf][1] = *(const bf16x8*)(aB + ((mf + 4) * 16 + rl) * 128 + pc1);
    }
    if (kt + 2 < NT) {
      asm volatile("s_waitcnt vmcnt(8)" ::: "memory");
    } else if (kt + 1 < NT) {
      asm volatile("s_waitcnt vmcnt(4)" ::: "memory");  // tail: drain B(NT-1)
    }
    SBAR();
    __builtin_amdgcn_s_setprio(1);
#pragma unroll
    for (int mf = 0; mf < 4; ++mf)
#pragma unroll
      for (int nf = 0; nf < 2; ++nf) {
        acc[mf + 4][nf + 2] = MFMA16(aR[mf][0], bR1[nf][0], acc[mf + 4][nf + 2]);
        acc[mf + 4][nf + 2] = MFMA16(aR[mf][1], bR1[nf][1], acc[mf + 4][nf + 2]);
      }
    __builtin_amdgcn_s_setprio(0);
    SBAR();
    // ---- P3: stage A(kt+2), read-ahead B-lo(kt+1), MFMA q3 ----
    if (kt + 2 < NT) STAGE_A(kt + 2);
#pragma unroll
    for (int nf = 0; nf < 2; ++nf) {
      b0n[nf][0] = *(const bf16x8*)(bBn + (brl + nf * 16 + rl) * 128 + pc0);
      b0n[nf][1] = *(const bf16x8*)(bBn + (brl + nf * 16 + rl) * 128 + pc1);
    }
    SBAR();
    __builtin_amdgcn_s_setprio(1);
#pragma unroll
    for (int mf = 0; mf < 4; ++mf)
#pragma unroll
      for (int nf = 0; nf < 2; ++nf) {
        acc[mf + 4][nf] = MFMA16(aR[mf][0], b0c[nf][0], acc[mf + 4][nf]);
        acc[mf + 4][nf] = MFMA16(aR[mf][1], b0c[nf][1], acc[mf + 4][nf]);
      }
    __builtin_amdgcn_s_setprio(0);
    if (kt + 2 < NT) {
      asm volatile("s_waitcnt vmcnt(8)" ::: "memory");  // drain A(kt+1)
    } else if (kt + 1 < NT) {
      asm volatile("s_waitcnt vmcnt(0)" ::: "memory");  // tail: drain A(NT-1)
    }
    SBAR();
#pragma unroll
    for (int nf = 0; nf < 2; ++nf) {
      b0c[nf][0] = b0n[nf][0];
      b0c[nf][1] = b0n[nf][1];
    }
  }

  const int g4 = g * 4;
  if constexpr (EP == 5) {
    const int acolBase = ((n0 + wn * 64) >> 1) + rl;
#pragma unroll
    for (int mf = 0; mf < 8; ++mf)
#pragma unroll
      for (int p = 0; p < 2; ++p) {
        int acol = acolBase + p * 16;
#pragma unroll
        for (int jj = 0; jj < 4; ++jj) {
          int row = m0 + wm * 128 + mf * 16 + g4 + jj;
          float gg = acc[mf][2 * p][jj];
          float uu = acc[mf][2 * p + 1][jj];
          outB[(size_t)row * F + acol] = f2bf(gg / (1.f + __expf(-gg)) * uu);
        }
      }
  } else {
    float* dst = kz ? outF2 : outF;
#pragma unroll
    for (int mf = 0; mf < 8; ++mf)
#pragma unroll
      for (int q = 0; q < 4; ++q) {
        int col = n0 + wn * 64 + q * 16 + rl;
#pragma unroll
        for (int jj = 0; jj < 4; ++jj) {
          int row = m0 + wm * 128 + mf * 16 + g4 + jj;
          dst[(size_t)row * Nd + col] = acc[mf][q][jj];
        }
      }
  }
#undef STAGE_A
#undef STAGE_B
#undef SBAR
}

// ---------------- Flash attention (MFMA) ----------------
constexpr int KLD = 136;
constexpr int VLD = 72;
constexpr int PLD = 72;

__global__ __launch_bounds__(256) void flash_attn(
    const unsigned short* __restrict__ qbf, const unsigned short* __restrict__ kbf,
    const unsigned short* __restrict__ vtbf, unsigned short* __restrict__ out) {
  __shared__ unsigned short K_lds[64 * KLD];
  __shared__ unsigned short Vt_lds[H * VLD];
  __shared__ unsigned short P_lds[4 * 16 * PLD];

  const int tid = threadIdx.x;
  const int lane = tid & 63;
  const int wave = tid >> 6;
  const int qb = blockIdx.x;
  const int n = blockIdx.y;
  const int kvh = n >> 2;
  const int g = lane >> 4;
  const int rl = lane & 15;
  const int qrow = qb * 64 + wave * 16;

  bf16x8 qfrag[4];
  {
    const unsigned short* qp = qbf + ((size_t)(qrow + rl) * NQ + n) * H + g * 8;
#pragma unroll
    for (int ks = 0; ks < 4; ++ks) qfrag[ks] = *(const bf16x8*)(qp + ks * 32);
  }

  f32x4 oacc[8];
#pragma unroll
  for (int ob = 0; ob < 8; ++ob) oacc[ob] = (f32x4){0.f, 0.f, 0.f, 0.f};
  float mrun[4] = {-1e30f, -1e30f, -1e30f, -1e30f};
  float lrun[4] = {0.f, 0.f, 0.f, 0.f};

  const int krow = tid >> 2, kseg = (tid & 3) * 32;
  const int vh = tid >> 1, vseg = (tid & 1) * 32;

  for (int kt = 0; kt <= qb; ++kt) {
    const int kbase = kt * 64;
    __syncthreads();
    {
      const unsigned short* kp = kbf + ((size_t)(kbase + krow) * NKV + kvh) * H + kseg;
#pragma unroll
      for (int i = 0; i < 4; ++i)
        *(bf16x8*)&K_lds[krow * KLD + kseg + i * 8] = *(const bf16x8*)(kp + i * 8);
      const unsigned short* vp = vtbf + (size_t)(kvh * H + vh) * T + kbase + vseg;
#pragma unroll
      for (int i = 0; i < 4; ++i)
        *(bf16x8*)&Vt_lds[vh * VLD + vseg + i * 8] = *(const bf16x8*)(vp + i * 8);
    }
    __syncthreads();

    f32x4 sacc[4];
#pragma unroll
    for (int cb = 0; cb < 4; ++cb) sacc[cb] = (f32x4){0.f, 0.f, 0.f, 0.f};
#pragma unroll
    for (int cb = 0; cb < 4; ++cb)
#pragma unroll
      for (int ks = 0; ks < 4; ++ks) {
        bf16x8 kf = *(const bf16x8*)&K_lds[(cb * 16 + rl) * KLD + ks * 32 + g * 8];
        sacc[cb] = MFMA16(qfrag[ks], kf, sacc[cb]);
      }

    if (kt == qb) {
#pragma unroll
      for (int cb = 0; cb < 4; ++cb) {
        int kvg = cb * 16 + rl;
#pragma unroll
        for (int r = 0; r < 4; ++r) {
          int qrel = wave * 16 + g * 4 + r;
          if (kvg > qrel) sacc[cb][r] = -1e30f;
        }
      }
    }

    float mx[4], sm[4], corr[4];
#pragma unroll
    for (int r = 0; r < 4; ++r) {
      float m0 = fmaxf(fmaxf(sacc[0][r], sacc[1][r]), fmaxf(sacc[2][r], sacc[3][r]));
#pragma unroll
      for (int off = 1; off < 16; off <<= 1) m0 = fmaxf(m0, __shfl_xor(m0, off, 64));
      float nm = fmaxf(mrun[r], m0);
      corr[r] = __expf(mrun[r] - nm);
      mrun[r] = nm;
      mx[r] = nm;
    }
#pragma unroll
    for (int cb = 0; cb < 4; ++cb)
#pragma unroll
      for (int r = 0; r < 4; ++r) sacc[cb][r] = __expf(sacc[cb][r] - mx[r]);
#pragma unroll
    for (int r = 0; r < 4; ++r) {
      float s0 = sacc[0][r] + sacc[1][r] + sacc[2][r] + sacc[3][r];
#pragma unroll
      for (int off = 1; off < 16; off <<= 1) s0 += __shfl_xor(s0, off, 64);
      sm[r] = s0;
      lrun[r] = lrun[r] * corr[r] + sm[r];
    }
#pragma unroll
    for (int ob = 0; ob < 8; ++ob)
#pragma unroll
      for (int r = 0; r < 4; ++r) oacc[ob][r] *= corr[r];

#pragma unroll
    for (int cb = 0; cb < 4; ++cb)
#pragma unroll
      for (int r = 0; r < 4; ++r)
        P_lds[(wave * 16 + g * 4 + r) * PLD + cb * 16 + rl] = f2bf(sacc[cb][r]);

    bf16x8 pa[2];
#pragma unroll
    for (int ks = 0; ks < 2; ++ks)
      pa[ks] = *(const bf16x8*)&P_lds[(wave * 16 + rl) * PLD + ks * 32 + g * 8];

#pragma unroll
    for (int ob = 0; ob < 8; ++ob)
#pragma unroll
      for (int ks = 0; ks < 2; ++ks) {
        bf16x8 vf = *(const bf16x8*)&Vt_lds[(ob * 16 + rl) * VLD + ks * 32 + g * 8];
        oacc[ob] = MFMA16(pa[ks], vf, oacc[ob]);
      }
  }

  float inv[4];
#pragma unroll
  for (int r = 0; r < 4; ++r) inv[r] = 1.f / lrun[r];
#pragma unroll
  for (int ob = 0; ob < 8; ++ob)
#pragma unroll
    for (int r = 0; r < 4; ++r) {
      int t = qrow + g * 4 + r;
      out[((size_t)t * NQ + n) * H + ob * 16 + rl] = f2bf(oacc[ob][r] * inv[r]);
    }
}

extern "C" void kernel_launch(void* const* d_in, const int* in_sizes, int n_in,
                              void* d_out, int out_size, void* d_ws, size_t ws_size,
                              hipStream_t stream) {
  (void)in_sizes; (void)n_in; (void)out_size; (void)ws_size;
  const float* x = (const float*)d_in[0];
  const int* positions = (const int*)d_in[1];
  const float* ln1 = (const float*)d_in[2];
  const float* w_q = (const float*)d_in[3];
  const float* w_k = (const float*)d_in[4];
  const float* w_v = (const float*)d_in[5];
  const float* w_o = (const float*)d_in[6];
  const float* ln2 = (const float*)d_in[7];
  const float* w_gate = (const float*)d_in[8];
  const float* w_up = (const float*)d_in[9];
  const float* w_down = (const float*)d_in[10];
  float* out = (float*)d_out;

  char* ws = (char*)d_ws;
  size_t off = 0;
  auto alloc = [&](size_t bytes) {
    char* p = ws + off;
    off += (bytes + 255) & ~(size_t)255;
    return p;
  };
  unsigned short* h_bf = (unsigned short*)alloc((size_t)T * D * 2);
  unsigned short* h2_bf = (unsigned short*)alloc((size_t)T * D * 2);
  unsigned short* attn_bf = (unsigned short*)alloc((size_t)T * NQ * H * 2);
  unsigned short* act_bf = (unsigned short*)alloc((size_t)T * F * 2);
  float* qkvf = (float*)alloc((size_t)T * NQKV * 4);
  float* resid = (float*)alloc((size_t)T * D * 4);
  float* ctab = (float*)alloc((size_t)T * 64 * 4);
  float* stab = (float*)alloc((size_t)T * 64 * 4);
  unsigned short* qbf = (unsigned short*)alloc((size_t)T * NQ * H * 2);
  unsigned short* kbf = (unsigned short*)alloc((size_t)T * NKV * H * 2);
  unsigned short* vtbf = (unsigned short*)alloc((size_t)NKV * H * T * 2);
  unsigned short* wqkvt = (unsigned short*)alloc((size_t)NQKV * D * 2);
  unsigned short* wot = (unsigned short*)alloc((size_t)D * NQ * H * 2);
  unsigned short* wgut = (unsigned short*)alloc((size_t)2 * F * D * 2);
  unsigned short* wdt = (unsigned short*)alloc((size_t)D * F * 2);
  // K-split partial buffers aliased onto dead regions (each needs T*D*4 = 33.6MB)
  float* part0 = qkvf;            // qkvf: 50.3MB, dead after rope_bf16
  float* part1 = (float*)wqkvt;   // wqkvt: 50.3MB, dead after QKV GEMM

  transpose_bf16<0><<<dim3(D / 64, (NQ * H) / 64), 256, 0, stream>>>(w_q, wqkvt, D, NQ * H);
  transpose_bf16<0><<<dim3(D / 64, (NKV * H) / 64), 256, 0, stream>>>(
      w_k, wqkvt + (size_t)NQ * H * D, D, NKV * H);
  transpose_bf16<0><<<dim3(D / 64, (NKV * H) / 64), 256, 0, stream>>>(
      w_v, wqkvt + (size_t)VOFF * D, D, NKV * H);
  transpose_bf16<0><<<dim3((NQ * H) / 64, D / 64), 256, 0, stream>>>(w_o, wot, NQ * H, D);
  transpose_bf16<1><<<dim3(D / 64, F / 64), 256, 0, stream>>>(w_gate, wgut, D, F);
  transpose_bf16<2><<<dim3(D / 64, F / 64), 256, 0, stream>>>(w_up, wgut, D, F);
  transpose_bf16<0><<<dim3(F / 64, D / 64), 256, 0, stream>>>(w_down, wdt, F, D);

  rmsnorm_kernel<<<T, 256, 0, stream>>>(x, ln1, h_bf);
  rope_table<<<(T * 64) / 256, 256, 0, stream>>>(positions, ctab, stab);
  gemm_bf<4><<<dim3(T / 128, NQKV / 128), 256, 0, stream>>>(
      h_bf, wqkvt, qkvf, vtbf, D, NQKV);
  rope_bf16<<<(T * NQ * 64) / 256, 256, 0, stream>>>(qkvf, ctab, stab, qbf, NQ, NQKV,
                                                     0.08838834764831845f);
  rope_bf16<<<(T * NKV * 64) / 256, 256, 0, stream>>>(qkvf + NQ * H, ctab, stab, kbf,
                                                      NKV, NQKV, 1.0f);
  flash_attn<<<dim3(T / 64, NQ), 256, 0, stream>>>(qbf, kbf, vtbf, attn_bf);
  // O-proj: 256² K-split x2 (full machine) -> partials, then resid = p0+p1+x
  gemm256<0><<<dim3(T / 256, D / 256, 2), 512, 0, stream>>>(
      attn_bf, wot, part0, part1, nullptr, NQ * H, D, NQ * H / 2);
  add3_kernel<<<(T * D / 4) / 256, 256, 0, stream>>>(part0, part1, x, resid);
  rmsnorm_kernel<<<T, 256, 0, stream>>>(resid, ln2, h2_bf);
  // 256² 8-phase interleaved gate/up GEMM
  gemm256<5><<<dim3(T / 256, (2 * F) / 256), 512, 0, stream>>>(
      h2_bf, wgut, nullptr, nullptr, act_bf, D, 2 * F, D);
  // down-proj: 256² K-split x2 -> partials, then out = p0+p1+resid
  gemm256<0><<<dim3(T / 256, D / 256, 2), 512, 0, stream>>>(
      act_bf, wdt, part0, part1, nullptr, F, D, F / 2);
  add3_kernel<<<(T * D / 4) / 256, 256, 0, stream>>>(part0, part1, resid, out);
}

// Round 9
// 1400.851 us; speedup vs baseline: 6.9100x; 1.0412x over previous
//
#include <hip/hip_runtime.h>

typedef __attribute__((ext_vector_type(8))) short bf16x8;
typedef __attribute__((ext_vector_type(4))) float f32x4;

constexpr int T = 2048;
constexpr int D = 4096;
constexpr int NQ = 32;    // query heads
constexpr int NKV = 8;    // kv heads
constexpr int H = 128;    // head dim
constexpr int F = 14336;  // ffn dim
constexpr int NQKV = (NQ + 2 * NKV) * H;  // 6144 packed qkv cols
constexpr int VOFF = (NQ + NKV) * H;      // 5120 col offset of V

__device__ inline unsigned short f2bf(float f) {
  unsigned u = __float_as_uint(f);
  return (unsigned short)((u + 0x7FFFu + ((u >> 16) & 1u)) >> 16);
}

__device__ inline void gload_lds16(const void* g, void* l) {
  __builtin_amdgcn_global_load_lds((const __attribute__((address_space(1))) void*)g,
                                   (__attribute__((address_space(3))) void*)l, 16, 0, 0);
}

#define MFMA16(a, b, c) __builtin_amdgcn_mfma_f32_16x16x32_bf16(a, b, c, 0, 0, 0)

// ------- weight transpose+convert: (K,N) f32 -> (rowmap(N),K) bf16 -------
// MODE 0: row = n;  MODE 1: row = (n>>4)*32 + (n&15);  MODE 2: MODE1 + 16
template <int MODE>
__global__ __launch_bounds__(256) void transpose_bf16(const float* __restrict__ in,
                                                      unsigned short* __restrict__ out,
                                                      int K, int N) {
  __shared__ float tile[64 * 65];
  const int kb = blockIdx.x * 64;
  const int nb = blockIdx.y * 64;
  const int tid = threadIdx.x;
  const int r = tid >> 2;
  const int c4 = tid & 3;
#pragma unroll
  for (int i = 0; i < 4; ++i) {
    float4 v = *(const float4*)(in + (size_t)(kb + r) * N + nb + c4 * 16 + i * 4);
    *(float4*)&tile[r * 65 + c4 * 16 + i * 4] = v;
  }
  __syncthreads();
  const int n = tid >> 2;
  const int kq = tid & 3;
  int nsrc = nb + n;
  int prow = (MODE == 0) ? nsrc : ((nsrc >> 4) * 32 + (nsrc & 15) + (MODE == 2 ? 16 : 0));
#pragma unroll
  for (int half = 0; half < 2; ++half) {
    ushort4 o0, o1;
    int k0 = kq * 16 + half * 8;
    o0.x = f2bf(tile[(k0 + 0) * 65 + n]);
    o0.y = f2bf(tile[(k0 + 1) * 65 + n]);
    o0.z = f2bf(tile[(k0 + 2) * 65 + n]);
    o0.w = f2bf(tile[(k0 + 3) * 65 + n]);
    o1.x = f2bf(tile[(k0 + 4) * 65 + n]);
    o1.y = f2bf(tile[(k0 + 5) * 65 + n]);
    o1.z = f2bf(tile[(k0 + 6) * 65 + n]);
    o1.w = f2bf(tile[(k0 + 7) * 65 + n]);
    unsigned short* op = out + (size_t)prow * K + kb + k0;
    *(ushort4*)(op + 0) = o0;
    *(ushort4*)(op + 4) = o1;
  }
}

// ---------------- RMSNorm: f32 in -> bf16 out ----------------
__global__ __launch_bounds__(256) void rmsnorm_kernel(
    const float* __restrict__ in, const float* __restrict__ scale,
    unsigned short* __restrict__ out) {
  int row = blockIdx.x;
  const float4* xr = (const float4*)(in + (size_t)row * D);
  const float4* sr = (const float4*)scale;
  float4 vals[4];
  float ss = 0.f;
#pragma unroll
  for (int i = 0; i < 4; ++i) {
    float4 v = xr[threadIdx.x + i * 256];
    vals[i] = v;
    ss += v.x * v.x + v.y * v.y + v.z * v.z + v.w * v.w;
  }
#pragma unroll
  for (int off = 32; off; off >>= 1) ss += __shfl_xor(ss, off, 64);
  __shared__ float wsum[4];
  if ((threadIdx.x & 63) == 0) wsum[threadIdx.x >> 6] = ss;
  __syncthreads();
  float r = rsqrtf((wsum[0] + wsum[1] + wsum[2] + wsum[3]) * (1.f / D) + 1e-5f);
#pragma unroll
  for (int i = 0; i < 4; ++i) {
    int vi = threadIdx.x + i * 256;
    float4 v = vals[i];
    float4 s = sr[vi];
    ushort4 o;
    o.x = f2bf(v.x * r * s.x);
    o.y = f2bf(v.y * r * s.y);
    o.z = f2bf(v.z * r * s.z);
    o.w = f2bf(v.w * r * s.w);
    *(ushort4*)(out + (size_t)row * D + (size_t)vi * 4) = o;
  }
}

// ---------------- out = a + b + c (f32, vectorized) ----------------
__global__ __launch_bounds__(256) void add3_kernel(const float* __restrict__ a,
                                                   const float* __restrict__ b,
                                                   const float* __restrict__ c,
                                                   float* __restrict__ o) {
  int i = blockIdx.x * 256 + threadIdx.x;
  float4 va = ((const float4*)a)[i];
  float4 vb = ((const float4*)b)[i];
  float4 vc = ((const float4*)c)[i];
  float4 vo;
  vo.x = va.x + vb.x + vc.x;
  vo.y = va.y + vb.y + vc.y;
  vo.z = va.z + vb.z + vc.z;
  vo.w = va.w + vb.w + vc.w;
  ((float4*)o)[i] = vo;
}

// ---------------- RoPE cos/sin table ----------------
__global__ __launch_bounds__(256) void rope_table(const int* __restrict__ pos,
                                                  float* __restrict__ ctab,
                                                  float* __restrict__ stab) {
  int idx = blockIdx.x * 256 + threadIdx.x;  // T*64
  int t = idx >> 6, i = idx & 63;
  float inv = exp2f(-(float)i * (log2f(500000.0f) / 64.0f));
  float ang = (float)pos[t] * inv;
  ctab[idx] = cosf(ang);
  stab[idx] = sinf(ang);
}

// ------- RoPE apply: f32 strided in -> bf16 out (scale folded) -------
__global__ __launch_bounds__(256) void rope_bf16(const float* __restrict__ x,
                                                 const float* __restrict__ ctab,
                                                 const float* __restrict__ stab,
                                                 unsigned short* __restrict__ out,
                                                 int nheads, int row_stride, float scale) {
  int idx = blockIdx.x * 256 + threadIdx.x;  // T*nheads*64
  int i = idx & 63;
  int tn = idx >> 6;
  int t = tn / nheads;
  int n = tn - t * nheads;
  float c = ctab[t * 64 + i], s = stab[t * 64 + i];
  const float* p = x + (size_t)t * row_stride + n * H;
  float x1 = p[i], x2 = p[i + 64];
  unsigned short* o = out + (size_t)tn * H;
  o[i] = f2bf((x1 * c - x2 * s) * scale);
  o[i + 64] = f2bf((x2 * c + x1 * s) * scale);
}

// ---------------- 128x128 GEMM (m97 structure) ----------------
// EP 4: qkv: cols<VOFF -> outF f32; cols>=VOFF -> outB[(c-VOFF)*T+row] bf16
template <int EP>
__global__ __launch_bounds__(256) void gemm_bf(
    const unsigned short* __restrict__ A, const unsigned short* __restrict__ Bt0,
    float* __restrict__ outF, unsigned short* __restrict__ outB, int Kd, int Nd) {
  __shared__ unsigned short lA[128 * 32];
  __shared__ unsigned short lB0[128 * 32];

  const int tid = threadIdx.x;
  const int m0 = blockIdx.x * 128;
  const int n0 = blockIdx.y * 128;
  const int lane = tid & 63;
  const int wv = tid >> 6;

  f32x4 acc[4][4];
#pragma unroll
  for (int i = 0; i < 4; ++i)
#pragma unroll
    for (int j = 0; j < 4; ++j) acc[i][j] = (f32x4){0.f, 0.f, 0.f, 0.f};

  const int wr = (wv >> 1) * 64;
  const int wc = (wv & 1) * 64;
  const int k8 = (lane >> 4) * 8;
  const int rl = lane & 15;
  const int sidx0 = wv * 512 + lane * 8;

  for (int k0 = 0; k0 < Kd; k0 += 32) {
    __syncthreads();
#pragma unroll
    for (int it = 0; it < 2; ++it) {
      int idx = sidx0 + it * 2048;
      int row = idx >> 5, kk = idx & 31;
      int base = wv * 512 + it * 2048;
      gload_lds16(A + (size_t)(m0 + row) * Kd + k0 + kk, &lA[base]);
      gload_lds16(Bt0 + (size_t)(n0 + row) * Kd + k0 + kk, &lB0[base]);
    }
    asm volatile("s_waitcnt vmcnt(0)" ::: "memory");
    __syncthreads();

    bf16x8 af[4], bfr[4];
#pragma unroll
    for (int i = 0; i < 4; ++i)
      af[i] = *(const bf16x8*)&lA[(wr + i * 16 + rl) * 32 + k8];
#pragma unroll
    for (int j = 0; j < 4; ++j)
      bfr[j] = *(const bf16x8*)&lB0[(wc + j * 16 + rl) * 32 + k8];
#pragma unroll
    for (int i = 0; i < 4; ++i)
#pragma unroll
      for (int j = 0; j < 4; ++j)
        acc[i][j] = MFMA16(af[i], bfr[j], acc[i][j]);
  }

  const int rb = (lane >> 4) * 4;
#pragma unroll
  for (int i = 0; i < 4; ++i)
#pragma unroll
    for (int j = 0; j < 4; ++j) {
      int col = n0 + wc + j * 16 + rl;
      if (EP == 4 && n0 >= VOFF) {
        int row0 = m0 + wr + i * 16 + rb;
        ushort4 o;
        o.x = f2bf(acc[i][j][0]);
        o.y = f2bf(acc[i][j][1]);
        o.z = f2bf(acc[i][j][2]);
        o.w = f2bf(acc[i][j][3]);
        *(ushort4*)&outB[(size_t)(col - VOFF) * T + row0] = o;
      } else {
#pragma unroll
        for (int jj = 0; jj < 4; ++jj) {
          int row = m0 + wr + i * 16 + rb + jj;
          outF[(size_t)row * Nd + col] = acc[i][j][jj];
        }
      }
    }
}

// ---------------- 256x256 8-phase GEMM, K-splittable, fine-staged ----------------
// A (M,K) bf16; Bt (N,K) bf16. 8 waves (2M x 4N), per-wave 128x64. BK=64.
// LDS 128KB dbuf. Swizzle both sides: byte_col ^= (row&7)<<4.
// Staging spread 0/2/2/4 lines per phase (placement proven race-free by
// read-completion order: A-lo & B-lo complete P0, B-hi P1, A-hi P2).
// One counted vmcnt(8) per K-tile (drains kt+1, keeps kt+2 in flight).
// blockIdx.z = K-split slice (Klen per slice).
// EP 0: outF/outF2 (by z) = acc (f32)
// EP 5: Bt packed gate/up alternating 16-col groups; outB = bf16(silu(g)*u)
template <int EP>
__global__ __launch_bounds__(512, 2) void gemm256(
    const unsigned short* __restrict__ A, const unsigned short* __restrict__ Bt,
    float* __restrict__ outF, float* __restrict__ outF2,
    unsigned short* __restrict__ outB, int Kd, int Nd, int Klen) {
  __shared__ unsigned short lds[65536];
  const int tid = threadIdx.x, lane = tid & 63, wv = tid >> 6;
  const int wm = wv >> 2, wn = wv & 3;
  const int rl = lane & 15, g = lane >> 4;
  const int kz = blockIdx.z;
  // XCD-aware block swizzle within z-slice (gx*gy % 8 == 0)
  int raw = blockIdx.x + blockIdx.y * gridDim.x;
  int cpx = (gridDim.x * gridDim.y) >> 3;
  int sid = (raw & 7) * cpx + (raw >> 3);
  int brow = sid % gridDim.x;
  int bcol = sid / gridDim.x;
  const int m0 = brow * 256, n0 = bcol * 256;

  const int l8 = lane >> 3;
  const int scol = ((lane & 7) ^ l8) * 8;  // pre-swizzled global src col
  const int xr = (rl & 7) << 4;            // read-side swizzle
  const int pc0 = (g * 16) ^ xr;
  const int pc1 = (64 + g * 16) ^ xr;

  const char* ldsc = (const char*)lds;
  const unsigned short* gA = A + (size_t)(m0 + wv * 8 + l8) * Kd + kz * Klen + scol;
  const unsigned short* gB = Bt + (size_t)(n0 + wv * 8 + l8) * Kd + kz * Klen + scol;

  f32x4 acc[8][4];
#pragma unroll
  for (int i = 0; i < 8; ++i)
#pragma unroll
    for (int j = 0; j < 4; ++j) acc[i][j] = (f32x4){0.f, 0.f, 0.f, 0.f};

  const int NT = Klen >> 6;

// line l covers tile rows [l*64, l*64+64): LDS ushort off l*4096 + wv*512
#define STAGE_AL(kt, l)                                                      \
  gload_lds16(gA + (size_t)(kt) * 64 + (size_t)(l) * 64 * Kd,                \
              (void*)&lds[((kt) & 1) * 32768 + (l) * 4096 + wv * 512]);
#define STAGE_BL(kt, l)                                                      \
  gload_lds16(gB + (size_t)(kt) * 64 + (size_t)(l) * 64 * Kd,                \
              (void*)&lds[((kt) & 1) * 32768 + 16384 + (l) * 4096 + wv * 512]);
#define SBAR()                        \
  __builtin_amdgcn_sched_barrier(0);  \
  __builtin_amdgcn_s_barrier();

  // prologue: stage kt=0 and kt=1 fully, wait for kt=0's 8 lines
  STAGE_AL(0, 0); STAGE_AL(0, 1); STAGE_AL(0, 2); STAGE_AL(0, 3);
  STAGE_BL(0, 0); STAGE_BL(0, 1); STAGE_BL(0, 2); STAGE_BL(0, 3);
  STAGE_AL(1, 0); STAGE_AL(1, 1); STAGE_AL(1, 2); STAGE_AL(1, 3);
  STAGE_BL(1, 0); STAGE_BL(1, 1); STAGE_BL(1, 2); STAGE_BL(1, 3);
  asm volatile("s_waitcnt vmcnt(8)" ::: "memory");
  SBAR();

  const int bhalf = (wn >> 1) * 16384;
  const int brl = (wn & 1) * 64;

  for (int kt = 0; kt < NT; ++kt) {
    const int b = kt & 1;
    const char* aB = ldsc + b * 65536 + wm * 16384;
    const char* bB = ldsc + b * 65536 + 32768 + bhalf;
    const bool pre = (kt + 2 < NT);
    bf16x8 aLo[4][2], aHi[4][2], bLo[2][2], bHi[2][2];
    // ---- P0: read A-lo + B-lo; MFMA q0 ----
#pragma unroll
    for (int mf = 0; mf < 4; ++mf) {
      aLo[mf][0] = *(const bf16x8*)(aB + (mf * 16 + rl) * 128 + pc0);
      aLo[mf][1] = *(const bf16x8*)(aB + (mf * 16 + rl) * 128 + pc1);
    }
#pragma unroll
    for (int nf = 0; nf < 2; ++nf) {
      bLo[nf][0] = *(const bf16x8*)(bB + (brl + nf * 16 + rl) * 128 + pc0);
      bLo[nf][1] = *(const bf16x8*)(bB + (brl + nf * 16 + rl) * 128 + pc1);
    }
    SBAR();
    __builtin_amdgcn_s_setprio(1);
#pragma unroll
    for (int mf = 0; mf < 4; ++mf)
#pragma unroll
      for (int nf = 0; nf < 2; ++nf) {
        acc[mf][nf] = MFMA16(aLo[mf][0], bLo[nf][0], acc[mf][nf]);
        acc[mf][nf] = MFMA16(aLo[mf][1], bLo[nf][1], acc[mf][nf]);
      }
    __builtin_amdgcn_s_setprio(0);
    SBAR();
    // ---- P1: read B-hi; stage A-lo-row lines of kt+2; MFMA q1 ----
#pragma unroll
    for (int nf = 0; nf < 2; ++nf) {
      bHi[nf][0] = *(const bf16x8*)(bB + (brl + (nf + 2) * 16 + rl) * 128 + pc0);
      bHi[nf][1] = *(const bf16x8*)(bB + (brl + (nf + 2) * 16 + rl) * 128 + pc1);
    }
    if (pre) { STAGE_AL(kt + 2, 0); STAGE_AL(kt + 2, 2); }
    SBAR();
    __builtin_amdgcn_s_setprio(1);
#pragma unroll
    for (int mf = 0; mf < 4; ++mf)
#pragma unroll
      for (int nf = 0; nf < 2; ++nf) {
        acc[mf][nf + 2] = MFMA16(aLo[mf][0], bHi[nf][0], acc[mf][nf + 2]);
        acc[mf][nf + 2] = MFMA16(aLo[mf][1], bHi[nf][1], acc[mf][nf + 2]);
      }
    __builtin_amdgcn_s_setprio(0);
    SBAR();
    // ---- P2: read A-hi; stage B lines 0,1; MFMA q2 ----
#pragma unroll
    for (int mf = 0; mf < 4; ++mf) {
      aHi[mf][0] = *(const bf16x8*)(aB + ((mf + 4) * 16 + rl) * 128 + pc0);
      aHi[mf][1] = *(const bf16x8*)(aB + ((mf + 4) * 16 + rl) * 128 + pc1);
    }
    if (pre) { STAGE_BL(kt + 2, 0); STAGE_BL(kt + 2, 1); }
    SBAR();
    __builtin_amdgcn_s_setprio(1);
#pragma unroll
    for (int mf = 0; mf < 4; ++mf)
#pragma unroll
      for (int nf = 0; nf < 2; ++nf) {
        acc[mf + 4][nf + 2] = MFMA16(aHi[mf][0], bHi[nf][0], acc[mf + 4][nf + 2]);
        acc[mf + 4][nf + 2] = MFMA16(aHi[mf][1], bHi[nf][1], acc[mf + 4][nf + 2]);
      }
    __builtin_amdgcn_s_setprio(0);
    SBAR();
    // ---- P3: stage B lines 2,3 + A-hi-row lines; MFMA q3 (reg-only); vmcnt ----
    if (pre) {
      STAGE_BL(kt + 2, 2); STAGE_BL(kt + 2, 3);
      STAGE_AL(kt + 2, 1); STAGE_AL(kt + 2, 3);
    }
    __builtin_amdgcn_s_setprio(1);
#pragma unroll
    for (int mf = 0; mf < 4; ++mf)
#pragma unroll
      for (int nf = 0; nf < 2; ++nf) {
        acc[mf + 4][nf] = MFMA16(aHi[mf][0], bLo[nf][0], acc[mf + 4][nf]);
        acc[mf + 4][nf] = MFMA16(aHi[mf][1], bLo[nf][1], acc[mf + 4][nf]);
      }
    __builtin_amdgcn_s_setprio(0);
    if (pre) {
      asm volatile("s_waitcnt vmcnt(8)" ::: "memory");  // drain kt+1's 8 lines
    } else if (kt + 1 < NT) {
      asm volatile("s_waitcnt vmcnt(0)" ::: "memory");  // tail: drain kt+1 fully
    }
    SBAR();
  }

  const int g4 = g * 4;
  if constexpr (EP == 5) {
    const int acolBase = ((n0 + wn * 64) >> 1) + rl;
#pragma unroll
    for (int mf = 0; mf < 8; ++mf)
#pragma unroll
      for (int p = 0; p < 2; ++p) {
        int acol = acolBase + p * 16;
#pragma unroll
        for (int jj = 0; jj < 4; ++jj) {
          int row = m0 + wm * 128 + mf * 16 + g4 + jj;
          float gg = acc[mf][2 * p][jj];
          float uu = acc[mf][2 * p + 1][jj];
          outB[(size_t)row * F + acol] = f2bf(gg / (1.f + __expf(-gg)) * uu);
        }
      }
  } else {
    float* dst = kz ? outF2 : outF;
#pragma unroll
    for (int mf = 0; mf < 8; ++mf)
#pragma unroll
      for (int q = 0; q < 4; ++q) {
        int col = n0 + wn * 64 + q * 16 + rl;
#pragma unroll
        for (int jj = 0; jj < 4; ++jj) {
          int row = m0 + wm * 128 + mf * 16 + g4 + jj;
          dst[(size_t)row * Nd + col] = acc[mf][q][jj];
        }
      }
  }
#undef STAGE_AL
#undef STAGE_BL
#undef SBAR
}

// ---------------- Flash attention (MFMA) ----------------
constexpr int KLD = 136;
constexpr int VLD = 72;
constexpr int PLD = 72;

__global__ __launch_bounds__(256) void flash_attn(
    const unsigned short* __restrict__ qbf, const unsigned short* __restrict__ kbf,
    const unsigned short* __restrict__ vtbf, unsigned short* __restrict__ out) {
  __shared__ unsigned short K_lds[64 * KLD];
  __shared__ unsigned short Vt_lds[H * VLD];
  __shared__ unsigned short P_lds[4 * 16 * PLD];

  const int tid = threadIdx.x;
  const int lane = tid & 63;
  const int wave = tid >> 6;
  const int qb = blockIdx.x;
  const int n = blockIdx.y;
  const int kvh = n >> 2;
  const int g = lane >> 4;
  const int rl = lane & 15;
  const int qrow = qb * 64 + wave * 16;

  bf16x8 qfrag[4];
  {
    const unsigned short* qp = qbf + ((size_t)(qrow + rl) * NQ + n) * H + g * 8;
#pragma unroll
    for (int ks = 0; ks < 4; ++ks) qfrag[ks] = *(const bf16x8*)(qp + ks * 32);
  }

  f32x4 oacc[8];
#pragma unroll
  for (int ob = 0; ob < 8; ++ob) oacc[ob] = (f32x4){0.f, 0.f, 0.f, 0.f};
  float mrun[4] = {-1e30f, -1e30f, -1e30f, -1e30f};
  float lrun[4] = {0.f, 0.f, 0.f, 0.f};

  const int krow = tid >> 2, kseg = (tid & 3) * 32;
  const int vh = tid >> 1, vseg = (tid & 1) * 32;

  for (int kt = 0; kt <= qb; ++kt) {
    const int kbase = kt * 64;
    __syncthreads();
    {
      const unsigned short* kp = kbf + ((size_t)(kbase + krow) * NKV + kvh) * H + kseg;
#pragma unroll
      for (int i = 0; i < 4; ++i)
        *(bf16x8*)&K_lds[krow * KLD + kseg + i * 8] = *(const bf16x8*)(kp + i * 8);
      const unsigned short* vp = vtbf + (size_t)(kvh * H + vh) * T + kbase + vseg;
#pragma unroll
      for (int i = 0; i < 4; ++i)
        *(bf16x8*)&Vt_lds[vh * VLD + vseg + i * 8] = *(const bf16x8*)(vp + i * 8);
    }
    __syncthreads();

    f32x4 sacc[4];
#pragma unroll
    for (int cb = 0; cb < 4; ++cb) sacc[cb] = (f32x4){0.f, 0.f, 0.f, 0.f};
#pragma unroll
    for (int cb = 0; cb < 4; ++cb)
#pragma unroll
      for (int ks = 0; ks < 4; ++ks) {
        bf16x8 kf = *(const bf16x8*)&K_lds[(cb * 16 + rl) * KLD + ks * 32 + g * 8];
        sacc[cb] = MFMA16(qfrag[ks], kf, sacc[cb]);
      }

    if (kt == qb) {
#pragma unroll
      for (int cb = 0; cb < 4; ++cb) {
        int kvg = cb * 16 + rl;
#pragma unroll
        for (int r = 0; r < 4; ++r) {
          int qrel = wave * 16 + g * 4 + r;
          if (kvg > qrel) sacc[cb][r] = -1e30f;
        }
      }
    }

    float mx[4], sm[4], corr[4];
#pragma unroll
    for (int r = 0; r < 4; ++r) {
      float m0 = fmaxf(fmaxf(sacc[0][r], sacc[1][r]), fmaxf(sacc[2][r], sacc[3][r]));
#pragma unroll
      for (int off = 1; off < 16; off <<= 1) m0 = fmaxf(m0, __shfl_xor(m0, off, 64));
      float nm = fmaxf(mrun[r], m0);
      corr[r] = __expf(mrun[r] - nm);
      mrun[r] = nm;
      mx[r] = nm;
    }
#pragma unroll
    for (int cb = 0; cb < 4; ++cb)
#pragma unroll
      for (int r = 0; r < 4; ++r) sacc[cb][r] = __expf(sacc[cb][r] - mx[r]);
#pragma unroll
    for (int r = 0; r < 4; ++r) {
      float s0 = sacc[0][r] + sacc[1][r] + sacc[2][r] + sacc[3][r];
#pragma unroll
      for (int off = 1; off < 16; off <<= 1) s0 += __shfl_xor(s0, off, 64);
      sm[r] = s0;
      lrun[r] = lrun[r] * corr[r] + sm[r];
    }
#pragma unroll
    for (int ob = 0; ob < 8; ++ob)
#pragma unroll
      for (int r = 0; r < 4; ++r) oacc[ob][r] *= corr[r];

#pragma unroll
    for (int cb = 0; cb < 4; ++cb)
#pragma unroll
      for (int r = 0; r < 4; ++r)
        P_lds[(wave * 16 + g * 4 + r) * PLD + cb * 16 + rl] = f2bf(sacc[cb][r]);

    bf16x8 pa[2];
#pragma unroll
    for (int ks = 0; ks < 2; ++ks)
      pa[ks] = *(const bf16x8*)&P_lds[(wave * 16 + rl) * PLD + ks * 32 + g * 8];

#pragma unroll
    for (int ob = 0; ob < 8; ++ob)
#pragma unroll
      for (int ks = 0; ks < 2; ++ks) {
        bf16x8 vf = *(const bf16x8*)&Vt_lds[(ob * 16 + rl) * VLD + ks * 32 + g * 8];
        oacc[ob] = MFMA16(pa[ks], vf, oacc[ob]);
      }
  }

  float inv[4];
#pragma unroll
  for (int r = 0; r < 4; ++r) inv[r] = 1.f / lrun[r];
#pragma unroll
  for (int ob = 0; ob < 8; ++ob)
#pragma unroll
    for (int r = 0; r < 4; ++r) {
      int t = qrow + g * 4 + r;
      out[((size_t)t * NQ + n) * H + ob * 16 + rl] = f2bf(oacc[ob][r] * inv[r]);
    }
}

extern "C" void kernel_launch(void* const* d_in, const int* in_sizes, int n_in,
                              void* d_out, int out_size, void* d_ws, size_t ws_size,
                              hipStream_t stream) {
  (void)in_sizes; (void)n_in; (void)out_size; (void)ws_size;
  const float* x = (const float*)d_in[0];
  const int* positions = (const int*)d_in[1];
  const float* ln1 = (const float*)d_in[2];
  const float* w_q = (const float*)d_in[3];
  const float* w_k = (const float*)d_in[4];
  const float* w_v = (const float*)d_in[5];
  const float* w_o = (const float*)d_in[6];
  const float* ln2 = (const float*)d_in[7];
  const float* w_gate = (const float*)d_in[8];
  const float* w_up = (const float*)d_in[9];
  const float* w_down = (const float*)d_in[10];
  float* out = (float*)d_out;

  char* ws = (char*)d_ws;
  size_t off = 0;
  auto alloc = [&](size_t bytes) {
    char* p = ws + off;
    off += (bytes + 255) & ~(size_t)255;
    return p;
  };
  unsigned short* h_bf = (unsigned short*)alloc((size_t)T * D * 2);
  unsigned short* h2_bf = (unsigned short*)alloc((size_t)T * D * 2);
  unsigned short* attn_bf = (unsigned short*)alloc((size_t)T * NQ * H * 2);
  unsigned short* act_bf = (unsigned short*)alloc((size_t)T * F * 2);
  float* qkvf = (float*)alloc((size_t)T * NQKV * 4);
  float* resid = (float*)alloc((size_t)T * D * 4);
  float* ctab = (float*)alloc((size_t)T * 64 * 4);
  float* stab = (float*)alloc((size_t)T * 64 * 4);
  unsigned short* qbf = (unsigned short*)alloc((size_t)T * NQ * H * 2);
  unsigned short* kbf = (unsigned short*)alloc((size_t)T * NKV * H * 2);
  unsigned short* vtbf = (unsigned short*)alloc((size_t)NKV * H * T * 2);
  unsigned short* wqkvt = (unsigned short*)alloc((size_t)NQKV * D * 2);
  unsigned short* wot = (unsigned short*)alloc((size_t)D * NQ * H * 2);
  unsigned short* wgut = (unsigned short*)alloc((size_t)2 * F * D * 2);
  unsigned short* wdt = (unsigned short*)alloc((size_t)D * F * 2);
  // K-split partial buffers aliased onto dead regions (each needs T*D*4 = 33.6MB)
  float* part0 = qkvf;            // qkvf: 50.3MB, dead after rope_bf16
  float* part1 = (float*)wqkvt;   // wqkvt: 50.3MB, dead after QKV GEMM

  transpose_bf16<0><<<dim3(D / 64, (NQ * H) / 64), 256, 0, stream>>>(w_q, wqkvt, D, NQ * H);
  transpose_bf16<0><<<dim3(D / 64, (NKV * H) / 64), 256, 0, stream>>>(
      w_k, wqkvt + (size_t)NQ * H * D, D, NKV * H);
  transpose_bf16<0><<<dim3(D / 64, (NKV * H) / 64), 256, 0, stream>>>(
      w_v, wqkvt + (size_t)VOFF * D, D, NKV * H);
  transpose_bf16<0><<<dim3((NQ * H) / 64, D / 64), 256, 0, stream>>>(w_o, wot, NQ * H, D);
  transpose_bf16<1><<<dim3(D / 64, F / 64), 256, 0, stream>>>(w_gate, wgut, D, F);
  transpose_bf16<2><<<dim3(D / 64, F / 64), 256, 0, stream>>>(w_up, wgut, D, F);
  transpose_bf16<0><<<dim3(F / 64, D / 64), 256, 0, stream>>>(w_down, wdt, F, D);

  rmsnorm_kernel<<<T, 256, 0, stream>>>(x, ln1, h_bf);
  rope_table<<<(T * 64) / 256, 256, 0, stream>>>(positions, ctab, stab);
  gemm_bf<4><<<dim3(T / 128, NQKV / 128), 256, 0, stream>>>(
      h_bf, wqkvt, qkvf, vtbf, D, NQKV);
  rope_bf16<<<(T * NQ * 64) / 256, 256, 0, stream>>>(qkvf, ctab, stab, qbf, NQ, NQKV,
                                                     0.08838834764831845f);
  rope_bf16<<<(T * NKV * 64) / 256, 256, 0, stream>>>(qkvf + NQ * H, ctab, stab, kbf,
                                                      NKV, NQKV, 1.0f);
  flash_attn<<<dim3(T / 64, NQ), 256, 0, stream>>>(qbf, kbf, vtbf, attn_bf);
  // O-proj: 256² K-split x2 (full machine) -> partials, then resid = p0+p1+x
  gemm256<0><<<dim3(T / 256, D / 256, 2), 512, 0, stream>>>(
      attn_bf, wot, part0, part1, nullptr, NQ * H, D, NQ * H / 2);
  add3_kernel<<<(T * D / 4) / 256, 256, 0, stream>>>(part0, part1, x, resid);
  rmsnorm_kernel<<<T, 256, 0, stream>>>(resid, ln2, h2_bf);
  // 256² 8-phase interleaved gate/up GEMM
  gemm256<5><<<dim3(T / 256, (2 * F) / 256), 512, 0, stream>>>(
      h2_bf, wgut, nullptr, nullptr, act_bf, D, 2 * F, D);
  // down-proj: 256² K-split x2 -> partials, then out = p0+p1+resid
  gemm256<0><<<dim3(T / 256, D / 256, 2), 512, 0, stream>>>(
      act_bf, wdt, part0, part1, nullptr, F, D, F / 2);
  add3_kernel<<<(T * D / 4) / 256, 256, 0, stream>>>(part0, part1, resid, out);
}

// Round 10
// 1377.997 us; speedup vs baseline: 7.0246x; 1.0166x over previous
//
#include <hip/hip_runtime.h>

typedef __attribute__((ext_vector_type(8))) short bf16x8;
typedef __attribute__((ext_vector_type(4))) float f32x4;

constexpr int T = 2048;
constexpr int D = 4096;
constexpr int NQ = 32;    // query heads
constexpr int NKV = 8;    // kv heads
constexpr int H = 128;    // head dim
constexpr int F = 14336;  // ffn dim
constexpr int NQKV = (NQ + 2 * NKV) * H;  // 6144 packed qkv cols
constexpr int VOFF = (NQ + NKV) * H;      // 5120 col offset of V

__device__ inline unsigned short f2bf(float f) {
  unsigned u = __float_as_uint(f);
  return (unsigned short)((u + 0x7FFFu + ((u >> 16) & 1u)) >> 16);
}

__device__ inline void gload_lds16(const void* g, void* l) {
  __builtin_amdgcn_global_load_lds((const __attribute__((address_space(1))) void*)g,
                                   (__attribute__((address_space(3))) void*)l, 16, 0, 0);
}

#define MFMA16(a, b, c) __builtin_amdgcn_mfma_f32_16x16x32_bf16(a, b, c, 0, 0, 0)

// ------- weight transpose+convert: (K,N) f32 -> (rowmap(N),K) bf16 -------
// MODE 0: row = n;  MODE 1: row = (n>>4)*32 + (n&15);  MODE 2: MODE1 + 16
template <int MODE>
__global__ __launch_bounds__(256) void transpose_bf16(const float* __restrict__ in,
                                                      unsigned short* __restrict__ out,
                                                      int K, int N) {
  __shared__ float tile[64 * 65];
  const int kb = blockIdx.x * 64;
  const int nb = blockIdx.y * 64;
  const int tid = threadIdx.x;
  const int r = tid >> 2;
  const int c4 = tid & 3;
#pragma unroll
  for (int i = 0; i < 4; ++i) {
    float4 v = *(const float4*)(in + (size_t)(kb + r) * N + nb + c4 * 16 + i * 4);
    *(float4*)&tile[r * 65 + c4 * 16 + i * 4] = v;
  }
  __syncthreads();
  const int n = tid >> 2;
  const int kq = tid & 3;
  int nsrc = nb + n;
  int prow = (MODE == 0) ? nsrc : ((nsrc >> 4) * 32 + (nsrc & 15) + (MODE == 2 ? 16 : 0));
#pragma unroll
  for (int half = 0; half < 2; ++half) {
    ushort4 o0, o1;
    int k0 = kq * 16 + half * 8;
    o0.x = f2bf(tile[(k0 + 0) * 65 + n]);
    o0.y = f2bf(tile[(k0 + 1) * 65 + n]);
    o0.z = f2bf(tile[(k0 + 2) * 65 + n]);
    o0.w = f2bf(tile[(k0 + 3) * 65 + n]);
    o1.x = f2bf(tile[(k0 + 4) * 65 + n]);
    o1.y = f2bf(tile[(k0 + 5) * 65 + n]);
    o1.z = f2bf(tile[(k0 + 6) * 65 + n]);
    o1.w = f2bf(tile[(k0 + 7) * 65 + n]);
    unsigned short* op = out + (size_t)prow * K + kb + k0;
    *(ushort4*)(op + 0) = o0;
    *(ushort4*)(op + 4) = o1;
  }
}

// ---------------- RMSNorm: f32 in -> bf16 out ----------------
__global__ __launch_bounds__(256) void rmsnorm_kernel(
    const float* __restrict__ in, const float* __restrict__ scale,
    unsigned short* __restrict__ out) {
  int row = blockIdx.x;
  const float4* xr = (const float4*)(in + (size_t)row * D);
  const float4* sr = (const float4*)scale;
  float4 vals[4];
  float ss = 0.f;
#pragma unroll
  for (int i = 0; i < 4; ++i) {
    float4 v = xr[threadIdx.x + i * 256];
    vals[i] = v;
    ss += v.x * v.x + v.y * v.y + v.z * v.z + v.w * v.w;
  }
#pragma unroll
  for (int off = 32; off; off >>= 1) ss += __shfl_xor(ss, off, 64);
  __shared__ float wsum[4];
  if ((threadIdx.x & 63) == 0) wsum[threadIdx.x >> 6] = ss;
  __syncthreads();
  float r = rsqrtf((wsum[0] + wsum[1] + wsum[2] + wsum[3]) * (1.f / D) + 1e-5f);
#pragma unroll
  for (int i = 0; i < 4; ++i) {
    int vi = threadIdx.x + i * 256;
    float4 v = vals[i];
    float4 s = sr[vi];
    ushort4 o;
    o.x = f2bf(v.x * r * s.x);
    o.y = f2bf(v.y * r * s.y);
    o.z = f2bf(v.z * r * s.z);
    o.w = f2bf(v.w * r * s.w);
    *(ushort4*)(out + (size_t)row * D + (size_t)vi * 4) = o;
  }
}

// ------- fused: resid = a+b+c (f32 out) ; h2 = rmsnorm(resid)*scale (bf16 out) -------
__global__ __launch_bounds__(256) void rmsnorm_add3(
    const float* __restrict__ a, const float* __restrict__ b,
    const float* __restrict__ c, const float* __restrict__ scale,
    float* __restrict__ residOut, unsigned short* __restrict__ out) {
  int row = blockIdx.x;
  const float4* ar = (const float4*)(a + (size_t)row * D);
  const float4* br = (const float4*)(b + (size_t)row * D);
  const float4* cr = (const float4*)(c + (size_t)row * D);
  const float4* sr = (const float4*)scale;
  float4* rr = (float4*)(residOut + (size_t)row * D);
  float4 vals[4];
  float ss = 0.f;
#pragma unroll
  for (int i = 0; i < 4; ++i) {
    int vi = threadIdx.x + i * 256;
    float4 va = ar[vi], vb = br[vi], vc = cr[vi];
    float4 v;
    v.x = va.x + vb.x + vc.x;
    v.y = va.y + vb.y + vc.y;
    v.z = va.z + vb.z + vc.z;
    v.w = va.w + vb.w + vc.w;
    vals[i] = v;
    ss += v.x * v.x + v.y * v.y + v.z * v.z + v.w * v.w;
  }
#pragma unroll
  for (int off = 32; off; off >>= 1) ss += __shfl_xor(ss, off, 64);
  __shared__ float wsum[4];
  if ((threadIdx.x & 63) == 0) wsum[threadIdx.x >> 6] = ss;
  __syncthreads();
  float r = rsqrtf((wsum[0] + wsum[1] + wsum[2] + wsum[3]) * (1.f / D) + 1e-5f);
#pragma unroll
  for (int i = 0; i < 4; ++i) {
    int vi = threadIdx.x + i * 256;
    float4 v = vals[i];
    rr[vi] = v;
    float4 s = sr[vi];
    ushort4 o;
    o.x = f2bf(v.x * r * s.x);
    o.y = f2bf(v.y * r * s.y);
    o.z = f2bf(v.z * r * s.z);
    o.w = f2bf(v.w * r * s.w);
    *(ushort4*)(out + (size_t)row * D + (size_t)vi * 4) = o;
  }
}

// ---------------- out = a + b + c (f32, vectorized) ----------------
__global__ __launch_bounds__(256) void add3_kernel(const float* __restrict__ a,
                                                   const float* __restrict__ b,
                                                   const float* __restrict__ c,
                                                   float* __restrict__ o) {
  int i = blockIdx.x * 256 + threadIdx.x;
  float4 va = ((const float4*)a)[i];
  float4 vb = ((const float4*)b)[i];
  float4 vc = ((const float4*)c)[i];
  float4 vo;
  vo.x = va.x + vb.x + vc.x;
  vo.y = va.y + vb.y + vc.y;
  vo.z = va.z + vb.z + vc.z;
  vo.w = va.w + vb.w + vc.w;
  ((float4*)o)[i] = vo;
}

// ---------------- RoPE cos/sin table ----------------
__global__ __launch_bounds__(256) void rope_table(const int* __restrict__ pos,
                                                  float* __restrict__ ctab,
                                                  float* __restrict__ stab) {
  int idx = blockIdx.x * 256 + threadIdx.x;  // T*64
  int t = idx >> 6, i = idx & 63;
  float inv = exp2f(-(float)i * (log2f(500000.0f) / 64.0f));
  float ang = (float)pos[t] * inv;
  ctab[idx] = cosf(ang);
  stab[idx] = sinf(ang);
}

// ------- RoPE apply: f32 strided in -> bf16 out (scale folded) -------
__global__ __launch_bounds__(256) void rope_bf16(const float* __restrict__ x,
                                                 const float* __restrict__ ctab,
                                                 const float* __restrict__ stab,
                                                 unsigned short* __restrict__ out,
                                                 int nheads, int row_stride, float scale) {
  int idx = blockIdx.x * 256 + threadIdx.x;  // T*nheads*64
  int i = idx & 63;
  int tn = idx >> 6;
  int t = tn / nheads;
  int n = tn - t * nheads;
  float c = ctab[t * 64 + i], s = stab[t * 64 + i];
  const float* p = x + (size_t)t * row_stride + n * H;
  float x1 = p[i], x2 = p[i + 64];
  unsigned short* o = out + (size_t)tn * H;
  o[i] = f2bf((x1 * c - x2 * s) * scale);
  o[i + 64] = f2bf((x2 * c + x1 * s) * scale);
}

// ---------------- 128x128 GEMM (m97 structure) ----------------
// EP 4: qkv: cols<VOFF -> outF f32; cols>=VOFF -> outB[(c-VOFF)*T+row] bf16
template <int EP>
__global__ __launch_bounds__(256) void gemm_bf(
    const unsigned short* __restrict__ A, const unsigned short* __restrict__ Bt0,
    float* __restrict__ outF, unsigned short* __restrict__ outB, int Kd, int Nd) {
  __shared__ unsigned short lA[128 * 32];
  __shared__ unsigned short lB0[128 * 32];

  const int tid = threadIdx.x;
  const int m0 = blockIdx.x * 128;
  const int n0 = blockIdx.y * 128;
  const int lane = tid & 63;
  const int wv = tid >> 6;

  f32x4 acc[4][4];
#pragma unroll
  for (int i = 0; i < 4; ++i)
#pragma unroll
    for (int j = 0; j < 4; ++j) acc[i][j] = (f32x4){0.f, 0.f, 0.f, 0.f};

  const int wr = (wv >> 1) * 64;
  const int wc = (wv & 1) * 64;
  const int k8 = (lane >> 4) * 8;
  const int rl = lane & 15;
  const int sidx0 = wv * 512 + lane * 8;

  for (int k0 = 0; k0 < Kd; k0 += 32) {
    __syncthreads();
#pragma unroll
    for (int it = 0; it < 2; ++it) {
      int idx = sidx0 + it * 2048;
      int row = idx >> 5, kk = idx & 31;
      int base = wv * 512 + it * 2048;
      gload_lds16(A + (size_t)(m0 + row) * Kd + k0 + kk, &lA[base]);
      gload_lds16(Bt0 + (size_t)(n0 + row) * Kd + k0 + kk, &lB0[base]);
    }
    asm volatile("s_waitcnt vmcnt(0)" ::: "memory");
    __syncthreads();

    bf16x8 af[4], bfr[4];
#pragma unroll
    for (int i = 0; i < 4; ++i)
      af[i] = *(const bf16x8*)&lA[(wr + i * 16 + rl) * 32 + k8];
#pragma unroll
    for (int j = 0; j < 4; ++j)
      bfr[j] = *(const bf16x8*)&lB0[(wc + j * 16 + rl) * 32 + k8];
#pragma unroll
    for (int i = 0; i < 4; ++i)
#pragma unroll
      for (int j = 0; j < 4; ++j)
        acc[i][j] = MFMA16(af[i], bfr[j], acc[i][j]);
  }

  const int rb = (lane >> 4) * 4;
#pragma unroll
  for (int i = 0; i < 4; ++i)
#pragma unroll
    for (int j = 0; j < 4; ++j) {
      int col = n0 + wc + j * 16 + rl;
      if (EP == 4 && n0 >= VOFF) {
        int row0 = m0 + wr + i * 16 + rb;
        ushort4 o;
        o.x = f2bf(acc[i][j][0]);
        o.y = f2bf(acc[i][j][1]);
        o.z = f2bf(acc[i][j][2]);
        o.w = f2bf(acc[i][j][3]);
        *(ushort4*)&outB[(size_t)(col - VOFF) * T + row0] = o;
      } else {
#pragma unroll
        for (int jj = 0; jj < 4; ++jj) {
          int row = m0 + wr + i * 16 + rb + jj;
          outF[(size_t)row * Nd + col] = acc[i][j][jj];
        }
      }
    }
}

// ---------------- 256x256 8-phase GEMM, K-splittable ----------------
// A (M,K) bf16; Bt (N,K) bf16. 8 waves (2M x 4N), per-wave 128x64. BK=64.
// LDS 128KB dbuf. Swizzle both sides: byte_col ^= (row&7)<<4.
// Even ds_read spread 8/4/8/4 via cross-tile B-lo pre-read in P3.
// Single vmcnt(6) per K-tile at P2 (before its barrier): leaves only kt+2's
// 6 newest loads outstanding => all kt+1 data block-wide landed for P3's
// pre-read and kt+1's reads. Tail: vmcnt(0) when no prefetch issued.
// EP 0: outF/outF2 (by blockIdx.z) = acc (f32)
// EP 5: Bt packed gate/up alternating 16-col groups; outB = bf16(silu(g)*u)
template <int EP>
__global__ __launch_bounds__(512, 2) void gemm256(
    const unsigned short* __restrict__ A, const unsigned short* __restrict__ Bt,
    float* __restrict__ outF, float* __restrict__ outF2,
    unsigned short* __restrict__ outB, int Kd, int Nd, int Klen) {
  __shared__ unsigned short lds[65536];
  const int tid = threadIdx.x, lane = tid & 63, wv = tid >> 6;
  const int wm = wv >> 2, wn = wv & 3;
  const int rl = lane & 15, g = lane >> 4;
  const int kz = blockIdx.z;
  // XCD-aware block swizzle within z-slice (gx*gy % 8 == 0)
  int raw = blockIdx.x + blockIdx.y * gridDim.x;
  int cpx = (gridDim.x * gridDim.y) >> 3;
  int sid = (raw & 7) * cpx + (raw >> 3);
  int brow = sid % gridDim.x;
  int bcol = sid / gridDim.x;
  const int m0 = brow * 256, n0 = bcol * 256;

  const int l8 = lane >> 3;
  const int scol = ((lane & 7) ^ l8) * 8;  // pre-swizzled global src col
  const int xr = (rl & 7) << 4;            // read-side swizzle
  const int pc0 = (g * 16) ^ xr;
  const int pc1 = (64 + g * 16) ^ xr;

  const char* ldsc = (const char*)lds;
  const unsigned short* gA = A + (size_t)(m0 + wv * 8 + l8) * Kd + kz * Klen + scol;
  const unsigned short* gB = Bt + (size_t)(n0 + wv * 8 + l8) * Kd + kz * Klen + scol;

  f32x4 acc[8][4];
#pragma unroll
  for (int i = 0; i < 8; ++i)
#pragma unroll
    for (int j = 0; j < 4; ++j) acc[i][j] = (f32x4){0.f, 0.f, 0.f, 0.f};

  const int NT = Klen >> 6;

// line l covers tile rows [l*64, l*64+64): LDS ushort off l*4096 + wv*512
#define STAGE_AL(kt, l)                                                      \
  gload_lds16(gA + (size_t)(kt) * 64 + (size_t)(l) * 64 * Kd,                \
              (void*)&lds[((kt) & 1) * 32768 + (l) * 4096 + wv * 512]);
#define STAGE_BL(kt, l)                                                      \
  gload_lds16(gB + (size_t)(kt) * 64 + (size_t)(l) * 64 * Kd,                \
              (void*)&lds[((kt) & 1) * 32768 + 16384 + (l) * 4096 + wv * 512]);
#define SBAR()                        \
  __builtin_amdgcn_sched_barrier(0);  \
  __builtin_amdgcn_s_barrier();

  // prologue: stage kt=0 and kt=1 fully, drain kt=0's 8 lines
  STAGE_AL(0, 0); STAGE_AL(0, 1); STAGE_AL(0, 2); STAGE_AL(0, 3);
  STAGE_BL(0, 0); STAGE_BL(0, 1); STAGE_BL(0, 2); STAGE_BL(0, 3);
  STAGE_AL(1, 0); STAGE_AL(1, 1); STAGE_AL(1, 2); STAGE_AL(1, 3);
  STAGE_BL(1, 0); STAGE_BL(1, 1); STAGE_BL(1, 2); STAGE_BL(1, 3);
  asm volatile("s_waitcnt vmcnt(8)" ::: "memory");
  SBAR();

  const int bhalf = (wn >> 1) * 16384;
  const int brl = (wn & 1) * 64;

  // pre-read B-lo of kt=0 (buffer 0; landed block-wide after prologue barrier)
  bf16x8 bLoC[2][2];
  {
    const char* bB0 = ldsc + 32768 + bhalf;
#pragma unroll
    for (int nf = 0; nf < 2; ++nf) {
      bLoC[nf][0] = *(const bf16x8*)(bB0 + (brl + nf * 16 + rl) * 128 + pc0);
      bLoC[nf][1] = *(const bf16x8*)(bB0 + (brl + nf * 16 + rl) * 128 + pc1);
    }
  }

  for (int kt = 0; kt < NT; ++kt) {
    const int b = kt & 1;
    const char* aB = ldsc + b * 65536 + wm * 16384;
    const char* bB = ldsc + b * 65536 + 32768 + bhalf;
    const char* bBn = ldsc + (b ^ 1) * 65536 + 32768 + bhalf;
    const bool pre = (kt + 2 < NT);
    bf16x8 aLo[4][2], aHi[4][2], bHi[2][2], bLoN[2][2];
    // ---- P0: read A-lo (8); MFMA q0 = aLo x bLoC ----
#pragma unroll
    for (int mf = 0; mf < 4; ++mf) {
      aLo[mf][0] = *(const bf16x8*)(aB + (mf * 16 + rl) * 128 + pc0);
      aLo[mf][1] = *(const bf16x8*)(aB + (mf * 16 + rl) * 128 + pc1);
    }
    SBAR();
    __builtin_amdgcn_s_setprio(1);
#pragma unroll
    for (int mf = 0; mf < 4; ++mf)
#pragma unroll
      for (int nf = 0; nf < 2; ++nf) {
        acc[mf][nf] = MFMA16(aLo[mf][0], bLoC[nf][0], acc[mf][nf]);
        acc[mf][nf] = MFMA16(aLo[mf][1], bLoC[nf][1], acc[mf][nf]);
      }
    __builtin_amdgcn_s_setprio(0);
    SBAR();
    // ---- P1: read B-hi (4); stage A(kt+2) lo-lines; MFMA q1 ----
#pragma unroll
    for (int nf = 0; nf < 2; ++nf) {
      bHi[nf][0] = *(const bf16x8*)(bB + (brl + (nf + 2) * 16 + rl) * 128 + pc0);
      bHi[nf][1] = *(const bf16x8*)(bB + (brl + (nf + 2) * 16 + rl) * 128 + pc1);
    }
    if (pre) { STAGE_AL(kt + 2, 0); STAGE_AL(kt + 2, 2); }
    SBAR();
    __builtin_amdgcn_s_setprio(1);
#pragma unroll
    for (int mf = 0; mf < 4; ++mf)
#pragma unroll
      for (int nf = 0; nf < 2; ++nf) {
        acc[mf][nf + 2] = MFMA16(aLo[mf][0], bHi[nf][0], acc[mf][nf + 2]);
        acc[mf][nf + 2] = MFMA16(aLo[mf][1], bHi[nf][1], acc[mf][nf + 2]);
      }
    __builtin_amdgcn_s_setprio(0);
    SBAR();
    // ---- P2: read A-hi (8); stage B(kt+2) all 4 lines; vmcnt; MFMA q2 ----
#pragma unroll
    for (int mf = 0; mf < 4; ++mf) {
      aHi[mf][0] = *(const bf16x8*)(aB + ((mf + 4) * 16 + rl) * 128 + pc0);
      aHi[mf][1] = *(const bf16x8*)(aB + ((mf + 4) * 16 + rl) * 128 + pc1);
    }
    if (pre) {
      STAGE_BL(kt + 2, 0); STAGE_BL(kt + 2, 1);
      STAGE_BL(kt + 2, 2); STAGE_BL(kt + 2, 3);
      asm volatile("s_waitcnt vmcnt(6)" ::: "memory");  // drain all kt+1 lines
    } else {
      asm volatile("s_waitcnt vmcnt(0)" ::: "memory");  // tail: drain everything
    }
    SBAR();
    __builtin_amdgcn_s_setprio(1);
#pragma unroll
    for (int mf = 0; mf < 4; ++mf)
#pragma unroll
      for (int nf = 0; nf < 2; ++nf) {
        acc[mf + 4][nf + 2] = MFMA16(aHi[mf][0], bHi[nf][0], acc[mf + 4][nf + 2]);
        acc[mf + 4][nf + 2] = MFMA16(aHi[mf][1], bHi[nf][1], acc[mf + 4][nf + 2]);
      }
    __builtin_amdgcn_s_setprio(0);
    SBAR();
    // ---- P3: stage A(kt+2) hi-lines; pre-read B-lo(kt+1) (4); MFMA q3 ----
    if (pre) { STAGE_AL(kt + 2, 1); STAGE_AL(kt + 2, 3); }
    if (kt + 1 < NT) {
#pragma unroll
      for (int nf = 0; nf < 2; ++nf) {
        bLoN[nf][0] = *(const bf16x8*)(bBn + (brl + nf * 16 + rl) * 128 + pc0);
        bLoN[nf][1] = *(const bf16x8*)(bBn + (brl + nf * 16 + rl) * 128 + pc1);
      }
    }
    SBAR();
    __builtin_amdgcn_s_setprio(1);
#pragma unroll
    for (int mf = 0; mf < 4; ++mf)
#pragma unroll
      for (int nf = 0; nf < 2; ++nf) {
        acc[mf + 4][nf] = MFMA16(aHi[mf][0], bLoC[nf][0], acc[mf + 4][nf]);
        acc[mf + 4][nf] = MFMA16(aHi[mf][1], bLoC[nf][1], acc[mf + 4][nf]);
      }
    __builtin_amdgcn_s_setprio(0);
    SBAR();
    if (kt + 1 < NT) {
#pragma unroll
      for (int nf = 0; nf < 2; ++nf) {
        bLoC[nf][0] = bLoN[nf][0];
        bLoC[nf][1] = bLoN[nf][1];
      }
    }
  }

  const int g4 = g * 4;
  if constexpr (EP == 5) {
    const int acolBase = ((n0 + wn * 64) >> 1) + rl;
#pragma unroll
    for (int mf = 0; mf < 8; ++mf)
#pragma unroll
      for (int p = 0; p < 2; ++p) {
        int acol = acolBase + p * 16;
#pragma unroll
        for (int jj = 0; jj < 4; ++jj) {
          int row = m0 + wm * 128 + mf * 16 + g4 + jj;
          float gg = acc[mf][2 * p][jj];
          float uu = acc[mf][2 * p + 1][jj];
          outB[(size_t)row * F + acol] = f2bf(gg / (1.f + __expf(-gg)) * uu);
        }
      }
  } else {
    float* dst = kz ? outF2 : outF;
#pragma unroll
    for (int mf = 0; mf < 8; ++mf)
#pragma unroll
      for (int q = 0; q < 4; ++q) {
        int col = n0 + wn * 64 + q * 16 + rl;
#pragma unroll
        for (int jj = 0; jj < 4; ++jj) {
          int row = m0 + wm * 128 + mf * 16 + g4 + jj;
          dst[(size_t)row * Nd + col] = acc[mf][q][jj];
        }
      }
  }
#undef STAGE_AL
#undef STAGE_BL
#undef SBAR
}

// ---------------- Flash attention (MFMA), GQA group-shared K/V ----------------
// Block: 32 q-rows x one KV group (4 heads). 8 waves (512 thr):
// wv&3 = head-in-group, wv>>2 = 16-row half. K/V staged once per block.
constexpr int KLD = 136;
constexpr int VLD = 72;
constexpr int PLD = 72;

__global__ __launch_bounds__(512) void flash_attn(
    const unsigned short* __restrict__ qbf, const unsigned short* __restrict__ kbf,
    const unsigned short* __restrict__ vtbf, unsigned short* __restrict__ out) {
  __shared__ unsigned short K_lds[64 * KLD];
  __shared__ unsigned short Vt_lds[H * VLD];
  __shared__ unsigned short P_lds[8 * 16 * PLD];

  const int tid = threadIdx.x;
  const int lane = tid & 63;
  const int wv = tid >> 6;
  const int qb = blockIdx.x;   // 32-row q block
  const int kvh = blockIdx.y;  // kv head
  const int qh = wv & 3, rh = wv >> 2;
  const int n = kvh * 4 + qh;
  const int g = lane >> 4;
  const int rl = lane & 15;
  const int qrow = qb * 32 + rh * 16;

  bf16x8 qfrag[4];
  {
    const unsigned short* qp = qbf + ((size_t)(qrow + rl) * NQ + n) * H + g * 8;
#pragma unroll
    for (int ks = 0; ks < 4; ++ks) qfrag[ks] = *(const bf16x8*)(qp + ks * 32);
  }

  f32x4 oacc[8];
#pragma unroll
  for (int ob = 0; ob < 8; ++ob) oacc[ob] = (f32x4){0.f, 0.f, 0.f, 0.f};
  float mrun[4] = {-1e30f, -1e30f, -1e30f, -1e30f};
  float lrun[4] = {0.f, 0.f, 0.f, 0.f};

  // staging maps (512 threads): K 64x128, Vt 128x64, 16 cols/thread each
  const int krow = tid >> 3, kseg = (tid & 7) * 16;
  const int vh = tid >> 2, vseg = (tid & 3) * 16;

  const int ktmax = (qb * 32 + 31) >> 6;
  for (int kt = 0; kt <= ktmax; ++kt) {
    const int kbase = kt * 64;
    __syncthreads();
    {
      const unsigned short* kp = kbf + ((size_t)(kbase + krow) * NKV + kvh) * H + kseg;
      *(bf16x8*)&K_lds[krow * KLD + kseg] = *(const bf16x8*)kp;
      *(bf16x8*)&K_lds[krow * KLD + kseg + 8] = *(const bf16x8*)(kp + 8);
      const unsigned short* vp = vtbf + (size_t)(kvh * H + vh) * T + kbase + vseg;
      *(bf16x8*)&Vt_lds[vh * VLD + vseg] = *(const bf16x8*)vp;
      *(bf16x8*)&Vt_lds[vh * VLD + vseg + 8] = *(const bf16x8*)(vp + 8);
    }
    __syncthreads();

    f32x4 sacc[4];
#pragma unroll
    for (int cb = 0; cb < 4; ++cb) sacc[cb] = (f32x4){0.f, 0.f, 0.f, 0.f};
#pragma unroll
    for (int cb = 0; cb < 4; ++cb)
#pragma unroll
      for (int ks = 0; ks < 4; ++ks) {
        bf16x8 kf = *(const bf16x8*)&K_lds[(cb * 16 + rl) * KLD + ks * 32 + g * 8];
        sacc[cb] = MFMA16(qfrag[ks], kf, sacc[cb]);
      }

    if (kt == ktmax) {  // causal mask, absolute indices
#pragma unroll
      for (int cb = 0; cb < 4; ++cb) {
        int kv_abs = kbase + cb * 16 + rl;
#pragma unroll
        for (int r = 0; r < 4; ++r) {
          if (kv_abs > qrow + g * 4 + r) sacc[cb][r] = -1e30f;
        }
      }
    }

    float mx[4], sm[4], corr[4];
#pragma unroll
    for (int r = 0; r < 4; ++r) {
      float m0 = fmaxf(fmaxf(sacc[0][r], sacc[1][r]), fmaxf(sacc[2][r], sacc[3][r]));
#pragma unroll
      for (int off = 1; off < 16; off <<= 1) m0 = fmaxf(m0, __shfl_xor(m0, off, 64));
      float nm = fmaxf(mrun[r], m0);
      corr[r] = __expf(mrun[r] - nm);
      mrun[r] = nm;
      mx[r] = nm;
    }
#pragma unroll
    for (int cb = 0; cb < 4; ++cb)
#pragma unroll
      for (int r = 0; r < 4; ++r) sacc[cb][r] = __expf(sacc[cb][r] - mx[r]);
#pragma unroll
    for (int r = 0; r < 4; ++r) {
      float s0 = sacc[0][r] + sacc[1][r] + sacc[2][r] + sacc[3][r];
#pragma unroll
      for (int off = 1; off < 16; off <<= 1) s0 += __shfl_xor(s0, off, 64);
      sm[r] = s0;
      lrun[r] = lrun[r] * corr[r] + sm[r];
    }
#pragma unroll
    for (int ob = 0; ob < 8; ++ob)
#pragma unroll
      for (int r = 0; r < 4; ++r) oacc[ob][r] *= corr[r];

#pragma unroll
    for (int cb = 0; cb < 4; ++cb)
#pragma unroll
      for (int r = 0; r < 4; ++r)
        P_lds[(wv * 16 + g * 4 + r) * PLD + cb * 16 + rl] = f2bf(sacc[cb][r]);

    bf16x8 pa[2];
#pragma unroll
    for (int ks = 0; ks < 2; ++ks)
      pa[ks] = *(const bf16x8*)&P_lds[(wv * 16 + rl) * PLD + ks * 32 + g * 8];

#pragma unroll
    for (int ob = 0; ob < 8; ++ob)
#pragma unroll
      for (int ks = 0; ks < 2; ++ks) {
        bf16x8 vf = *(const bf16x8*)&Vt_lds[(ob * 16 + rl) * VLD + ks * 32 + g * 8];
        oacc[ob] = MFMA16(pa[ks], vf, oacc[ob]);
      }
  }

  float inv[4];
#pragma unroll
  for (int r = 0; r < 4; ++r) inv[r] = 1.f / lrun[r];
#pragma unroll
  for (int ob = 0; ob < 8; ++ob)
#pragma unroll
    for (int r = 0; r < 4; ++r) {
      int t = qrow + g * 4 + r;
      out[((size_t)t * NQ + n) * H + ob * 16 + rl] = f2bf(oacc[ob][r] * inv[r]);
    }
}

extern "C" void kernel_launch(void* const* d_in, const int* in_sizes, int n_in,
                              void* d_out, int out_size, void* d_ws, size_t ws_size,
                              hipStream_t stream) {
  (void)in_sizes; (void)n_in; (void)out_size; (void)ws_size;
  const float* x = (const float*)d_in[0];
  const int* positions = (const int*)d_in[1];
  const float* ln1 = (const float*)d_in[2];
  const float* w_q = (const float*)d_in[3];
  const float* w_k = (const float*)d_in[4];
  const float* w_v = (const float*)d_in[5];
  const float* w_o = (const float*)d_in[6];
  const float* ln2 = (const float*)d_in[7];
  const float* w_gate = (const float*)d_in[8];
  const float* w_up = (const float*)d_in[9];
  const float* w_down = (const float*)d_in[10];
  float* out = (float*)d_out;

  char* ws = (char*)d_ws;
  size_t off = 0;
  auto alloc = [&](size_t bytes) {
    char* p = ws + off;
    off += (bytes + 255) & ~(size_t)255;
    return p;
  };
  unsigned short* h_bf = (unsigned short*)alloc((size_t)T * D * 2);
  unsigned short* h2_bf = (unsigned short*)alloc((size_t)T * D * 2);
  unsigned short* attn_bf = (unsigned short*)alloc((size_t)T * NQ * H * 2);
  unsigned short* act_bf = (unsigned short*)alloc((size_t)T * F * 2);
  float* qkvf = (float*)alloc((size_t)T * NQKV * 4);
  float* resid = (float*)alloc((size_t)T * D * 4);
  float* ctab = (float*)alloc((size_t)T * 64 * 4);
  float* stab = (float*)alloc((size_t)T * 64 * 4);
  unsigned short* qbf = (unsigned short*)alloc((size_t)T * NQ * H * 2);
  unsigned short* kbf = (unsigned short*)alloc((size_t)T * NKV * H * 2);
  unsigned short* vtbf = (unsigned short*)alloc((size_t)NKV * H * T * 2);
  unsigned short* wqkvt = (unsigned short*)alloc((size_t)NQKV * D * 2);
  unsigned short* wot = (unsigned short*)alloc((size_t)D * NQ * H * 2);
  unsigned short* wgut = (unsigned short*)alloc((size_t)2 * F * D * 2);
  unsigned short* wdt = (unsigned short*)alloc((size_t)D * F * 2);
  // K-split partial buffers aliased onto dead regions (each needs T*D*4 = 33.6MB)
  float* part0 = qkvf;            // qkvf: 50.3MB, dead after rope_bf16
  float* part1 = (float*)wqkvt;   // wqkvt: 50.3MB, dead after QKV GEMM

  transpose_bf16<0><<<dim3(D / 64, (NQ * H) / 64), 256, 0, stream>>>(w_q, wqkvt, D, NQ * H);
  transpose_bf16<0><<<dim3(D / 64, (NKV * H) / 64), 256, 0, stream>>>(
      w_k, wqkvt + (size_t)NQ * H * D, D, NKV * H);
  transpose_bf16<0><<<dim3(D / 64, (NKV * H) / 64), 256, 0, stream>>>(
      w_v, wqkvt + (size_t)VOFF * D, D, NKV * H);
  transpose_bf16<0><<<dim3((NQ * H) / 64, D / 64), 256, 0, stream>>>(w_o, wot, NQ * H, D);
  transpose_bf16<1><<<dim3(D / 64, F / 64), 256, 0, stream>>>(w_gate, wgut, D, F);
  transpose_bf16<2><<<dim3(D / 64, F / 64), 256, 0, stream>>>(w_up, wgut, D, F);
  transpose_bf16<0><<<dim3(F / 64, D / 64), 256, 0, stream>>>(w_down, wdt, F, D);

  rmsnorm_kernel<<<T, 256, 0, stream>>>(x, ln1, h_bf);
  rope_table<<<(T * 64) / 256, 256, 0, stream>>>(positions, ctab, stab);
  gemm_bf<4><<<dim3(T / 128, NQKV / 128), 256, 0, stream>>>(
      h_bf, wqkvt, qkvf, vtbf, D, NQKV);
  rope_bf16<<<(T * NQ * 64) / 256, 256, 0, stream>>>(qkvf, ctab, stab, qbf, NQ, NQKV,
                                                     0.08838834764831845f);
  rope_bf16<<<(T * NKV * 64) / 256, 256, 0, stream>>>(qkvf + NQ * H, ctab, stab, kbf,
                                                      NKV, NQKV, 1.0f);
  flash_attn<<<dim3(T / 32, NKV), 512, 0, stream>>>(qbf, kbf, vtbf, attn_bf);
  // O-proj: 256² K-split x2 (full machine) -> partials
  gemm256<0><<<dim3(T / 256, D / 256, 2), 512, 0, stream>>>(
      attn_bf, wot, part0, part1, nullptr, NQ * H, D, NQ * H / 2);
  // fused: resid = p0+p1+x ; h2 = rmsnorm(resid)*ln2
  rmsnorm_add3<<<T, 256, 0, stream>>>(part0, part1, x, ln2, resid, h2_bf);
  // 256² 8-phase interleaved gate/up GEMM
  gemm256<5><<<dim3(T / 256, (2 * F) / 256), 512, 0, stream>>>(
      h2_bf, wgut, nullptr, nullptr, act_bf, D, 2 * F, D);
  // down-proj: 256² K-split x2 -> partials, then out = p0+p1+resid
  gemm256<0><<<dim3(T / 256, D / 256, 2), 512, 0, stream>>>(
      act_bf, wdt, part0, part1, nullptr, F, D, F / 2);
  add3_kernel<<<(T * D / 4) / 256, 256, 0, stream>>>(part0, part1, resid, out);
}

// Round 11
// 1283.243 us; speedup vs baseline: 7.5433x; 1.0738x over previous
//
#include <hip/hip_runtime.h>

typedef __attribute__((ext_vector_type(8))) short bf16x8;
typedef __attribute__((ext_vector_type(4))) float f32x4;

constexpr int T = 2048;
constexpr int D = 4096;
constexpr int NQ = 32;    // query heads
constexpr int NKV = 8;    // kv heads
constexpr int H = 128;    // head dim
constexpr int F = 14336;  // ffn dim
constexpr int NQKV = (NQ + 2 * NKV) * H;  // 6144 packed qkv cols
constexpr int VOFF = (NQ + NKV) * H;      // 5120 col offset of V

__device__ inline unsigned short f2bf(float f) {
  unsigned u = __float_as_uint(f);
  return (unsigned short)((u + 0x7FFFu + ((u >> 16) & 1u)) >> 16);
}

__device__ inline void gload_lds16(const void* g, void* l) {
  __builtin_amdgcn_global_load_lds((const __attribute__((address_space(1))) void*)g,
                                   (__attribute__((address_space(3))) void*)l, 16, 0, 0);
}

#define MFMA16(a, b, c) __builtin_amdgcn_mfma_f32_16x16x32_bf16(a, b, c, 0, 0, 0)

// ------- weight transpose+convert: (K,N) f32 -> (rowmap(N),K) bf16 -------
// MODE 0: row = n;  MODE 1: row = (n>>4)*32 + (n&15);  MODE 2: MODE1 + 16
template <int MODE>
__global__ __launch_bounds__(256) void transpose_bf16(const float* __restrict__ in,
                                                      unsigned short* __restrict__ out,
                                                      int K, int N) {
  __shared__ float tile[64 * 65];
  const int kb = blockIdx.x * 64;
  const int nb = blockIdx.y * 64;
  const int tid = threadIdx.x;
  const int r = tid >> 2;
  const int c4 = tid & 3;
#pragma unroll
  for (int i = 0; i < 4; ++i) {
    float4 v = *(const float4*)(in + (size_t)(kb + r) * N + nb + c4 * 16 + i * 4);
    *(float4*)&tile[r * 65 + c4 * 16 + i * 4] = v;
  }
  __syncthreads();
  const int n = tid >> 2;
  const int kq = tid & 3;
  int nsrc = nb + n;
  int prow = (MODE == 0) ? nsrc : ((nsrc >> 4) * 32 + (nsrc & 15) + (MODE == 2 ? 16 : 0));
#pragma unroll
  for (int half = 0; half < 2; ++half) {
    ushort4 o0, o1;
    int k0 = kq * 16 + half * 8;
    o0.x = f2bf(tile[(k0 + 0) * 65 + n]);
    o0.y = f2bf(tile[(k0 + 1) * 65 + n]);
    o0.z = f2bf(tile[(k0 + 2) * 65 + n]);
    o0.w = f2bf(tile[(k0 + 3) * 65 + n]);
    o1.x = f2bf(tile[(k0 + 4) * 65 + n]);
    o1.y = f2bf(tile[(k0 + 5) * 65 + n]);
    o1.z = f2bf(tile[(k0 + 6) * 65 + n]);
    o1.w = f2bf(tile[(k0 + 7) * 65 + n]);
    unsigned short* op = out + (size_t)prow * K + kb + k0;
    *(ushort4*)(op + 0) = o0;
    *(ushort4*)(op + 4) = o1;
  }
}

// ---------------- RMSNorm: f32 in -> bf16 out ----------------
__global__ __launch_bounds__(256) void rmsnorm_kernel(
    const float* __restrict__ in, const float* __restrict__ scale,
    unsigned short* __restrict__ out) {
  int row = blockIdx.x;
  const float4* xr = (const float4*)(in + (size_t)row * D);
  const float4* sr = (const float4*)scale;
  float4 vals[4];
  float ss = 0.f;
#pragma unroll
  for (int i = 0; i < 4; ++i) {
    float4 v = xr[threadIdx.x + i * 256];
    vals[i] = v;
    ss += v.x * v.x + v.y * v.y + v.z * v.z + v.w * v.w;
  }
#pragma unroll
  for (int off = 32; off; off >>= 1) ss += __shfl_xor(ss, off, 64);
  __shared__ float wsum[4];
  if ((threadIdx.x & 63) == 0) wsum[threadIdx.x >> 6] = ss;
  __syncthreads();
  float r = rsqrtf((wsum[0] + wsum[1] + wsum[2] + wsum[3]) * (1.f / D) + 1e-5f);
#pragma unroll
  for (int i = 0; i < 4; ++i) {
    int vi = threadIdx.x + i * 256;
    float4 v = vals[i];
    float4 s = sr[vi];
    ushort4 o;
    o.x = f2bf(v.x * r * s.x);
    o.y = f2bf(v.y * r * s.y);
    o.z = f2bf(v.z * r * s.z);
    o.w = f2bf(v.w * r * s.w);
    *(ushort4*)(out + (size_t)row * D + (size_t)vi * 4) = o;
  }
}

// ------- fused: resid = a+b+c (f32 out) ; h2 = rmsnorm(resid)*scale (bf16 out) -------
__global__ __launch_bounds__(256) void rmsnorm_add3(
    const float* __restrict__ a, const float* __restrict__ b,
    const float* __restrict__ c, const float* __restrict__ scale,
    float* __restrict__ residOut, unsigned short* __restrict__ out) {
  int row = blockIdx.x;
  const float4* ar = (const float4*)(a + (size_t)row * D);
  const float4* br = (const float4*)(b + (size_t)row * D);
  const float4* cr = (const float4*)(c + (size_t)row * D);
  const float4* sr = (const float4*)scale;
  float4* rr = (float4*)(residOut + (size_t)row * D);
  float4 vals[4];
  float ss = 0.f;
#pragma unroll
  for (int i = 0; i < 4; ++i) {
    int vi = threadIdx.x + i * 256;
    float4 va = ar[vi], vb = br[vi], vc = cr[vi];
    float4 v;
    v.x = va.x + vb.x + vc.x;
    v.y = va.y + vb.y + vc.y;
    v.z = va.z + vb.z + vc.z;
    v.w = va.w + vb.w + vc.w;
    vals[i] = v;
    ss += v.x * v.x + v.y * v.y + v.z * v.z + v.w * v.w;
  }
#pragma unroll
  for (int off = 32; off; off >>= 1) ss += __shfl_xor(ss, off, 64);
  __shared__ float wsum[4];
  if ((threadIdx.x & 63) == 0) wsum[threadIdx.x >> 6] = ss;
  __syncthreads();
  float r = rsqrtf((wsum[0] + wsum[1] + wsum[2] + wsum[3]) * (1.f / D) + 1e-5f);
#pragma unroll
  for (int i = 0; i < 4; ++i) {
    int vi = threadIdx.x + i * 256;
    float4 v = vals[i];
    rr[vi] = v;
    float4 s = sr[vi];
    ushort4 o;
    o.x = f2bf(v.x * r * s.x);
    o.y = f2bf(v.y * r * s.y);
    o.z = f2bf(v.z * r * s.z);
    o.w = f2bf(v.w * r * s.w);
    *(ushort4*)(out + (size_t)row * D + (size_t)vi * 4) = o;
  }
}

// ---------------- out = a + b + c (f32, vectorized) ----------------
__global__ __launch_bounds__(256) void add3_kernel(const float* __restrict__ a,
                                                   const float* __restrict__ b,
                                                   const float* __restrict__ c,
                                                   float* __restrict__ o) {
  int i = blockIdx.x * 256 + threadIdx.x;
  float4 va = ((const float4*)a)[i];
  float4 vb = ((const float4*)b)[i];
  float4 vc = ((const float4*)c)[i];
  float4 vo;
  vo.x = va.x + vb.x + vc.x;
  vo.y = va.y + vb.y + vc.y;
  vo.z = va.z + vb.z + vc.z;
  vo.w = va.w + vb.w + vc.w;
  ((float4*)o)[i] = vo;
}

// ---------------- RoPE cos/sin table ----------------
__global__ __launch_bounds__(256) void rope_table(const int* __restrict__ pos,
                                                  float* __restrict__ ctab,
                                                  float* __restrict__ stab) {
  int idx = blockIdx.x * 256 + threadIdx.x;  // T*64
  int t = idx >> 6, i = idx & 63;
  float inv = exp2f(-(float)i * (log2f(500000.0f) / 64.0f));
  float ang = (float)pos[t] * inv;
  ctab[idx] = cosf(ang);
  stab[idx] = sinf(ang);
}

// ------- RoPE apply: f32 strided in -> bf16 out (scale folded) -------
__global__ __launch_bounds__(256) void rope_bf16(const float* __restrict__ x,
                                                 const float* __restrict__ ctab,
                                                 const float* __restrict__ stab,
                                                 unsigned short* __restrict__ out,
                                                 int nheads, int row_stride, float scale) {
  int idx = blockIdx.x * 256 + threadIdx.x;  // T*nheads*64
  int i = idx & 63;
  int tn = idx >> 6;
  int t = tn / nheads;
  int n = tn - t * nheads;
  float c = ctab[t * 64 + i], s = stab[t * 64 + i];
  const float* p = x + (size_t)t * row_stride + n * H;
  float x1 = p[i], x2 = p[i + 64];
  unsigned short* o = out + (size_t)tn * H;
  o[i] = f2bf((x1 * c - x2 * s) * scale);
  o[i + 64] = f2bf((x2 * c + x1 * s) * scale);
}

// ---------------- 256x256 single-barrier-per-phase GEMM, K-splittable ----------------
// A (M,K) bf16; Bt (N,K) bf16. 8 waves (2M x 4N), per-wave 128x64. BK=64.
// LDS 128KB dbuf. Swizzle both sides: byte_col ^= (row&7)<<4.
// ONE barrier per phase (after reads/stages, before MFMA): read-segment of
// phase p and MFMA of phase p-1 overlap across waves; exactly one barrier
// separates every read from the stage that overwrites its region (validated
// separation pattern). vmcnt(6) at P2 drains all of kt+1 (queue: max 14).
// EP 0: outF/outF2 (by blockIdx.z) = acc (f32)
// EP 4: qkv: col<VOFF -> outF f32 stride Nd; else outB[(col-VOFF)*T+row] bf16
// EP 5: Bt packed gate/up alternating 16-col groups; outB = bf16(silu(g)*u)
template <int EP>
__global__ __launch_bounds__(512, 2) void gemm256(
    const unsigned short* __restrict__ A, const unsigned short* __restrict__ Bt,
    float* __restrict__ outF, float* __restrict__ outF2,
    unsigned short* __restrict__ outB, int Kd, int Nd, int Klen) {
  __shared__ unsigned short lds[65536];
  const int tid = threadIdx.x, lane = tid & 63, wv = tid >> 6;
  const int wm = wv >> 2, wn = wv & 3;
  const int rl = lane & 15, g = lane >> 4;
  const int kz = blockIdx.z;
  // XCD-aware block swizzle within z-slice (gx*gy % 8 == 0)
  int raw = blockIdx.x + blockIdx.y * gridDim.x;
  int cpx = (gridDim.x * gridDim.y) >> 3;
  int sid = (raw & 7) * cpx + (raw >> 3);
  int brow = sid % gridDim.x;
  int bcol = sid / gridDim.x;
  const int m0 = brow * 256, n0 = bcol * 256;

  const int l8 = lane >> 3;
  const int scol = ((lane & 7) ^ l8) * 8;  // pre-swizzled global src col
  const int xr = (rl & 7) << 4;            // read-side swizzle
  const int pc0 = (g * 16) ^ xr;
  const int pc1 = (64 + g * 16) ^ xr;

  const char* ldsc = (const char*)lds;
  const unsigned short* gA = A + (size_t)(m0 + wv * 8 + l8) * Kd + kz * Klen + scol;
  const unsigned short* gB = Bt + (size_t)(n0 + wv * 8 + l8) * Kd + kz * Klen + scol;

  f32x4 acc[8][4];
#pragma unroll
  for (int i = 0; i < 8; ++i)
#pragma unroll
    for (int j = 0; j < 4; ++j) acc[i][j] = (f32x4){0.f, 0.f, 0.f, 0.f};

  const int NT = Klen >> 6;

// line l covers tile rows [l*64, l*64+64): LDS ushort off l*4096 + wv*512
#define STAGE_AL(kt, l)                                                      \
  gload_lds16(gA + (size_t)(kt) * 64 + (size_t)(l) * 64 * Kd,                \
              (void*)&lds[((kt) & 1) * 32768 + (l) * 4096 + wv * 512]);
#define STAGE_BL(kt, l)                                                      \
  gload_lds16(gB + (size_t)(kt) * 64 + (size_t)(l) * 64 * Kd,                \
              (void*)&lds[((kt) & 1) * 32768 + 16384 + (l) * 4096 + wv * 512]);
#define SBAR()                        \
  __builtin_amdgcn_sched_barrier(0);  \
  __builtin_amdgcn_s_barrier();

  // prologue: stage kt=0 and kt=1 fully, drain kt=0's 8 lines
  STAGE_AL(0, 0); STAGE_AL(0, 1); STAGE_AL(0, 2); STAGE_AL(0, 3);
  STAGE_BL(0, 0); STAGE_BL(0, 1); STAGE_BL(0, 2); STAGE_BL(0, 3);
  STAGE_AL(1, 0); STAGE_AL(1, 1); STAGE_AL(1, 2); STAGE_AL(1, 3);
  STAGE_BL(1, 0); STAGE_BL(1, 1); STAGE_BL(1, 2); STAGE_BL(1, 3);
  asm volatile("s_waitcnt vmcnt(8)" ::: "memory");
  SBAR();

  const int bhalf = (wn >> 1) * 16384;
  const int brl = (wn & 1) * 64;

  // pre-read B-lo of kt=0 (buffer 0; landed block-wide after prologue barrier)
  bf16x8 bLoC[2][2];
  {
    const char* bB0 = ldsc + 32768 + bhalf;
#pragma unroll
    for (int nf = 0; nf < 2; ++nf) {
      bLoC[nf][0] = *(const bf16x8*)(bB0 + (brl + nf * 16 + rl) * 128 + pc0);
      bLoC[nf][1] = *(const bf16x8*)(bB0 + (brl + nf * 16 + rl) * 128 + pc1);
    }
  }

  for (int kt = 0; kt < NT; ++kt) {
    const int b = kt & 1;
    const char* aB = ldsc + b * 65536 + wm * 16384;
    const char* bB = ldsc + b * 65536 + 32768 + bhalf;
    const char* bBn = ldsc + (b ^ 1) * 65536 + 32768 + bhalf;
    const bool pre = (kt + 2 < NT);
    bf16x8 aLo[4][2], aHi[4][2], bHi[2][2], bLoN[2][2];
    // ---- P0: read A-lo (8); | q0 = aLo x bLoC ----
#pragma unroll
    for (int mf = 0; mf < 4; ++mf) {
      aLo[mf][0] = *(const bf16x8*)(aB + (mf * 16 + rl) * 128 + pc0);
      aLo[mf][1] = *(const bf16x8*)(aB + (mf * 16 + rl) * 128 + pc1);
    }
    SBAR();
    __builtin_amdgcn_s_setprio(1);
#pragma unroll
    for (int mf = 0; mf < 4; ++mf)
#pragma unroll
      for (int nf = 0; nf < 2; ++nf) {
        acc[mf][nf] = MFMA16(aLo[mf][0], bLoC[nf][0], acc[mf][nf]);
        acc[mf][nf] = MFMA16(aLo[mf][1], bLoC[nf][1], acc[mf][nf]);
      }
    __builtin_amdgcn_s_setprio(0);
    // ---- P1: read B-hi (4); stage A(kt+2) lo-lines; | q1 ----
#pragma unroll
    for (int nf = 0; nf < 2; ++nf) {
      bHi[nf][0] = *(const bf16x8*)(bB + (brl + (nf + 2) * 16 + rl) * 128 + pc0);
      bHi[nf][1] = *(const bf16x8*)(bB + (brl + (nf + 2) * 16 + rl) * 128 + pc1);
    }
    if (pre) { STAGE_AL(kt + 2, 0); STAGE_AL(kt + 2, 2); }
    SBAR();
    __builtin_amdgcn_s_setprio(1);
#pragma unroll
    for (int mf = 0; mf < 4; ++mf)
#pragma unroll
      for (int nf = 0; nf < 2; ++nf) {
        acc[mf][nf + 2] = MFMA16(aLo[mf][0], bHi[nf][0], acc[mf][nf + 2]);
        acc[mf][nf + 2] = MFMA16(aLo[mf][1], bHi[nf][1], acc[mf][nf + 2]);
      }
    __builtin_amdgcn_s_setprio(0);
    // ---- P2: read A-hi (8); stage B(kt+2) 4 lines; vmcnt; | q2 ----
#pragma unroll
    for (int mf = 0; mf < 4; ++mf) {
      aHi[mf][0] = *(const bf16x8*)(aB + ((mf + 4) * 16 + rl) * 128 + pc0);
      aHi[mf][1] = *(const bf16x8*)(aB + ((mf + 4) * 16 + rl) * 128 + pc1);
    }
    if (pre) {
      STAGE_BL(kt + 2, 0); STAGE_BL(kt + 2, 1);
      STAGE_BL(kt + 2, 2); STAGE_BL(kt + 2, 3);
      asm volatile("s_waitcnt vmcnt(6)" ::: "memory");  // drain all kt+1 lines
    } else {
      asm volatile("s_waitcnt vmcnt(0)" ::: "memory");  // tail: drain everything
    }
    SBAR();
    __builtin_amdgcn_s_setprio(1);
#pragma unroll
    for (int mf = 0; mf < 4; ++mf)
#pragma unroll
      for (int nf = 0; nf < 2; ++nf) {
        acc[mf + 4][nf + 2] = MFMA16(aHi[mf][0], bHi[nf][0], acc[mf + 4][nf + 2]);
        acc[mf + 4][nf + 2] = MFMA16(aHi[mf][1], bHi[nf][1], acc[mf + 4][nf + 2]);
      }
    __builtin_amdgcn_s_setprio(0);
    // ---- P3: stage A(kt+2) hi-lines; pre-read B-lo(kt+1) (4); | q3 ----
    if (pre) { STAGE_AL(kt + 2, 1); STAGE_AL(kt + 2, 3); }
    if (kt + 1 < NT) {
#pragma unroll
      for (int nf = 0; nf < 2; ++nf) {
        bLoN[nf][0] = *(const bf16x8*)(bBn + (brl + nf * 16 + rl) * 128 + pc0);
        bLoN[nf][1] = *(const bf16x8*)(bBn + (brl + nf * 16 + rl) * 128 + pc1);
      }
    }
    SBAR();
    __builtin_amdgcn_s_setprio(1);
#pragma unroll
    for (int mf = 0; mf < 4; ++mf)
#pragma unroll
      for (int nf = 0; nf < 2; ++nf) {
        acc[mf + 4][nf] = MFMA16(aHi[mf][0], bLoC[nf][0], acc[mf + 4][nf]);
        acc[mf + 4][nf] = MFMA16(aHi[mf][1], bLoC[nf][1], acc[mf + 4][nf]);
      }
    __builtin_amdgcn_s_setprio(0);
    if (kt + 1 < NT) {
#pragma unroll
      for (int nf = 0; nf < 2; ++nf) {
        bLoC[nf][0] = bLoN[nf][0];
        bLoC[nf][1] = bLoN[nf][1];
      }
    }
  }

  const int g4 = g * 4;
  if constexpr (EP == 5) {
    const int acolBase = ((n0 + wn * 64) >> 1) + rl;
#pragma unroll
    for (int mf = 0; mf < 8; ++mf)
#pragma unroll
      for (int p = 0; p < 2; ++p) {
        int acol = acolBase + p * 16;
#pragma unroll
        for (int jj = 0; jj < 4; ++jj) {
          int row = m0 + wm * 128 + mf * 16 + g4 + jj;
          float gg = acc[mf][2 * p][jj];
          float uu = acc[mf][2 * p + 1][jj];
          outB[(size_t)row * F + acol] = f2bf(gg / (1.f + __expf(-gg)) * uu);
        }
      }
  } else if constexpr (EP == 4) {
    if (n0 >= VOFF) {
      // V region: bf16 transposed (NKV*H, T)
#pragma unroll
      for (int mf = 0; mf < 8; ++mf)
#pragma unroll
        for (int q = 0; q < 4; ++q) {
          int col = n0 + wn * 64 + q * 16 + rl;
          int row0 = m0 + wm * 128 + mf * 16 + g4;
          ushort4 o;
          o.x = f2bf(acc[mf][q][0]);
          o.y = f2bf(acc[mf][q][1]);
          o.z = f2bf(acc[mf][q][2]);
          o.w = f2bf(acc[mf][q][3]);
          *(ushort4*)&outB[(size_t)(col - VOFF) * T + row0] = o;
        }
    } else {
#pragma unroll
      for (int mf = 0; mf < 8; ++mf)
#pragma unroll
        for (int q = 0; q < 4; ++q) {
          int col = n0 + wn * 64 + q * 16 + rl;
#pragma unroll
          for (int jj = 0; jj < 4; ++jj) {
            int row = m0 + wm * 128 + mf * 16 + g4 + jj;
            outF[(size_t)row * Nd + col] = acc[mf][q][jj];
          }
        }
    }
  } else {
    float* dst = kz ? outF2 : outF;
#pragma unroll
    for (int mf = 0; mf < 8; ++mf)
#pragma unroll
      for (int q = 0; q < 4; ++q) {
        int col = n0 + wn * 64 + q * 16 + rl;
#pragma unroll
        for (int jj = 0; jj < 4; ++jj) {
          int row = m0 + wm * 128 + mf * 16 + g4 + jj;
          dst[(size_t)row * Nd + col] = acc[mf][q][jj];
        }
      }
  }
#undef STAGE_AL
#undef STAGE_BL
#undef SBAR
}

// ---------------- Flash attention (MFMA), GQA group-shared K/V ----------------
// Block: 32 q-rows x one KV group (4 heads). 8 waves (512 thr):
// wv&3 = head-in-group, wv>>2 = 16-row half. K/V staged once per block.
constexpr int KLD = 136;
constexpr int VLD = 72;
constexpr int PLD = 72;

__global__ __launch_bounds__(512) void flash_attn(
    const unsigned short* __restrict__ qbf, const unsigned short* __restrict__ kbf,
    const unsigned short* __restrict__ vtbf, unsigned short* __restrict__ out) {
  __shared__ unsigned short K_lds[64 * KLD];
  __shared__ unsigned short Vt_lds[H * VLD];
  __shared__ unsigned short P_lds[8 * 16 * PLD];

  const int tid = threadIdx.x;
  const int lane = tid & 63;
  const int wv = tid >> 6;
  const int qb = blockIdx.x;   // 32-row q block
  const int kvh = blockIdx.y;  // kv head
  const int qh = wv & 3, rh = wv >> 2;
  const int n = kvh * 4 + qh;
  const int g = lane >> 4;
  const int rl = lane & 15;
  const int qrow = qb * 32 + rh * 16;

  bf16x8 qfrag[4];
  {
    const unsigned short* qp = qbf + ((size_t)(qrow + rl) * NQ + n) * H + g * 8;
#pragma unroll
    for (int ks = 0; ks < 4; ++ks) qfrag[ks] = *(const bf16x8*)(qp + ks * 32);
  }

  f32x4 oacc[8];
#pragma unroll
  for (int ob = 0; ob < 8; ++ob) oacc[ob] = (f32x4){0.f, 0.f, 0.f, 0.f};
  float mrun[4] = {-1e30f, -1e30f, -1e30f, -1e30f};
  float lrun[4] = {0.f, 0.f, 0.f, 0.f};

  // staging maps (512 threads): K 64x128, Vt 128x64, 16 cols/thread each
  const int krow = tid >> 3, kseg = (tid & 7) * 16;
  const int vh = tid >> 2, vseg = (tid & 3) * 16;

  const int ktmax = (qb * 32 + 31) >> 6;
  for (int kt = 0; kt <= ktmax; ++kt) {
    const int kbase = kt * 64;
    __syncthreads();
    {
      const unsigned short* kp = kbf + ((size_t)(kbase + krow) * NKV + kvh) * H + kseg;
      *(bf16x8*)&K_lds[krow * KLD + kseg] = *(const bf16x8*)kp;
      *(bf16x8*)&K_lds[krow * KLD + kseg + 8] = *(const bf16x8*)(kp + 8);
      const unsigned short* vp = vtbf + (size_t)(kvh * H + vh) * T + kbase + vseg;
      *(bf16x8*)&Vt_lds[vh * VLD + vseg] = *(const bf16x8*)vp;
      *(bf16x8*)&Vt_lds[vh * VLD + vseg + 8] = *(const bf16x8*)(vp + 8);
    }
    __syncthreads();

    f32x4 sacc[4];
#pragma unroll
    for (int cb = 0; cb < 4; ++cb) sacc[cb] = (f32x4){0.f, 0.f, 0.f, 0.f};
#pragma unroll
    for (int cb = 0; cb < 4; ++cb)
#pragma unroll
      for (int ks = 0; ks < 4; ++ks) {
        bf16x8 kf = *(const bf16x8*)&K_lds[(cb * 16 + rl) * KLD + ks * 32 + g * 8];
        sacc[cb] = MFMA16(qfrag[ks], kf, sacc[cb]);
      }

    if (kt == ktmax) {  // causal mask, absolute indices
#pragma unroll
      for (int cb = 0; cb < 4; ++cb) {
        int kv_abs = kbase + cb * 16 + rl;
#pragma unroll
        for (int r = 0; r < 4; ++r) {
          if (kv_abs > qrow + g * 4 + r) sacc[cb][r] = -1e30f;
        }
      }
    }

    float mx[4], sm[4], corr[4];
#pragma unroll
    for (int r = 0; r < 4; ++r) {
      float m0 = fmaxf(fmaxf(sacc[0][r], sacc[1][r]), fmaxf(sacc[2][r], sacc[3][r]));
#pragma unroll
      for (int off = 1; off < 16; off <<= 1) m0 = fmaxf(m0, __shfl_xor(m0, off, 64));
      float nm = fmaxf(mrun[r], m0);
      corr[r] = __expf(mrun[r] - nm);
      mrun[r] = nm;
      mx[r] = nm;
    }
#pragma unroll
    for (int cb = 0; cb < 4; ++cb)
#pragma unroll
      for (int r = 0; r < 4; ++r) sacc[cb][r] = __expf(sacc[cb][r] - mx[r]);
#pragma unroll
    for (int r = 0; r < 4; ++r) {
      float s0 = sacc[0][r] + sacc[1][r] + sacc[2][r] + sacc[3][r];
#pragma unroll
      for (int off = 1; off < 16; off <<= 1) s0 += __shfl_xor(s0, off, 64);
      sm[r] = s0;
      lrun[r] = lrun[r] * corr[r] + sm[r];
    }
#pragma unroll
    for (int ob = 0; ob < 8; ++ob)
#pragma unroll
      for (int r = 0; r < 4; ++r) oacc[ob][r] *= corr[r];

#pragma unroll
    for (int cb = 0; cb < 4; ++cb)
#pragma unroll
      for (int r = 0; r < 4; ++r)
        P_lds[(wv * 16 + g * 4 + r) * PLD + cb * 16 + rl] = f2bf(sacc[cb][r]);

    bf16x8 pa[2];
#pragma unroll
    for (int ks = 0; ks < 2; ++ks)
      pa[ks] = *(const bf16x8*)&P_lds[(wv * 16 + rl) * PLD + ks * 32 + g * 8];

#pragma unroll
    for (int ob = 0; ob < 8; ++ob)
#pragma unroll
      for (int ks = 0; ks < 2; ++ks) {
        bf16x8 vf = *(const bf16x8*)&Vt_lds[(ob * 16 + rl) * VLD + ks * 32 + g * 8];
        oacc[ob] = MFMA16(pa[ks], vf, oacc[ob]);
      }
  }

  float inv[4];
#pragma unroll
  for (int r = 0; r < 4; ++r) inv[r] = 1.f / lrun[r];
#pragma unroll
  for (int ob = 0; ob < 8; ++ob)
#pragma unroll
    for (int r = 0; r < 4; ++r) {
      int t = qrow + g * 4 + r;
      out[((size_t)t * NQ + n) * H + ob * 16 + rl] = f2bf(oacc[ob][r] * inv[r]);
    }
}

extern "C" void kernel_launch(void* const* d_in, const int* in_sizes, int n_in,
                              void* d_out, int out_size, void* d_ws, size_t ws_size,
                              hipStream_t stream) {
  (void)in_sizes; (void)n_in; (void)out_size; (void)ws_size;
  const float* x = (const float*)d_in[0];
  const int* positions = (const int*)d_in[1];
  const float* ln1 = (const float*)d_in[2];
  const float* w_q = (const float*)d_in[3];
  const float* w_k = (const float*)d_in[4];
  const float* w_v = (const float*)d_in[5];
  const float* w_o = (const float*)d_in[6];
  const float* ln2 = (const float*)d_in[7];
  const float* w_gate = (const float*)d_in[8];
  const float* w_up = (const float*)d_in[9];
  const float* w_down = (const float*)d_in[10];
  float* out = (float*)d_out;

  char* ws = (char*)d_ws;
  size_t off = 0;
  auto alloc = [&](size_t bytes) {
    char* p = ws + off;
    off += (bytes + 255) & ~(size_t)255;
    return p;
  };
  unsigned short* h_bf = (unsigned short*)alloc((size_t)T * D * 2);
  unsigned short* h2_bf = (unsigned short*)alloc((size_t)T * D * 2);
  unsigned short* attn_bf = (unsigned short*)alloc((size_t)T * NQ * H * 2);
  unsigned short* act_bf = (unsigned short*)alloc((size_t)T * F * 2);
  float* qkvf = (float*)alloc((size_t)T * NQKV * 4);
  float* resid = (float*)alloc((size_t)T * D * 4);
  float* ctab = (float*)alloc((size_t)T * 64 * 4);
  float* stab = (float*)alloc((size_t)T * 64 * 4);
  unsigned short* qbf = (unsigned short*)alloc((size_t)T * NQ * H * 2);
  unsigned short* kbf = (unsigned short*)alloc((size_t)T * NKV * H * 2);
  unsigned short* vtbf = (unsigned short*)alloc((size_t)NKV * H * T * 2);
  unsigned short* wqkvt = (unsigned short*)alloc((size_t)NQKV * D * 2);
  unsigned short* wot = (unsigned short*)alloc((size_t)D * NQ * H * 2);
  unsigned short* wgut = (unsigned short*)alloc((size_t)2 * F * D * 2);
  unsigned short* wdt = (unsigned short*)alloc((size_t)D * F * 2);
  // K-split partial buffers aliased onto dead regions (each needs T*D*4 = 33.6MB)
  float* part0 = qkvf;            // qkvf: 50.3MB, dead after rope_bf16
  float* part1 = (float*)wqkvt;   // wqkvt: 50.3MB, dead after QKV GEMM

  transpose_bf16<0><<<dim3(D / 64, (NQ * H) / 64), 256, 0, stream>>>(w_q, wqkvt, D, NQ * H);
  transpose_bf16<0><<<dim3(D / 64, (NKV * H) / 64), 256, 0, stream>>>(
      w_k, wqkvt + (size_t)NQ * H * D, D, NKV * H);
  transpose_bf16<0><<<dim3(D / 64, (NKV * H) / 64), 256, 0, stream>>>(
      w_v, wqkvt + (size_t)VOFF * D, D, NKV * H);
  transpose_bf16<0><<<dim3((NQ * H) / 64, D / 64), 256, 0, stream>>>(w_o, wot, NQ * H, D);
  transpose_bf16<1><<<dim3(D / 64, F / 64), 256, 0, stream>>>(w_gate, wgut, D, F);
  transpose_bf16<2><<<dim3(D / 64, F / 64), 256, 0, stream>>>(w_up, wgut, D, F);
  transpose_bf16<0><<<dim3(F / 64, D / 64), 256, 0, stream>>>(w_down, wdt, F, D);

  rmsnorm_kernel<<<T, 256, 0, stream>>>(x, ln1, h_bf);
  rope_table<<<(T * 64) / 256, 256, 0, stream>>>(positions, ctab, stab);
  // QKV on 256² structure: q/k -> qkvf f32, V -> vtbf bf16 transposed
  gemm256<4><<<dim3(T / 256, NQKV / 256, 1), 512, 0, stream>>>(
      h_bf, wqkvt, qkvf, nullptr, vtbf, D, NQKV, D);
  rope_bf16<<<(T * NQ * 64) / 256, 256, 0, stream>>>(qkvf, ctab, stab, qbf, NQ, NQKV,
                                                     0.08838834764831845f);
  rope_bf16<<<(T * NKV * 64) / 256, 256, 0, stream>>>(qkvf + NQ * H, ctab, stab, kbf,
                                                      NKV, NQKV, 1.0f);
  flash_attn<<<dim3(T / 32, NKV), 512, 0, stream>>>(qbf, kbf, vtbf, attn_bf);
  // O-proj: 256² K-split x2 (full machine) -> partials
  gemm256<0><<<dim3(T / 256, D / 256, 2), 512, 0, stream>>>(
      attn_bf, wot, part0, part1, nullptr, NQ * H, D, NQ * H / 2);
  // fused: resid = p0+p1+x ; h2 = rmsnorm(resid)*ln2
  rmsnorm_add3<<<T, 256, 0, stream>>>(part0, part1, x, ln2, resid, h2_bf);
  // 256² interleaved gate/up GEMM
  gemm256<5><<<dim3(T / 256, (2 * F) / 256), 512, 0, stream>>>(
      h2_bf, wgut, nullptr, nullptr, act_bf, D, 2 * F, D);
  // down-proj: 256² K-split x2 -> partials, then out = p0+p1+resid
  gemm256<0><<<dim3(T / 256, D / 256, 2), 512, 0, stream>>>(
      act_bf, wdt, part0, part1, nullptr, F, D, F / 2);
  add3_kernel<<<(T * D / 4) / 256, 256, 0, stream>>>(part0, part1, resid, out);
}